// Round 3
// baseline (1509.217 us; speedup 1.0000x reference)
//
#include <hip/hip_runtime.h>
#include <cstdint>

#define B_ 16
#define L_ 512
#define N_ 8192
#define K_ 30
#define E_ (N_*K_)
#define H_ 32
#define C_ 35
#define INVDIM 102

typedef uint16_t u16;
typedef uint32_t u32;

// adaptive float load: bf16 (u16<<16) or fp32
static __device__ __forceinline__ float ldf(const void* p, int i, int bf) {
    return bf ? __uint_as_float(((u32)((const u16*)p)[i]) << 16)
              : ((const float*)p)[i];
}
// mask load: mode 0 = u8 bool, 1 = int32, 2 = int64 (little-endian low word)
static __device__ __forceinline__ int ldmask(const void* p, int i, int mode) {
    if (mode == 0) return ((const unsigned char*)p)[i] != 0;
    if (mode == 2) return ((const u32*)p)[2*i] != 0;
    return ((const u32*)p)[i] != 0;
}
// f32 -> bf16 RNE
static __device__ __forceinline__ u16 f2bf(float f) {
    u32 x = __float_as_uint(f);
    u32 r = x + 0x7FFFu + ((x >> 16) & 1u);
    return (u16)(r >> 16);
}

// ---------------- kernel 0: dtype detection ----------------
// flag[0]: 1 if float inputs are bf16, 0 if fp32.  flag[1]: mask mode (0/1/2).
__global__ void detect_kernel(const u16* __restrict__ tr, const u32* __restrict__ xm,
                              int* __restrict__ flag)
{
    int lane = threadIdx.x;
    int cnt = 0;
    for (int i = lane; i < 256; i += 64) {
        u16 v = tr[2 * i];                      // even u16: real value if bf16, mantissa noise if fp32
        int e = (v >> 7) & 0xFF;
        if ((e >= 100 && e <= 141) || (v & 0x7FFFu) == 0) cnt++;
    }
    int anyBig = 0, oddNZ = 0;
    for (int i = lane; i < 1024; i += 64) {
        u32 w = xm[i];
        if (w & ~1u) anyBig = 1;                // byte-packed bools
        if ((i & 1) && w) oddNZ = 1;            // odd words nonzero -> not int64
    }
    #pragma unroll
    for (int d = 1; d < 64; d <<= 1) {
        cnt    += __shfl_xor(cnt, d, 64);
        anyBig |= __shfl_xor(anyBig, d, 64);
        oddNZ  |= __shfl_xor(oddNZ, d, 64);
    }
    if (lane == 0) {
        flag[0] = (cnt >= 192) ? 1 : 0;
        flag[1] = anyBig ? 0 : (oddNZ ? 1 : 2);
    }
}

// ---------------- kernel 0.5: canonicalize all inputs to f32 ----------------
#define T_NODE  1048576
#define T_TRANS 1073152
#define T_ROTS  1146880
#define T_WA    1159936
#define T_AV    1160064
#define T_WV    1162304
#define T_WO    1164352
#define T_WG    1165376
#define T_W2    1166400
#define T_EDIT  1174592

__global__ void conv_kernel(const void* rots, const void* trans, const void* node,
                            const void* xm, const void* nm,
                            const void* Wa, const void* av, const void* Wv,
                            const void* Wo, const void* Wg, const void* W2,
                            const int* __restrict__ flag,
                            float* c_node, float* c_trans, float* c_rots,
                            float* c_Wa, float* c_av, float* c_Wv,
                            float* c_Wo, float* c_Wg, float* c_W2, float* c_edit)
{
    int gid = blockIdx.x * 256 + threadIdx.x;
    if (gid >= T_EDIT) return;
    int bf = flag[0], mm = flag[1];
    if      (gid < T_NODE)  c_node [gid]           = ldf(node,  gid,            bf);
    else if (gid < T_TRANS) c_trans[gid - T_NODE]  = ldf(trans, gid - T_NODE,   bf);
    else if (gid < T_ROTS)  c_rots [gid - T_TRANS] = ldf(rots,  gid - T_TRANS,  bf);
    else if (gid < T_WA)    c_Wa   [gid - T_ROTS]  = ldf(Wa,    gid - T_ROTS,   bf);
    else if (gid < T_AV)    c_av   [gid - T_WA]    = ldf(av,    gid - T_WA,     bf);
    else if (gid < T_WV)    c_Wv   [gid - T_AV]    = ldf(Wv,    gid - T_AV,     bf);
    else if (gid < T_WO)    c_Wo   [gid - T_WV]    = ldf(Wo,    gid - T_WV,     bf);
    else if (gid < T_WG)    c_Wg   [gid - T_WO]    = ldf(Wg,    gid - T_WO,     bf);
    else if (gid < T_W2)    c_W2   [gid - T_WG]    = ldf(W2,    gid - T_WG,     bf);
    else {
        int n = gid - T_W2;
        c_edit[n] = (ldmask(nm, n, mm) && !ldmask(xm, n, mm)) ? 1.f : 0.f;
    }
}

// ---------------- kernel 1: per-chain kNN (top-30 smallest d2, tie -> lowest index) ----------------
__global__ __launch_bounds__(512) void knn_kernel(const float* __restrict__ trans,
                                                  int* __restrict__ srcArr)
{
    const int t    = blockIdx.x;
    const int b    = t >> 9;
    const int l    = t & 511;
    const int base = b * L_;
    __shared__ float xs[L_], ys[L_], zs[L_];
    __shared__ float redd[8];
    __shared__ int   redi[8];
    __shared__ int   winner_s;
    const int tid = threadIdx.x;

    xs[tid] = trans[(base + tid) * 3 + 0];
    ys[tid] = trans[(base + tid) * 3 + 1];
    zs[tid] = trans[(base + tid) * 3 + 2];
    __syncthreads();

    const float tx = xs[l], ty = ys[l], tz = zs[l];
    // match numpy: ((dx*dx + dy*dy) + dz*dz), no FMA contraction
    float dx = __fsub_rn(tx, xs[tid]);
    float dy = __fsub_rn(ty, ys[tid]);
    float dz = __fsub_rn(tz, zs[tid]);
    float d2 = __fadd_rn(__fadd_rn(__fmul_rn(dx, dx), __fmul_rn(dy, dy)), __fmul_rn(dz, dz));
    if (tid == l) d2 = __fadd_rn(d2, 1e9f);

    float kd = d2;
    int   ki = tid;
    const int lane = tid & 63, wid = tid >> 6;

    for (int k = 0; k < K_; ++k) {
        float md = kd; int mi = ki;
        #pragma unroll
        for (int d = 1; d < 64; d <<= 1) {
            float od = __shfl_xor(md, d, 64);
            int   oi = __shfl_xor(mi, d, 64);
            if (od < md || (od == md && oi < mi)) { md = od; mi = oi; }
        }
        if (lane == 0) { redd[wid] = md; redi[wid] = mi; }
        __syncthreads();
        if (tid == 0) {
            float bd = redd[0]; int bi = redi[0];
            #pragma unroll
            for (int w = 1; w < 8; ++w)
                if (redd[w] < bd || (redd[w] == bd && redi[w] < bi)) { bd = redd[w]; bi = redi[w]; }
            srcArr[t * K_ + k] = base + bi;
            winner_s = bi;
        }
        __syncthreads();
        if (tid == winner_s) kd = 3.0e38f;
    }
}

// ---------------- kernel 2: fused node embedding [N,4,35] f32 ----------------
__constant__ float cBB[9] = {-0.525f, 1.363f, 0.f,  0.f, 0.f, 0.f,  1.526f, 0.f, 0.f};

__global__ void emb_kernel(const float* __restrict__ rots,
                           const float* __restrict__ node_emb,
                           const float* __restrict__ edit,
                           float* __restrict__ emb)
{
    int gid = blockIdx.x * blockDim.x + threadIdx.x;
    if (gid >= N_ * 140) return;
    int n = gid / 140, s = gid - n * 140;
    int r = s / 35,   c = s - r * 35;
    float v;
    if (c < H_) {
        v = node_emb[n * 128 + r * 32 + c];
    } else if (r == 0) {
        v = (c == 34) ? edit[n] : 0.f;
    } else {
        int i = r - 1, a = c - 32;
        v = rots[n*9 + i*3 + 0] * cBB[a*3 + 0]
          + rots[n*9 + i*3 + 1] * cBB[a*3 + 1]
          + rots[n*9 + i*3 + 2] * cBB[a*3 + 2];
    }
    emb[gid] = v;
}

// ---------------- kernel 3: per-edge D1, edge features, logits (one wave per edge) ----------------
__global__ __launch_bounds__(256) void edge_logits_kernel(
    const float* __restrict__ trans, const float* __restrict__ emb,
    const int* __restrict__ srcArr,
    const float* __restrict__ Wa, const float* __restrict__ avec,
    float* __restrict__ d1w, float* __restrict__ logitsw)
{
    __shared__ float invs[4][104];
    const int wid  = threadIdx.x >> 6, lane = threadIdx.x & 63;
    const int e    = blockIdx.x * 4 + wid;
    const int tgt  = e / K_;
    int src = srcArr[e];
    src = (src < 0) ? 0 : ((src >= N_) ? (N_ - 1) : src);

    float vx = trans[src*3+0] - trans[tgt*3+0];
    float vy = trans[src*3+1] - trans[tgt*3+1];
    float vz = trans[src*3+2] - trans[tgt*3+2];
    float dist = sqrtf(vx*vx + vy*vy + vz*vz);
    bool valid = isfinite(dist) && (dist > 1e-3f);

    float dn  = dist + 1e-12f;
    float nxx = vx/dn, nxy = vy/dn, nxz = vz/dn;
    bool useX = fabsf(nxx) < 0.9f;
    float rx = useX ? 1.f : 0.f;
    float rz = useX ? 0.f : 1.f;
    float czx = nxy * rz;
    float czy = nxz * rx - nxx * rz;
    float czz = -nxy * rx;
    float nn = sqrtf(czx*czx + czy*czy + czz*czz) + 1e-12f;
    czx /= nn; czy /= nn; czz /= nn;
    float cyx = nxy * czz - nxz * czy;
    float cyy = nxz * czx - nxx * czz;
    float cyz = nxx * czy - nxy * czx;
    float nn2 = sqrtf(cyx*cyx + cyy*cyy + cyz*cyz) + 1e-12f;
    cyx /= nn2; cyy /= nn2; cyz /= nn2;
    // R rows: [nz, nx, ny];  D1[i][j] = R[p(i)][p(j)], p=(1,2,0)
    float R00=czx, R01=czy, R02=czz;
    float R10=nxx, R11=nxy, R12=nxz;
    float R20=cyx, R21=cyy, R22=cyz;
    if (lane == 0) {
        float dv[9] = {R11,R12,R10, R21,R22,R20, R01,R02,R00};
        float* dp = d1w + (size_t)e * 9;
        #pragma unroll
        for (int q = 0; q < 9; ++q) dp[q] = (fabsf(dv[q]) < 1e30f) ? dv[q] : 0.f;  // NaN/inf scrub
    }

    float dd = (float)(src - tgt);
    for (int idx = lane; idx < INVDIM; idx += 64) {
        float v;
        if (idx < 35) {
            v = emb[(size_t)src * 140 + idx];
        } else if (idx < 70) {
            v = emb[(size_t)tgt * 140 + (idx - 35)];
        } else {
            int f = idx - 70;
            if (f < 16) {
                float tt = (dist - (float)f * (20.f/15.f)) * 0.8f;
                v = expf(-tt * tt);
            } else if (f < 24) {
                int q = f - 16;
                float fr = expf((float)(2*q) * (-0.5756462732485115f));
                v = cosf(dd * fr);
            } else {
                int q = f - 24;
                float fr = expf((float)(2*q) * (-0.5756462732485115f));
                v = sinf(dd * fr);
            }
        }
        invs[wid][idx] = v;
    }
    __syncthreads();

    // hdn = silu(inv @ W_alpha[102,128]); lane computes columns 2*lane, 2*lane+1
    const float2* wa2 = (const float2*)Wa;
    float acc0 = 0.f, acc1 = 0.f;
    for (int i = 0; i < INVDIM; ++i) {
        float v = invs[wid][i];
        float2 w = wa2[i * 64 + lane];
        acc0 = fmaf(v, w.x, acc0);
        acc1 = fmaf(v, w.y, acc1);
    }
    float h0 = acc0 / (1.f + expf(-acc0));
    float h1 = acc1 / (1.f + expf(-acc1));

    int hh = lane >> 3, k0 = (lane & 7) * 2;
    float part = h0 * avec[hh*16 + k0] + h1 * avec[hh*16 + k0 + 1];
    #pragma unroll
    for (int d = 1; d < 8; d <<= 1) part += __shfl_xor(part, d, 64);
    float lg = (part >= 0.f) ? part : 0.2f * part;
    if (!valid) lg = -1e9f;
    lg = (fabsf(lg) < 1e30f) ? lg : -1e9f;          // NaN/inf scrub
    if ((lane & 7) == 0) logitsw[(size_t)e * 8 + hh] = lg;
}

// ---------------- kernel 4: segment softmax (in place, segments contiguous) ----------------
__global__ void softmax_kernel(float* __restrict__ logitsw)
{
    int gid = blockIdx.x * blockDim.x + threadIdx.x;
    if (gid >= N_ * 8) return;
    int t = gid >> 3, h = gid & 7;
    float* lp = logitsw + (size_t)t * K_ * 8 + h;
    float buf[K_];
    float mx = -1e30f;
    #pragma unroll
    for (int k = 0; k < K_; ++k) { buf[k] = lp[k * 8]; mx = fmaxf(mx, buf[k]); }
    float den = 0.f;
    #pragma unroll
    for (int k = 0; k < K_; ++k) {
        float e = (buf[k] > -1e8f) ? expf(buf[k] - mx) : 0.f;
        buf[k] = e; den += e;
    }
    float inv = 1.f / (den + 1e-9f);
    #pragma unroll
    for (int k = 0; k < K_; ++k) lp[k * 8] = buf[k] * inv;
}

// ---------------- kernel 5: values + back-rotation + segment sum + epilogue ----------------
__global__ __launch_bounds__(256) void agg_out_kernel(
    const float* __restrict__ emb, const int* __restrict__ srcArr,
    const float* __restrict__ d1w, const float* __restrict__ alphaw,
    const float* __restrict__ Wv, const float* __restrict__ Wo,
    const float* __restrict__ Wg, const float* __restrict__ W2,
    const int* __restrict__ flag, void* __restrict__ outv)
{
    __shared__ float wv[35 * 64];
    __shared__ float xsr[140];
    __shared__ float mbuf[256];
    __shared__ float ybuf[128];
    __shared__ float gbuf[32];
    const int t = blockIdx.x, tid = threadIdx.x;
    const int obf = flag[0];

    for (int i = tid; i < 35 * 64; i += 256) wv[i] = Wv[i];
    const int r = tid >> 6, cc = tid & 63;
    float agg = 0.f;
    __syncthreads();

    for (int k = 0; k < K_; ++k) {
        const int e = t * K_ + k;
        if (tid < 140) {
            int s = srcArr[e];
            s = (s < 0) ? 0 : ((s >= N_) ? (N_ - 1) : s);
            int rr = tid / 35, c = tid - rr * 35;
            const float* eb = emb + (size_t)s * 140;
            float v;
            if (rr == 0) v = eb[c];
            else {
                const float* dr = d1w + (size_t)e * 9 + (rr - 1) * 3;
                v = dr[0]*eb[35 + c] + dr[1]*eb[70 + c] + dr[2]*eb[105 + c];
            }
            xsr[tid] = v;
        }
        __syncthreads();
        float acc = 0.f;
        const float* xr = xsr + r * 35;
        #pragma unroll
        for (int cp = 0; cp < 35; ++cp) acc = fmaf(xr[cp], wv[cp * 64 + cc], acc);
        acc *= alphaw[(size_t)e * 8 + (cc >> 3)];
        mbuf[tid] = acc;
        __syncthreads();
        if (r == 0) agg += mbuf[cc];
        else {
            const float* dp = d1w + (size_t)e * 9;
            int i = r - 1;                         // m_out[i] = sum_j D1[j][i] * m[1+j]
            agg += dp[i] * mbuf[64 + cc] + dp[3 + i] * mbuf[128 + cc] + dp[6 + i] * mbuf[192 + cc];
        }
        __syncthreads();
    }

    mbuf[tid] = agg;
    __syncthreads();
    if (tid < 128) {
        int rr = tid >> 5, o = tid & 31;
        float y = 0.f;
        #pragma unroll
        for (int c = 0; c < 64; ++c) y = fmaf(mbuf[rr * 64 + c], Wo[c * 32 + o], y);
        ybuf[tid] = y;
    }
    __syncthreads();
    if (tid < 32) {
        float g = 0.f;
        #pragma unroll
        for (int o = 0; o < 32; ++o) g = fmaf(ybuf[o], Wg[o * 32 + tid], g);
        gbuf[tid] = g / (1.f + expf(-g));
    }
    __syncthreads();
    if (tid < 128) {
        int rr = tid >> 5, hh = tid & 31;
        float o = 0.f;
        #pragma unroll
        for (int g = 0; g < 32; ++g) o = fmaf(ybuf[rr * 32 + g] * gbuf[g], W2[g * 32 + hh], o);
        o = (fabsf(o) < 1e30f) ? o : 0.f;          // final NaN/inf scrub
        size_t idx = (size_t)t * 128 + tid;
        if (obf) ((u16*)outv)[idx] = f2bf(o);
        else     ((float*)outv)[idx] = o;
    }
}

extern "C" void kernel_launch(void* const* d_in, const int* in_sizes, int n_in,
                              void* d_out, int out_size, void* d_ws, size_t ws_size,
                              hipStream_t stream)
{
    const void* rots         = d_in[0];
    const void* trans        = d_in[1];
    const void* node_emb     = d_in[2];
    /* d_in[3] = batch (unused; chains are contiguous) */
    const void* x_mask       = d_in[4];
    const void* noising_mask = d_in[5];
    const void* Wa           = d_in[6];
    const void* avec         = d_in[7];
    const void* Wv           = d_in[8];
    const void* Wo           = d_in[9];
    const void* Wg           = d_in[10];
    const void* W2           = d_in[11];

    char* ws = (char*)d_ws;
    int*   flag    = (int*)  (ws + 0);            // 64 B
    float* c_trans = (float*)(ws + 64);           //    98,304
    float* c_rots  = (float*)(ws + 98368);        //   294,912
    float* c_node  = (float*)(ws + 393280);       // 4,194,304
    float* c_Wa    = (float*)(ws + 4587584);      //    52,224
    float* c_av    = (float*)(ws + 4639808);      //       512
    float* c_Wv    = (float*)(ws + 4640320);      //     8,960
    float* c_Wo    = (float*)(ws + 4649280);      //     8,192
    float* c_Wg    = (float*)(ws + 4657472);      //     4,096
    float* c_W2    = (float*)(ws + 4661568);      //     4,096
    float* c_edit  = (float*)(ws + 4665664);      //    32,768
    int*   srcArr  = (int*)  (ws + 4698432);      //   983,040
    float* emb     = (float*)(ws + 5681472);      // 4,587,520
    float* d1w     = (float*)(ws + 10268992);     // 8,847,360
    float* logitsw = (float*)(ws + 19116352);     // 7,864,320  (softmax in place; end ~27.0 MB)

    hipLaunchKernelGGL(detect_kernel, dim3(1), dim3(64), 0, stream,
                       (const u16*)trans, (const u32*)x_mask, flag);
    hipLaunchKernelGGL(conv_kernel, dim3((T_EDIT + 255) / 256), dim3(256), 0, stream,
                       rots, trans, node_emb, x_mask, noising_mask,
                       Wa, avec, Wv, Wo, Wg, W2, flag,
                       c_node, c_trans, c_rots, c_Wa, c_av, c_Wv, c_Wo, c_Wg, c_W2, c_edit);
    hipLaunchKernelGGL(knn_kernel,         dim3(N_),               dim3(512), 0, stream, c_trans, srcArr);
    hipLaunchKernelGGL(emb_kernel,         dim3((N_*140+255)/256), dim3(256), 0, stream, c_rots, c_node, c_edit, emb);
    hipLaunchKernelGGL(edge_logits_kernel, dim3(E_/4),             dim3(256), 0, stream, c_trans, emb, srcArr, c_Wa, c_av, d1w, logitsw);
    hipLaunchKernelGGL(softmax_kernel,     dim3((N_*8+255)/256),   dim3(256), 0, stream, logitsw);
    hipLaunchKernelGGL(agg_out_kernel,     dim3(N_),               dim3(256), 0, stream, emb, srcArr, d1w, logitsw, c_Wv, c_Wo, c_Wg, c_W2, flag, d_out);
}

// Round 4
// 681.846 us; speedup vs baseline: 2.2134x; 2.2134x over previous
//
#include <hip/hip_runtime.h>
#include <cstdint>

#define B_ 16
#define L_ 512
#define N_ 8192
#define K_ 30
#define E_ (N_*K_)
#define H_ 32
#define C_ 35

typedef uint16_t u16;
typedef uint32_t u32;

// adaptive float load: bf16 (u16<<16) or fp32
static __device__ __forceinline__ float ldf(const void* p, int i, int bf) {
    return bf ? __uint_as_float(((u32)((const u16*)p)[i]) << 16)
              : ((const float*)p)[i];
}
// mask load: mode 0 = u8 bool, 1 = int32, 2 = int64 (little-endian low word)
static __device__ __forceinline__ int ldmask(const void* p, int i, int mode) {
    if (mode == 0) return ((const unsigned char*)p)[i] != 0;
    if (mode == 2) return ((const u32*)p)[2*i] != 0;
    return ((const u32*)p)[i] != 0;
}
// f32 -> bf16 RNE
static __device__ __forceinline__ u16 f2bf(float f) {
    u32 x = __float_as_uint(f);
    u32 r = x + 0x7FFFu + ((x >> 16) & 1u);
    return (u16)(r >> 16);
}

// ---------------- kernel 0: dtype detection ----------------
__global__ void detect_kernel(const u16* __restrict__ tr, const u32* __restrict__ xm,
                              int* __restrict__ flag)
{
    int lane = threadIdx.x;
    int cnt = 0;
    for (int i = lane; i < 256; i += 64) {
        u16 v = tr[2 * i];
        int e = (v >> 7) & 0xFF;
        if ((e >= 100 && e <= 141) || (v & 0x7FFFu) == 0) cnt++;
    }
    int anyBig = 0, oddNZ = 0;
    for (int i = lane; i < 1024; i += 64) {
        u32 w = xm[i];
        if (w & ~1u) anyBig = 1;
        if ((i & 1) && w) oddNZ = 1;
    }
    #pragma unroll
    for (int d = 1; d < 64; d <<= 1) {
        cnt    += __shfl_xor(cnt, d, 64);
        anyBig |= __shfl_xor(anyBig, d, 64);
        oddNZ  |= __shfl_xor(oddNZ, d, 64);
    }
    if (lane == 0) {
        flag[0] = (cnt >= 192) ? 1 : 0;
        flag[1] = anyBig ? 0 : (oddNZ ? 1 : 2);
    }
}

// ---------------- kernel 0.5: canonicalize all inputs to f32 ----------------
#define T_NODE  1048576
#define T_TRANS 1073152
#define T_ROTS  1146880
#define T_WA    1159936
#define T_AV    1160064
#define T_WV    1162304
#define T_WO    1164352
#define T_WG    1165376
#define T_W2    1166400
#define T_EDIT  1174592

__global__ void conv_kernel(const void* rots, const void* trans, const void* node,
                            const void* xm, const void* nm,
                            const void* Wa, const void* av, const void* Wv,
                            const void* Wo, const void* Wg, const void* W2,
                            const int* __restrict__ flag,
                            float* c_node, float* c_trans, float* c_rots,
                            float* c_Wa, float* c_av, float* c_Wv,
                            float* c_Wo, float* c_Wg, float* c_W2, float* c_edit)
{
    int gid = blockIdx.x * 256 + threadIdx.x;
    if (gid >= T_EDIT) return;
    int bf = flag[0], mm = flag[1];
    if      (gid < T_NODE)  c_node [gid]           = ldf(node,  gid,            bf);
    else if (gid < T_TRANS) c_trans[gid - T_NODE]  = ldf(trans, gid - T_NODE,   bf);
    else if (gid < T_ROTS)  c_rots [gid - T_TRANS] = ldf(rots,  gid - T_TRANS,  bf);
    else if (gid < T_WA)    c_Wa   [gid - T_ROTS]  = ldf(Wa,    gid - T_ROTS,   bf);
    else if (gid < T_AV)    c_av   [gid - T_WA]    = ldf(av,    gid - T_WA,     bf);
    else if (gid < T_WV)    c_Wv   [gid - T_AV]    = ldf(Wv,    gid - T_AV,     bf);
    else if (gid < T_WO)    c_Wo   [gid - T_WV]    = ldf(Wo,    gid - T_WV,     bf);
    else if (gid < T_WG)    c_Wg   [gid - T_WO]    = ldf(Wg,    gid - T_WO,     bf);
    else if (gid < T_W2)    c_W2   [gid - T_WG]    = ldf(W2,    gid - T_WG,     bf);
    else {
        int n = gid - T_W2;
        c_edit[n] = (ldmask(nm, n, mm) && !ldmask(xm, n, mm)) ? 1.f : 0.f;
    }
}

// ---------------- kernel 1: per-chain kNN ----------------
__global__ __launch_bounds__(512) void knn_kernel(const float* __restrict__ trans,
                                                  int* __restrict__ srcArr)
{
    const int t    = blockIdx.x;
    const int b    = t >> 9;
    const int l    = t & 511;
    const int base = b * L_;
    __shared__ float xs[L_], ys[L_], zs[L_];
    __shared__ float redd[8];
    __shared__ int   redi[8];
    __shared__ int   winner_s;
    const int tid = threadIdx.x;

    xs[tid] = trans[(base + tid) * 3 + 0];
    ys[tid] = trans[(base + tid) * 3 + 1];
    zs[tid] = trans[(base + tid) * 3 + 2];
    __syncthreads();

    const float tx = xs[l], ty = ys[l], tz = zs[l];
    float dx = __fsub_rn(tx, xs[tid]);
    float dy = __fsub_rn(ty, ys[tid]);
    float dz = __fsub_rn(tz, zs[tid]);
    float d2 = __fadd_rn(__fadd_rn(__fmul_rn(dx, dx), __fmul_rn(dy, dy)), __fmul_rn(dz, dz));
    if (tid == l) d2 = __fadd_rn(d2, 1e9f);

    float kd = d2;
    int   ki = tid;
    const int lane = tid & 63, wid = tid >> 6;

    for (int k = 0; k < K_; ++k) {
        float md = kd; int mi = ki;
        #pragma unroll
        for (int d = 1; d < 64; d <<= 1) {
            float od = __shfl_xor(md, d, 64);
            int   oi = __shfl_xor(mi, d, 64);
            if (od < md || (od == md && oi < mi)) { md = od; mi = oi; }
        }
        if (lane == 0) { redd[wid] = md; redi[wid] = mi; }
        __syncthreads();
        if (tid == 0) {
            float bd = redd[0]; int bi = redi[0];
            #pragma unroll
            for (int w = 1; w < 8; ++w)
                if (redd[w] < bd || (redd[w] == bd && redi[w] < bi)) { bd = redd[w]; bi = redi[w]; }
            srcArr[t * K_ + k] = base + bi;
            winner_s = bi;
        }
        __syncthreads();
        if (tid == winner_s) kd = 3.0e38f;
    }
}

// ---------------- kernel 2: fused node embedding [N,4,35] f32 ----------------
__constant__ float cBB[9] = {-0.525f, 1.363f, 0.f,  0.f, 0.f, 0.f,  1.526f, 0.f, 0.f};

__global__ void emb_kernel(const float* __restrict__ rots,
                           const float* __restrict__ node_emb,
                           const float* __restrict__ edit,
                           float* __restrict__ emb)
{
    int gid = blockIdx.x * blockDim.x + threadIdx.x;
    if (gid >= N_ * 140) return;
    int n = gid / 140, s = gid - n * 140;
    int r = s / 35,   c = s - r * 35;
    float v;
    if (c < H_) {
        v = node_emb[n * 128 + r * 32 + c];
    } else if (r == 0) {
        v = (c == 34) ? edit[n] : 0.f;
    } else {
        int i = r - 1, a = c - 32;
        v = rots[n*9 + i*3 + 0] * cBB[a*3 + 0]
          + rots[n*9 + i*3 + 1] * cBB[a*3 + 1]
          + rots[n*9 + i*3 + 2] * cBB[a*3 + 2];
    }
    emb[gid] = v;
}

// ---------------- kernel 3: per-node hidden contributions + pos-emb table ----------------
// hsrc[n] = emb[n,0,:] @ Wa[0:35];  htgt[n] = emb[n,0,:] @ Wa[35:70]
// ptab[d] = posemb(d-512) @ Wa[86:102]
__global__ __launch_bounds__(128) void prep_kernel(const float* __restrict__ emb,
                                                   const float* __restrict__ Wa,
                                                   float* __restrict__ hsrc,
                                                   float* __restrict__ htgt,
                                                   float* __restrict__ ptab)
{
    const int bid = blockIdx.x, c = threadIdx.x;
    if (bid < N_) {
        __shared__ float e0[35];
        if (c < 35) e0[c] = emb[(size_t)bid * 140 + c];
        __syncthreads();
        float a = 0.f, bacc = 0.f;
        #pragma unroll 5
        for (int i = 0; i < 35; ++i) {
            float v = e0[i];
            a    = fmaf(v, Wa[i * 128 + c],        a);
            bacc = fmaf(v, Wa[(35 + i) * 128 + c], bacc);
        }
        hsrc[(size_t)bid * 128 + c] = a;
        htgt[(size_t)bid * 128 + c] = bacc;
    } else {
        int d = bid - N_;                   // 0..1023
        float dd = (float)(d - 512);
        float acc = 0.f;
        #pragma unroll
        for (int q = 0; q < 8; ++q) {
            float fr = expf((float)(2 * q) * (-0.5756462732485115f)); // -ln(1e4)/16
            float ang = dd * fr;
            acc = fmaf(cosf(ang), Wa[(86 + q) * 128 + c], acc);
            acc = fmaf(sinf(ang), Wa[(94 + q) * 128 + c], acc);
        }
        ptab[(size_t)d * 128 + c] = acc;
    }
}

// ---------------- kernel 4: per-edge logits (wave handles 8 edges; rbf GEMV only) ----------------
__global__ __launch_bounds__(256) void logits_kernel(
    const float* __restrict__ trans, const int* __restrict__ srcArr,
    const float* __restrict__ hsrc, const float* __restrict__ htgt,
    const float* __restrict__ ptab, const float* __restrict__ Wa,
    const float* __restrict__ avec, float* __restrict__ logitsw)
{
    __shared__ float wrb[16 * 128];                 // Wa rows 70..85 (rbf block)
    const int tid = threadIdx.x;
    for (int i = tid; i < 2048; i += 256) wrb[i] = Wa[70 * 128 + i];
    __syncthreads();
    const int wid = tid >> 6, lane = tid & 63;
    const float2 av = ((const float2*)avec)[lane];  // a_vec elems (2*lane, 2*lane+1)
    const int e0 = (blockIdx.x * 4 + wid) * 8;

    for (int q = 0; q < 8; ++q) {
        const int e   = e0 + q;
        const int tgt = e / K_;
        int src = srcArr[e];
        src = (src < 0) ? 0 : ((src >= N_) ? (N_ - 1) : src);

        float vx = trans[src*3+0] - trans[tgt*3+0];
        float vy = trans[src*3+1] - trans[tgt*3+1];
        float vz = trans[src*3+2] - trans[tgt*3+2];
        float dist = sqrtf(vx*vx + vy*vy + vz*vz);
        bool valid = isfinite(dist) && (dist > 1e-3f);
        int d = src - tgt + 512;
        d = (d < 0) ? 0 : ((d > 1023) ? 1023 : d);

        float2 hs = ((const float2*)(hsrc + (size_t)src * 128))[lane];
        float2 ht = ((const float2*)(htgt + (size_t)tgt * 128))[lane];
        float2 pt = ((const float2*)(ptab + (size_t)d   * 128))[lane];
        float acc0 = hs.x + ht.x + pt.x;
        float acc1 = hs.y + ht.y + pt.y;
        #pragma unroll
        for (int j = 0; j < 16; ++j) {
            float tt = (dist - (float)j * (20.f/15.f)) * 0.8f;
            float rb = expf(-tt * tt);
            float2 w = ((const float2*)(wrb + j * 128))[lane];
            acc0 = fmaf(rb, w.x, acc0);
            acc1 = fmaf(rb, w.y, acc1);
        }
        float h0 = acc0 / (1.f + expf(-acc0));      // silu
        float h1 = acc1 / (1.f + expf(-acc1));
        float part = h0 * av.x + h1 * av.y;
        #pragma unroll
        for (int s = 1; s < 8; s <<= 1) part += __shfl_xor(part, s, 64);
        float lg = (part >= 0.f) ? part : 0.2f * part;
        if (!valid) lg = -1e9f;
        lg = (fabsf(lg) < 1e30f) ? lg : -1e9f;
        if ((lane & 7) == 0) logitsw[(size_t)e * 8 + (lane >> 3)] = lg;
    }
}

// ---------------- kernel 5: fused softmax + alpha-weighted emb sum + W_v GEMM + epilogue ----------
// Rotation cancellation: agg[t][r] = (sum_k alpha_k[h] * emb[src_k][r]) @ Wv  (per head h)
__global__ __launch_bounds__(256) void agg_out_kernel(
    const float* __restrict__ emb, const int* __restrict__ srcArr,
    const float* __restrict__ logitsw,
    const float* __restrict__ Wv, const float* __restrict__ Wo,
    const float* __restrict__ Wg, const float* __restrict__ W2,
    const int* __restrict__ flag, void* __restrict__ outv)
{
    __shared__ float alp[240];          // [k][h]
    __shared__ int   srcs[K_];
    __shared__ float embS[K_ * 140];    // gathered source features
    __shared__ float wsS[8 * 140];      // per-head weighted sums [h][r*35+cp]
    __shared__ float aggS[256];
    __shared__ float ybuf[128];
    __shared__ float gbuf[32];
    const int t = blockIdx.x, tid = threadIdx.x;
    const int obf = flag[0];

    if (tid < 240) alp[tid] = logitsw[(size_t)t * 240 + tid];
    if (tid < K_) {
        int s = srcArr[t * K_ + tid];
        srcs[tid] = (s < 0) ? 0 : ((s >= N_) ? (N_ - 1) : s);
    }
    __syncthreads();

    // per-head softmax over 30 incoming edges (8 threads)
    if (tid < 8) {
        float mx = -1e30f;
        #pragma unroll
        for (int k = 0; k < K_; ++k) mx = fmaxf(mx, alp[k*8 + tid]);
        float ex[K_]; float den = 0.f;
        #pragma unroll
        for (int k = 0; k < K_; ++k) {
            float l = alp[k*8 + tid];
            float e = (l > -1e8f) ? expf(l - mx) : 0.f;
            ex[k] = e; den += e;
        }
        float inv = 1.f / (den + 1e-9f);
        #pragma unroll
        for (int k = 0; k < K_; ++k) alp[k*8 + tid] = ex[k] * inv;
    }
    // stage gathered emb rows (independent of alp)
    for (int v = tid; v < K_ * 140; v += 256) {
        int k = v / 140, rc = v - k * 140;
        embS[v] = emb[(size_t)srcs[k] * 140 + rc];
    }
    __syncthreads();

    // ws[h][rc] = sum_k alpha[k][h] * embS[k][rc]
    for (int v = tid; v < 8 * 140; v += 256) {
        int h = v / 140, rc = v - h * 140;
        float s = 0.f;
        #pragma unroll 6
        for (int k = 0; k < K_; ++k) s = fmaf(alp[k*8 + h], embS[k*140 + rc], s);
        wsS[v] = s;
    }
    __syncthreads();

    // agg[r][cc] = sum_cp ws[cc>>3][r*35+cp] * Wv[cp][cc]
    {
        const int r = tid >> 6, cc = tid & 63;
        const float* wp = wsS + (cc >> 3) * 140 + r * 35;
        float acc = 0.f;
        #pragma unroll 5
        for (int cp = 0; cp < 35; ++cp) acc = fmaf(wp[cp], Wv[cp * 64 + cc], acc);
        aggS[tid] = acc;
    }
    __syncthreads();

    // epilogue: y = agg @ W_o ; gate = silu(y0 @ W_g) ; out = (y*gate) @ W_2
    if (tid < 128) {
        int rr = tid >> 5, o = tid & 31;
        float y = 0.f;
        #pragma unroll
        for (int c = 0; c < 64; ++c) y = fmaf(aggS[rr * 64 + c], Wo[c * 32 + o], y);
        ybuf[tid] = y;
    }
    __syncthreads();
    if (tid < 32) {
        float g = 0.f;
        #pragma unroll
        for (int o = 0; o < 32; ++o) g = fmaf(ybuf[o], Wg[o * 32 + tid], g);
        gbuf[tid] = g / (1.f + expf(-g));
    }
    __syncthreads();
    if (tid < 128) {
        int rr = tid >> 5, hh = tid & 31;
        float o = 0.f;
        #pragma unroll
        for (int g = 0; g < 32; ++g) o = fmaf(ybuf[rr * 32 + g] * gbuf[g], W2[g * 32 + hh], o);
        o = (fabsf(o) < 1e30f) ? o : 0.f;
        size_t idx = (size_t)t * 128 + tid;
        if (obf) ((u16*)outv)[idx] = f2bf(o);
        else     ((float*)outv)[idx] = o;
    }
}

extern "C" void kernel_launch(void* const* d_in, const int* in_sizes, int n_in,
                              void* d_out, int out_size, void* d_ws, size_t ws_size,
                              hipStream_t stream)
{
    const void* rots         = d_in[0];
    const void* trans        = d_in[1];
    const void* node_emb     = d_in[2];
    /* d_in[3] = batch (unused; chains contiguous) */
    const void* x_mask       = d_in[4];
    const void* noising_mask = d_in[5];
    const void* Wa           = d_in[6];
    const void* avec         = d_in[7];
    const void* Wv           = d_in[8];
    const void* Wo           = d_in[9];
    const void* Wg           = d_in[10];
    const void* W2           = d_in[11];

    char* ws = (char*)d_ws;
    int*   flag    = (int*)  (ws + 0);            // 64
    float* c_trans = (float*)(ws + 64);           //    98,304
    float* c_rots  = (float*)(ws + 98368);        //   294,912
    float* c_node  = (float*)(ws + 393280);       // 4,194,304
    float* c_Wa    = (float*)(ws + 4587584);      //    52,224
    float* c_av    = (float*)(ws + 4639808);      //       512
    float* c_Wv    = (float*)(ws + 4640320);      //     8,960
    float* c_Wo    = (float*)(ws + 4649280);      //     8,192
    float* c_Wg    = (float*)(ws + 4657472);      //     4,096
    float* c_W2    = (float*)(ws + 4661568);      //     4,096
    float* c_edit  = (float*)(ws + 4665664);      //    32,768
    int*   srcArr  = (int*)  (ws + 4698432);      //   983,040
    float* emb     = (float*)(ws + 5681472);      // 4,587,520
    float* hsrc    = (float*)(ws + 10268992);     // 4,194,304
    float* htgt    = (float*)(ws + 14463296);     // 4,194,304
    float* ptab    = (float*)(ws + 18657600);     //   524,288
    float* logitsw = (float*)(ws + 19181888);     // 7,864,320  (end ~27.0 MB)

    hipLaunchKernelGGL(detect_kernel, dim3(1), dim3(64), 0, stream,
                       (const u16*)trans, (const u32*)x_mask, flag);
    hipLaunchKernelGGL(conv_kernel, dim3((T_EDIT + 255) / 256), dim3(256), 0, stream,
                       rots, trans, node_emb, x_mask, noising_mask,
                       Wa, avec, Wv, Wo, Wg, W2, flag,
                       c_node, c_trans, c_rots, c_Wa, c_av, c_Wv, c_Wo, c_Wg, c_W2, c_edit);
    hipLaunchKernelGGL(knn_kernel,   dim3(N_),               dim3(512), 0, stream, c_trans, srcArr);
    hipLaunchKernelGGL(emb_kernel,   dim3((N_*140+255)/256), dim3(256), 0, stream, c_rots, c_node, c_edit, emb);
    hipLaunchKernelGGL(prep_kernel,  dim3(N_ + 1024),        dim3(128), 0, stream, emb, c_Wa, hsrc, htgt, ptab);
    hipLaunchKernelGGL(logits_kernel,dim3(E_/32),            dim3(256), 0, stream,
                       c_trans, srcArr, hsrc, htgt, ptab, c_Wa, c_av, logitsw);
    hipLaunchKernelGGL(agg_out_kernel, dim3(N_),             dim3(256), 0, stream,
                       emb, srcArr, logitsw, c_Wv, c_Wo, c_Wg, c_W2, flag, d_out);
}

// Round 5
// 343.404 us; speedup vs baseline: 4.3949x; 1.9855x over previous
//
#include <hip/hip_runtime.h>
#include <cstdint>

#define B_ 16
#define L_ 512
#define N_ 8192
#define K_ 30
#define E_ (N_*K_)
#define H_ 32
#define C_ 35

typedef uint16_t u16;
typedef uint32_t u32;

// adaptive float load: bf16 (u16<<16) or fp32
static __device__ __forceinline__ float ldf(const void* p, int i, int bf) {
    return bf ? __uint_as_float(((u32)((const u16*)p)[i]) << 16)
              : ((const float*)p)[i];
}
// mask load: mode 0 = u8 bool, 1 = int32, 2 = int64 (little-endian low word)
static __device__ __forceinline__ int ldmask(const void* p, int i, int mode) {
    if (mode == 0) return ((const unsigned char*)p)[i] != 0;
    if (mode == 2) return ((const u32*)p)[2*i] != 0;
    return ((const u32*)p)[i] != 0;
}
// f32 -> bf16 RNE
static __device__ __forceinline__ u16 f2bf(float f) {
    u32 x = __float_as_uint(f);
    u32 r = x + 0x7FFFu + ((x >> 16) & 1u);
    return (u16)(r >> 16);
}

// ---------------- kernel 0: dtype detection ----------------
__global__ void detect_kernel(const u16* __restrict__ tr, const u32* __restrict__ xm,
                              int* __restrict__ flag)
{
    int lane = threadIdx.x;
    int cnt = 0;
    for (int i = lane; i < 256; i += 64) {
        u16 v = tr[2 * i];
        int e = (v >> 7) & 0xFF;
        if ((e >= 100 && e <= 141) || (v & 0x7FFFu) == 0) cnt++;
    }
    int anyBig = 0, oddNZ = 0;
    for (int i = lane; i < 1024; i += 64) {
        u32 w = xm[i];
        if (w & ~1u) anyBig = 1;
        if ((i & 1) && w) oddNZ = 1;
    }
    #pragma unroll
    for (int d = 1; d < 64; d <<= 1) {
        cnt    += __shfl_xor(cnt, d, 64);
        anyBig |= __shfl_xor(anyBig, d, 64);
        oddNZ  |= __shfl_xor(oddNZ, d, 64);
    }
    if (lane == 0) {
        flag[0] = (cnt >= 192) ? 1 : 0;
        flag[1] = anyBig ? 0 : (oddNZ ? 1 : 2);
    }
}

// ---------------- kernel 0.5: canonicalize all inputs to f32 ----------------
#define T_NODE  1048576
#define T_TRANS 1073152
#define T_ROTS  1146880
#define T_WA    1159936
#define T_AV    1160064
#define T_WV    1162304
#define T_WO    1164352
#define T_WG    1165376
#define T_W2    1166400
#define T_EDIT  1174592

__global__ void conv_kernel(const void* rots, const void* trans, const void* node,
                            const void* xm, const void* nm,
                            const void* Wa, const void* av, const void* Wv,
                            const void* Wo, const void* Wg, const void* W2,
                            const int* __restrict__ flag,
                            float* c_node, float* c_trans, float* c_rots,
                            float* c_Wa, float* c_av, float* c_Wv,
                            float* c_Wo, float* c_Wg, float* c_W2, float* c_edit)
{
    int gid = blockIdx.x * 256 + threadIdx.x;
    if (gid >= T_EDIT) return;
    int bf = flag[0], mm = flag[1];
    if      (gid < T_NODE)  c_node [gid]           = ldf(node,  gid,            bf);
    else if (gid < T_TRANS) c_trans[gid - T_NODE]  = ldf(trans, gid - T_NODE,   bf);
    else if (gid < T_ROTS)  c_rots [gid - T_TRANS] = ldf(rots,  gid - T_TRANS,  bf);
    else if (gid < T_WA)    c_Wa   [gid - T_ROTS]  = ldf(Wa,    gid - T_ROTS,   bf);
    else if (gid < T_AV)    c_av   [gid - T_WA]    = ldf(av,    gid - T_WA,     bf);
    else if (gid < T_WV)    c_Wv   [gid - T_AV]    = ldf(Wv,    gid - T_AV,     bf);
    else if (gid < T_WO)    c_Wo   [gid - T_WV]    = ldf(Wo,    gid - T_WV,     bf);
    else if (gid < T_WG)    c_Wg   [gid - T_WO]    = ldf(Wg,    gid - T_WO,     bf);
    else if (gid < T_W2)    c_W2   [gid - T_WG]    = ldf(W2,    gid - T_WG,     bf);
    else {
        int n = gid - T_W2;
        c_edit[n] = (ldmask(nm, n, mm) && !ldmask(xm, n, mm)) ? 1.f : 0.f;
    }
}

// ---------------- kernel 1: per-chain kNN — one wave per target, barrier-free selection ----------
__global__ __launch_bounds__(256) void knn_kernel(const float* __restrict__ trans,
                                                  int* __restrict__ srcArr)
{
    __shared__ float xs[L_], ys[L_], zs[L_];
    const int tid  = threadIdx.x;
    const int t0   = blockIdx.x * 4;        // 4 targets per block, same chain (512 % 4 == 0)
    const int base = (t0 >> 9) << 9;        // chain base node

    for (int i = tid; i < L_; i += 256) {
        xs[i] = trans[(base + i) * 3 + 0];
        ys[i] = trans[(base + i) * 3 + 1];
        zs[i] = trans[(base + i) * 3 + 2];
    }
    __syncthreads();

    const int wid = tid >> 6, lane = tid & 63;
    const int t = t0 + wid;
    const int l = t & 511;
    const float tx = xs[l], ty = ys[l], tz = zs[l];

    // lane owns candidates idx = lane + 64*slot, slot = 0..7 (registers only)
    float cd[8];
    #pragma unroll
    for (int i = 0; i < 8; ++i) {
        int j = lane + (i << 6);
        // match numpy: ((dx*dx + dy*dy) + dz*dz), no FMA contraction
        float dx = __fsub_rn(tx, xs[j]);
        float dy = __fsub_rn(ty, ys[j]);
        float dz = __fsub_rn(tz, zs[j]);
        float d2 = __fadd_rn(__fadd_rn(__fmul_rn(dx, dx), __fmul_rn(dy, dy)), __fmul_rn(dz, dz));
        if (j == l) d2 = __fadd_rn(d2, 1e9f);   // exclude self
        cd[i] = d2;
    }

    int myres = 0;
    for (int k = 0; k < K_; ++k) {
        // local lexicographic min over 8 slots (strict < keeps earliest slot = lowest idx on tie)
        float lm = cd[0]; int ls = 0;
        #pragma unroll
        for (int i = 1; i < 8; ++i)
            if (cd[i] < lm) { lm = cd[i]; ls = i; }
        float md = lm;
        int   mi = lane + (ls << 6);
        // wave butterfly argmin, (d2, idx) lexicographic
        #pragma unroll
        for (int d = 1; d < 64; d <<= 1) {
            float od = __shfl_xor(md, d, 64);
            int   oi = __shfl_xor(mi, d, 64);
            if (od < md || (od == md && oi < mi)) { md = od; mi = oi; }
        }
        if (k == lane) myres = mi;              // lane k records the k-th neighbor
        if ((mi & 63) == lane) {                // winner lane invalidates its slot
            int ws = mi >> 6;
            #pragma unroll
            for (int i = 0; i < 8; ++i)
                if (ws == i) cd[i] = 3.0e38f;
        }
    }
    if (lane < K_) srcArr[t * K_ + lane] = base + myres;
}

// ---------------- kernel 2: fused node embedding [N,4,35] f32 ----------------
__constant__ float cBB[9] = {-0.525f, 1.363f, 0.f,  0.f, 0.f, 0.f,  1.526f, 0.f, 0.f};

__global__ void emb_kernel(const float* __restrict__ rots,
                           const float* __restrict__ node_emb,
                           const float* __restrict__ edit,
                           float* __restrict__ emb)
{
    int gid = blockIdx.x * blockDim.x + threadIdx.x;
    if (gid >= N_ * 140) return;
    int n = gid / 140, s = gid - n * 140;
    int r = s / 35,   c = s - r * 35;
    float v;
    if (c < H_) {
        v = node_emb[n * 128 + r * 32 + c];
    } else if (r == 0) {
        v = (c == 34) ? edit[n] : 0.f;
    } else {
        int i = r - 1, a = c - 32;
        v = rots[n*9 + i*3 + 0] * cBB[a*3 + 0]
          + rots[n*9 + i*3 + 1] * cBB[a*3 + 1]
          + rots[n*9 + i*3 + 2] * cBB[a*3 + 2];
    }
    emb[gid] = v;
}

// ---------------- kernel 3: per-node hidden contributions + pos-emb table ----------------
__global__ __launch_bounds__(128) void prep_kernel(const float* __restrict__ emb,
                                                   const float* __restrict__ Wa,
                                                   float* __restrict__ hsrc,
                                                   float* __restrict__ htgt,
                                                   float* __restrict__ ptab)
{
    const int bid = blockIdx.x, c = threadIdx.x;
    if (bid < N_) {
        __shared__ float e0[35];
        if (c < 35) e0[c] = emb[(size_t)bid * 140 + c];
        __syncthreads();
        float a = 0.f, bacc = 0.f;
        #pragma unroll 5
        for (int i = 0; i < 35; ++i) {
            float v = e0[i];
            a    = fmaf(v, Wa[i * 128 + c],        a);
            bacc = fmaf(v, Wa[(35 + i) * 128 + c], bacc);
        }
        hsrc[(size_t)bid * 128 + c] = a;
        htgt[(size_t)bid * 128 + c] = bacc;
    } else {
        int d = bid - N_;                   // 0..1023
        float dd = (float)(d - 512);
        float acc = 0.f;
        #pragma unroll
        for (int q = 0; q < 8; ++q) {
            float fr = expf((float)(2 * q) * (-0.5756462732485115f)); // -ln(1e4)/16
            float ang = dd * fr;
            acc = fmaf(cosf(ang), Wa[(86 + q) * 128 + c], acc);
            acc = fmaf(sinf(ang), Wa[(94 + q) * 128 + c], acc);
        }
        ptab[(size_t)d * 128 + c] = acc;
    }
}

// ---------------- kernel 4: per-edge logits ----------------
__global__ __launch_bounds__(256) void logits_kernel(
    const float* __restrict__ trans, const int* __restrict__ srcArr,
    const float* __restrict__ hsrc, const float* __restrict__ htgt,
    const float* __restrict__ ptab, const float* __restrict__ Wa,
    const float* __restrict__ avec, float* __restrict__ logitsw)
{
    __shared__ float wrb[16 * 128];                 // Wa rows 70..85 (rbf block)
    const int tid = threadIdx.x;
    for (int i = tid; i < 2048; i += 256) wrb[i] = Wa[70 * 128 + i];
    __syncthreads();
    const int wid = tid >> 6, lane = tid & 63;
    const float2 av = ((const float2*)avec)[lane];
    const int e0 = (blockIdx.x * 4 + wid) * 8;

    for (int q = 0; q < 8; ++q) {
        const int e   = e0 + q;
        const int tgt = e / K_;
        int src = srcArr[e];
        src = (src < 0) ? 0 : ((src >= N_) ? (N_ - 1) : src);

        float vx = trans[src*3+0] - trans[tgt*3+0];
        float vy = trans[src*3+1] - trans[tgt*3+1];
        float vz = trans[src*3+2] - trans[tgt*3+2];
        float dist = sqrtf(vx*vx + vy*vy + vz*vz);
        bool valid = isfinite(dist) && (dist > 1e-3f);
        int d = src - tgt + 512;
        d = (d < 0) ? 0 : ((d > 1023) ? 1023 : d);

        float2 hs = ((const float2*)(hsrc + (size_t)src * 128))[lane];
        float2 ht = ((const float2*)(htgt + (size_t)tgt * 128))[lane];
        float2 pt = ((const float2*)(ptab + (size_t)d   * 128))[lane];
        float acc0 = hs.x + ht.x + pt.x;
        float acc1 = hs.y + ht.y + pt.y;
        #pragma unroll
        for (int j = 0; j < 16; ++j) {
            float tt = (dist - (float)j * (20.f/15.f)) * 0.8f;
            float rb = expf(-tt * tt);
            float2 w = ((const float2*)(wrb + j * 128))[lane];
            acc0 = fmaf(rb, w.x, acc0);
            acc1 = fmaf(rb, w.y, acc1);
        }
        float h0 = acc0 / (1.f + expf(-acc0));      // silu
        float h1 = acc1 / (1.f + expf(-acc1));
        float part = h0 * av.x + h1 * av.y;
        #pragma unroll
        for (int s = 1; s < 8; s <<= 1) part += __shfl_xor(part, s, 64);
        float lg = (part >= 0.f) ? part : 0.2f * part;
        if (!valid) lg = -1e9f;
        lg = (fabsf(lg) < 1e30f) ? lg : -1e9f;
        if ((lane & 7) == 0) logitsw[(size_t)e * 8 + (lane >> 3)] = lg;
    }
}

// ---------------- kernel 5: fused softmax + alpha-weighted emb sum + W_v GEMM + epilogue ----------
__global__ __launch_bounds__(256) void agg_out_kernel(
    const float* __restrict__ emb, const int* __restrict__ srcArr,
    const float* __restrict__ logitsw,
    const float* __restrict__ Wv, const float* __restrict__ Wo,
    const float* __restrict__ Wg, const float* __restrict__ W2,
    const int* __restrict__ flag, void* __restrict__ outv)
{
    __shared__ float alp[240];          // [k][h]
    __shared__ int   srcs[K_];
    __shared__ float embS[K_ * 140];
    __shared__ float wsS[8 * 140];      // per-head weighted sums [h][r*35+cp]
    __shared__ float aggS[256];
    __shared__ float ybuf[128];
    __shared__ float gbuf[32];
    const int t = blockIdx.x, tid = threadIdx.x;
    const int obf = flag[0];

    if (tid < 240) alp[tid] = logitsw[(size_t)t * 240 + tid];
    if (tid < K_) {
        int s = srcArr[t * K_ + tid];
        srcs[tid] = (s < 0) ? 0 : ((s >= N_) ? (N_ - 1) : s);
    }
    __syncthreads();

    if (tid < 8) {
        float mx = -1e30f;
        #pragma unroll
        for (int k = 0; k < K_; ++k) mx = fmaxf(mx, alp[k*8 + tid]);
        float ex[K_]; float den = 0.f;
        #pragma unroll
        for (int k = 0; k < K_; ++k) {
            float l = alp[k*8 + tid];
            float e = (l > -1e8f) ? expf(l - mx) : 0.f;
            ex[k] = e; den += e;
        }
        float inv = 1.f / (den + 1e-9f);
        #pragma unroll
        for (int k = 0; k < K_; ++k) alp[k*8 + tid] = ex[k] * inv;
    }
    for (int v = tid; v < K_ * 140; v += 256) {
        int k = v / 140, rc = v - k * 140;
        embS[v] = emb[(size_t)srcs[k] * 140 + rc];
    }
    __syncthreads();

    for (int v = tid; v < 8 * 140; v += 256) {
        int h = v / 140, rc = v - h * 140;
        float s = 0.f;
        #pragma unroll 6
        for (int k = 0; k < K_; ++k) s = fmaf(alp[k*8 + h], embS[k*140 + rc], s);
        wsS[v] = s;
    }
    __syncthreads();

    {
        const int r = tid >> 6, cc = tid & 63;
        const float* wp = wsS + (cc >> 3) * 140 + r * 35;
        float acc = 0.f;
        #pragma unroll 5
        for (int cp = 0; cp < 35; ++cp) acc = fmaf(wp[cp], Wv[cp * 64 + cc], acc);
        aggS[tid] = acc;
    }
    __syncthreads();

    if (tid < 128) {
        int rr = tid >> 5, o = tid & 31;
        float y = 0.f;
        #pragma unroll
        for (int c = 0; c < 64; ++c) y = fmaf(aggS[rr * 64 + c], Wo[c * 32 + o], y);
        ybuf[tid] = y;
    }
    __syncthreads();
    if (tid < 32) {
        float g = 0.f;
        #pragma unroll
        for (int o = 0; o < 32; ++o) g = fmaf(ybuf[o], Wg[o * 32 + tid], g);
        gbuf[tid] = g / (1.f + expf(-g));
    }
    __syncthreads();
    if (tid < 128) {
        int rr = tid >> 5, hh = tid & 31;
        float o = 0.f;
        #pragma unroll
        for (int g = 0; g < 32; ++g) o = fmaf(ybuf[rr * 32 + g] * gbuf[g], W2[g * 32 + hh], o);
        o = (fabsf(o) < 1e30f) ? o : 0.f;
        size_t idx = (size_t)t * 128 + tid;
        if (obf) ((u16*)outv)[idx] = f2bf(o);
        else     ((float*)outv)[idx] = o;
    }
}

extern "C" void kernel_launch(void* const* d_in, const int* in_sizes, int n_in,
                              void* d_out, int out_size, void* d_ws, size_t ws_size,
                              hipStream_t stream)
{
    const void* rots         = d_in[0];
    const void* trans        = d_in[1];
    const void* node_emb     = d_in[2];
    /* d_in[3] = batch (unused; chains contiguous) */
    const void* x_mask       = d_in[4];
    const void* noising_mask = d_in[5];
    const void* Wa           = d_in[6];
    const void* avec         = d_in[7];
    const void* Wv           = d_in[8];
    const void* Wo           = d_in[9];
    const void* Wg           = d_in[10];
    const void* W2           = d_in[11];

    char* ws = (char*)d_ws;
    int*   flag    = (int*)  (ws + 0);            // 64
    float* c_trans = (float*)(ws + 64);           //    98,304
    float* c_rots  = (float*)(ws + 98368);        //   294,912
    float* c_node  = (float*)(ws + 393280);       // 4,194,304
    float* c_Wa    = (float*)(ws + 4587584);      //    52,224
    float* c_av    = (float*)(ws + 4639808);      //       512
    float* c_Wv    = (float*)(ws + 4640320);      //     8,960
    float* c_Wo    = (float*)(ws + 4649280);      //     8,192
    float* c_Wg    = (float*)(ws + 4657472);      //     4,096
    float* c_W2    = (float*)(ws + 4661568);      //     4,096
    float* c_edit  = (float*)(ws + 4665664);      //    32,768
    int*   srcArr  = (int*)  (ws + 4698432);      //   983,040
    float* emb     = (float*)(ws + 5681472);      // 4,587,520
    float* hsrc    = (float*)(ws + 10268992);     // 4,194,304
    float* htgt    = (float*)(ws + 14463296);     // 4,194,304
    float* ptab    = (float*)(ws + 18657600);     //   524,288
    float* logitsw = (float*)(ws + 19181888);     // 7,864,320  (end ~27.0 MB)

    hipLaunchKernelGGL(detect_kernel, dim3(1), dim3(64), 0, stream,
                       (const u16*)trans, (const u32*)x_mask, flag);
    hipLaunchKernelGGL(conv_kernel, dim3((T_EDIT + 255) / 256), dim3(256), 0, stream,
                       rots, trans, node_emb, x_mask, noising_mask,
                       Wa, avec, Wv, Wo, Wg, W2, flag,
                       c_node, c_trans, c_rots, c_Wa, c_av, c_Wv, c_Wo, c_Wg, c_W2, c_edit);
    hipLaunchKernelGGL(knn_kernel,   dim3(N_/4),             dim3(256), 0, stream, c_trans, srcArr);
    hipLaunchKernelGGL(emb_kernel,   dim3((N_*140+255)/256), dim3(256), 0, stream, c_rots, c_node, c_edit, emb);
    hipLaunchKernelGGL(prep_kernel,  dim3(N_ + 1024),        dim3(128), 0, stream, emb, c_Wa, hsrc, htgt, ptab);
    hipLaunchKernelGGL(logits_kernel,dim3(E_/32),            dim3(256), 0, stream,
                       c_trans, srcArr, hsrc, htgt, ptab, c_Wa, c_av, logitsw);
    hipLaunchKernelGGL(agg_out_kernel, dim3(N_),             dim3(256), 0, stream,
                       emb, srcArr, logitsw, c_Wv, c_Wo, c_Wg, c_W2, flag, d_out);
}

// Round 6
// 273.110 us; speedup vs baseline: 5.5260x; 1.2574x over previous
//
#include <hip/hip_runtime.h>
#include <cstdint>

#define B_ 16
#define L_ 512
#define N_ 8192
#define K_ 30
#define E_ (N_*K_)
#define H_ 32
#define C_ 35

typedef uint16_t u16;
typedef uint32_t u32;

// adaptive float load: bf16 (u16<<16) or fp32
static __device__ __forceinline__ float ldf(const void* p, int i, int bf) {
    return bf ? __uint_as_float(((u32)((const u16*)p)[i]) << 16)
              : ((const float*)p)[i];
}
// mask load: mode 0 = u8 bool, 1 = int32, 2 = int64 (little-endian low word)
static __device__ __forceinline__ int ldmask(const void* p, int i, int mode) {
    if (mode == 0) return ((const unsigned char*)p)[i] != 0;
    if (mode == 2) return ((const u32*)p)[2*i] != 0;
    return ((const u32*)p)[i] != 0;
}
// f32 -> bf16 RNE
static __device__ __forceinline__ u16 f2bf(float f) {
    u32 x = __float_as_uint(f);
    u32 r = x + 0x7FFFu + ((x >> 16) & 1u);
    return (u16)(r >> 16);
}

// ---------------- kernel 0: dtype detection ----------------
__global__ void detect_kernel(const u16* __restrict__ tr, const u32* __restrict__ xm,
                              int* __restrict__ flag)
{
    int lane = threadIdx.x;
    int cnt = 0;
    for (int i = lane; i < 256; i += 64) {
        u16 v = tr[2 * i];
        int e = (v >> 7) & 0xFF;
        if ((e >= 100 && e <= 141) || (v & 0x7FFFu) == 0) cnt++;
    }
    int anyBig = 0, oddNZ = 0;
    for (int i = lane; i < 1024; i += 64) {
        u32 w = xm[i];
        if (w & ~1u) anyBig = 1;
        if ((i & 1) && w) oddNZ = 1;
    }
    #pragma unroll
    for (int d = 1; d < 64; d <<= 1) {
        cnt    += __shfl_xor(cnt, d, 64);
        anyBig |= __shfl_xor(anyBig, d, 64);
        oddNZ  |= __shfl_xor(oddNZ, d, 64);
    }
    if (lane == 0) {
        flag[0] = (cnt >= 192) ? 1 : 0;
        flag[1] = anyBig ? 0 : (oddNZ ? 1 : 2);
    }
}

// ---------------- kernel 0.5: canonicalize all inputs to f32 ----------------
#define T_NODE  1048576
#define T_TRANS 1073152
#define T_ROTS  1146880
#define T_WA    1159936
#define T_AV    1160064
#define T_WV    1162304
#define T_WO    1164352
#define T_WG    1165376
#define T_W2    1166400
#define T_EDIT  1174592

__global__ void conv_kernel(const void* rots, const void* trans, const void* node,
                            const void* xm, const void* nm,
                            const void* Wa, const void* av, const void* Wv,
                            const void* Wo, const void* Wg, const void* W2,
                            const int* __restrict__ flag,
                            float* c_node, float* c_trans, float* c_rots,
                            float* c_Wa, float* c_av, float* c_Wv,
                            float* c_Wo, float* c_Wg, float* c_W2, float* c_edit)
{
    int gid = blockIdx.x * 256 + threadIdx.x;
    if (gid >= T_EDIT) return;
    int bf = flag[0], mm = flag[1];
    if      (gid < T_NODE)  c_node [gid]           = ldf(node,  gid,            bf);
    else if (gid < T_TRANS) c_trans[gid - T_NODE]  = ldf(trans, gid - T_NODE,   bf);
    else if (gid < T_ROTS)  c_rots [gid - T_TRANS] = ldf(rots,  gid - T_TRANS,  bf);
    else if (gid < T_WA)    c_Wa   [gid - T_ROTS]  = ldf(Wa,    gid - T_ROTS,   bf);
    else if (gid < T_AV)    c_av   [gid - T_WA]    = ldf(av,    gid - T_WA,     bf);
    else if (gid < T_WV)    c_Wv   [gid - T_AV]    = ldf(Wv,    gid - T_AV,     bf);
    else if (gid < T_WO)    c_Wo   [gid - T_WV]    = ldf(Wo,    gid - T_WV,     bf);
    else if (gid < T_WG)    c_Wg   [gid - T_WO]    = ldf(Wg,    gid - T_WO,     bf);
    else if (gid < T_W2)    c_W2   [gid - T_WG]    = ldf(W2,    gid - T_WG,     bf);
    else {
        int n = gid - T_W2;
        c_edit[n] = (ldmask(nm, n, mm) && !ldmask(xm, n, mm)) ? 1.f : 0.f;
    }
}

// ---------------- kernel 1: per-chain kNN — one wave per target, barrier-free selection ----------
__global__ __launch_bounds__(256) void knn_kernel(const float* __restrict__ trans,
                                                  int* __restrict__ srcArr)
{
    __shared__ float xs[L_], ys[L_], zs[L_];
    const int tid  = threadIdx.x;
    const int t0   = blockIdx.x * 4;        // 4 targets per block, same chain (512 % 4 == 0)
    const int base = (t0 >> 9) << 9;        // chain base node

    for (int i = tid; i < L_; i += 256) {
        xs[i] = trans[(base + i) * 3 + 0];
        ys[i] = trans[(base + i) * 3 + 1];
        zs[i] = trans[(base + i) * 3 + 2];
    }
    __syncthreads();

    const int wid = tid >> 6, lane = tid & 63;
    const int t = t0 + wid;
    const int l = t & 511;
    const float tx = xs[l], ty = ys[l], tz = zs[l];

    float cd[8];
    #pragma unroll
    for (int i = 0; i < 8; ++i) {
        int j = lane + (i << 6);
        // match numpy: ((dx*dx + dy*dy) + dz*dz), no FMA contraction
        float dx = __fsub_rn(tx, xs[j]);
        float dy = __fsub_rn(ty, ys[j]);
        float dz = __fsub_rn(tz, zs[j]);
        float d2 = __fadd_rn(__fadd_rn(__fmul_rn(dx, dx), __fmul_rn(dy, dy)), __fmul_rn(dz, dz));
        if (j == l) d2 = __fadd_rn(d2, 1e9f);   // exclude self
        cd[i] = d2;
    }

    int myres = 0;
    for (int k = 0; k < K_; ++k) {
        float lm = cd[0]; int ls = 0;
        #pragma unroll
        for (int i = 1; i < 8; ++i)
            if (cd[i] < lm) { lm = cd[i]; ls = i; }
        float md = lm;
        int   mi = lane + (ls << 6);
        #pragma unroll
        for (int d = 1; d < 64; d <<= 1) {
            float od = __shfl_xor(md, d, 64);
            int   oi = __shfl_xor(mi, d, 64);
            if (od < md || (od == md && oi < mi)) { md = od; mi = oi; }
        }
        if (k == lane) myres = mi;
        if ((mi & 63) == lane) {
            int ws = mi >> 6;
            #pragma unroll
            for (int i = 0; i < 8; ++i)
                if (ws == i) cd[i] = 3.0e38f;
        }
    }
    if (lane < K_) srcArr[t * K_ + lane] = base + myres;
}

// ---------------- kernel 2: fused node embedding [N,4,35] f32 ----------------
__constant__ float cBB[9] = {-0.525f, 1.363f, 0.f,  0.f, 0.f, 0.f,  1.526f, 0.f, 0.f};

__global__ void emb_kernel(const float* __restrict__ rots,
                           const float* __restrict__ node_emb,
                           const float* __restrict__ edit,
                           float* __restrict__ emb)
{
    int gid = blockIdx.x * blockDim.x + threadIdx.x;
    if (gid >= N_ * 140) return;
    int n = gid / 140, s = gid - n * 140;
    int r = s / 35,   c = s - r * 35;
    float v;
    if (c < H_) {
        v = node_emb[n * 128 + r * 32 + c];
    } else if (r == 0) {
        v = (c == 34) ? edit[n] : 0.f;
    } else {
        int i = r - 1, a = c - 32;
        v = rots[n*9 + i*3 + 0] * cBB[a*3 + 0]
          + rots[n*9 + i*3 + 1] * cBB[a*3 + 1]
          + rots[n*9 + i*3 + 2] * cBB[a*3 + 2];
    }
    emb[gid] = v;
}

// ---------------- kernel 3: per-node hidden contributions + pos-emb table ----------------
__global__ __launch_bounds__(128) void prep_kernel(const float* __restrict__ emb,
                                                   const float* __restrict__ Wa,
                                                   float* __restrict__ hsrc,
                                                   float* __restrict__ htgt,
                                                   float* __restrict__ ptab)
{
    const int bid = blockIdx.x, c = threadIdx.x;
    if (bid < N_) {
        __shared__ float e0[35];
        if (c < 35) e0[c] = emb[(size_t)bid * 140 + c];
        __syncthreads();
        float a = 0.f, bacc = 0.f;
        #pragma unroll 5
        for (int i = 0; i < 35; ++i) {
            float v = e0[i];
            a    = fmaf(v, Wa[i * 128 + c],        a);
            bacc = fmaf(v, Wa[(35 + i) * 128 + c], bacc);
        }
        hsrc[(size_t)bid * 128 + c] = a;
        htgt[(size_t)bid * 128 + c] = bacc;
    } else {
        int d = bid - N_;                   // 0..1023
        float dd = (float)(d - 512);
        float acc = 0.f;
        #pragma unroll
        for (int q = 0; q < 8; ++q) {
            float fr = expf((float)(2 * q) * (-0.5756462732485115f)); // -ln(1e4)/16
            float ang = dd * fr;
            acc = fmaf(cosf(ang), Wa[(86 + q) * 128 + c], acc);
            acc = fmaf(sinf(ang), Wa[(94 + q) * 128 + c], acc);
        }
        ptab[(size_t)d * 128 + c] = acc;
    }
}

// ---------------- kernel 4: per-edge logits, two-phase (dedup scalar work per edge) ------------
// Phase A: lane owns one edge -> dist/valid/d + 16 rbf exps (once per edge, not per lane).
// Phase B: wave sweeps 64 edges; W_rbf columns live in 32 VGPRs; rbf via LDS broadcast.
__global__ __launch_bounds__(256) void logits_kernel(
    const float* __restrict__ trans, const int* __restrict__ srcArr,
    const float* __restrict__ hsrc, const float* __restrict__ htgt,
    const float* __restrict__ ptab, const float* __restrict__ Wa,
    const float* __restrict__ avec, float* __restrict__ logitsw)
{
    __shared__ float rbfS[4][64][20];   // pad 20 -> 16B-aligned rows, broadcast reads
    __shared__ int   srcS[4][64];
    __shared__ int   dS[4][64];         // d | (invalid << 16)
    __shared__ float lgS[4][512];       // staged logits for coalesced flush
    const int tid = threadIdx.x, wid = tid >> 6, lane = tid & 63;

    // W_alpha rbf-block columns (2 per lane) in registers: 32 VGPRs, zero LDS traffic in loop
    float2 wrb[16];
    #pragma unroll
    for (int j = 0; j < 16; ++j)
        wrb[j] = ((const float2*)(Wa + (70 + j) * 128))[lane];
    const float2 av = ((const float2*)avec)[lane];

    const int e0 = (blockIdx.x * 4 + wid) * 64;

    // ---- phase A ----
    {
        const int e   = e0 + lane;
        const int tgt = e / K_;
        int src = srcArr[e];
        src = (src < 0) ? 0 : ((src >= N_) ? (N_ - 1) : src);
        float vx = trans[src*3+0] - trans[tgt*3+0];
        float vy = trans[src*3+1] - trans[tgt*3+1];
        float vz = trans[src*3+2] - trans[tgt*3+2];
        float dist = sqrtf(vx*vx + vy*vy + vz*vz);
        bool valid = isfinite(dist) && (dist > 1e-3f);
        int d = src - tgt + 512;
        d = (d < 0) ? 0 : ((d > 1023) ? 1023 : d);
        srcS[wid][lane] = src;
        dS[wid][lane]   = d | (valid ? 0 : (1 << 16));
        #pragma unroll
        for (int j = 0; j < 16; ++j) {
            float tt = (dist - (float)j * (20.f/15.f)) * 0.8f;
            rbfS[wid][lane][j] = expf(-tt * tt);
        }
    }
    __syncthreads();

    // ---- phase B ----
    #pragma unroll 2
    for (int q = 0; q < 64; ++q) {
        const int e   = e0 + q;             // wave-uniform
        const int tgt = e / K_;
        const int src = srcS[wid][q];
        const int dm  = dS[wid][q];
        const int d   = dm & 0xFFFF;
        const bool valid = (dm >> 16) == 0;

        float2 hs = ((const float2*)(hsrc + (size_t)src * 128))[lane];
        float2 ht = ((const float2*)(htgt + (size_t)tgt * 128))[lane];
        float2 pt = ((const float2*)(ptab + (size_t)d   * 128))[lane];
        float acc0 = hs.x + ht.x + pt.x;
        float acc1 = hs.y + ht.y + pt.y;
        const float4* rp = (const float4*)(&rbfS[wid][q][0]);
        #pragma unroll
        for (int jj = 0; jj < 4; ++jj) {
            float4 rb = rp[jj];             // broadcast read (all lanes same addr)
            acc0 = fmaf(rb.x, wrb[4*jj+0].x, acc0); acc1 = fmaf(rb.x, wrb[4*jj+0].y, acc1);
            acc0 = fmaf(rb.y, wrb[4*jj+1].x, acc0); acc1 = fmaf(rb.y, wrb[4*jj+1].y, acc1);
            acc0 = fmaf(rb.z, wrb[4*jj+2].x, acc0); acc1 = fmaf(rb.z, wrb[4*jj+2].y, acc1);
            acc0 = fmaf(rb.w, wrb[4*jj+3].x, acc0); acc1 = fmaf(rb.w, wrb[4*jj+3].y, acc1);
        }
        float h0 = acc0 / (1.f + expf(-acc0));      // silu
        float h1 = acc1 / (1.f + expf(-acc1));
        float part = h0 * av.x + h1 * av.y;
        #pragma unroll
        for (int s = 1; s < 8; s <<= 1) part += __shfl_xor(part, s, 64);
        float lg = (part >= 0.f) ? part : 0.2f * part;
        if (!valid) lg = -1e9f;
        lg = (fabsf(lg) < 1e30f) ? lg : -1e9f;
        if ((lane & 7) == 0) lgS[wid][q * 8 + (lane >> 3)] = lg;
    }
    __syncthreads();
    // coalesced flush: 512 floats per wave = 2 float4 per lane
    {
        float4* dst = (float4*)(logitsw + (size_t)e0 * 8);
        const float4* srcp = (const float4*)lgS[wid];
        dst[lane]      = srcp[lane];
        dst[lane + 64] = srcp[lane + 64];
    }
}

// ---------------- kernel 5: fused softmax + alpha-weighted emb sum + W_v GEMM + epilogue ----------
__global__ __launch_bounds__(256) void agg_out_kernel(
    const float* __restrict__ emb, const int* __restrict__ srcArr,
    const float* __restrict__ logitsw,
    const float* __restrict__ Wv, const float* __restrict__ Wo,
    const float* __restrict__ Wg, const float* __restrict__ W2,
    const int* __restrict__ flag, void* __restrict__ outv)
{
    __shared__ float alp[240];          // [k][h]
    __shared__ int   srcs[K_];
    __shared__ float embS[K_ * 140];
    __shared__ float wsS[8 * 140];      // per-head weighted sums [h][r*35+cp]
    __shared__ float aggS[256];
    __shared__ float ybuf[128];
    __shared__ float gbuf[32];
    const int t = blockIdx.x, tid = threadIdx.x;
    const int obf = flag[0];

    if (tid < 240) alp[tid] = logitsw[(size_t)t * 240 + tid];
    if (tid < K_) {
        int s = srcArr[t * K_ + tid];
        srcs[tid] = (s < 0) ? 0 : ((s >= N_) ? (N_ - 1) : s);
    }
    __syncthreads();

    if (tid < 8) {
        float mx = -1e30f;
        #pragma unroll
        for (int k = 0; k < K_; ++k) mx = fmaxf(mx, alp[k*8 + tid]);
        float ex[K_]; float den = 0.f;
        #pragma unroll
        for (int k = 0; k < K_; ++k) {
            float l = alp[k*8 + tid];
            float e = (l > -1e8f) ? expf(l - mx) : 0.f;
            ex[k] = e; den += e;
        }
        float inv = 1.f / (den + 1e-9f);
        #pragma unroll
        for (int k = 0; k < K_; ++k) alp[k*8 + tid] = ex[k] * inv;
    }
    for (int v = tid; v < K_ * 140; v += 256) {
        int k = v / 140, rc = v - k * 140;
        embS[v] = emb[(size_t)srcs[k] * 140 + rc];
    }
    __syncthreads();

    for (int v = tid; v < 8 * 140; v += 256) {
        int h = v / 140, rc = v - h * 140;
        float s = 0.f;
        #pragma unroll 6
        for (int k = 0; k < K_; ++k) s = fmaf(alp[k*8 + h], embS[k*140 + rc], s);
        wsS[v] = s;
    }
    __syncthreads();

    {
        const int r = tid >> 6, cc = tid & 63;
        const float* wp = wsS + (cc >> 3) * 140 + r * 35;
        float acc = 0.f;
        #pragma unroll 5
        for (int cp = 0; cp < 35; ++cp) acc = fmaf(wp[cp], Wv[cp * 64 + cc], acc);
        aggS[tid] = acc;
    }
    __syncthreads();

    if (tid < 128) {
        int rr = tid >> 5, o = tid & 31;
        float y = 0.f;
        #pragma unroll
        for (int c = 0; c < 64; ++c) y = fmaf(aggS[rr * 64 + c], Wo[c * 32 + o], y);
        ybuf[tid] = y;
    }
    __syncthreads();
    if (tid < 32) {
        float g = 0.f;
        #pragma unroll
        for (int o = 0; o < 32; ++o) g = fmaf(ybuf[o], Wg[o * 32 + tid], g);
        gbuf[tid] = g / (1.f + expf(-g));
    }
    __syncthreads();
    if (tid < 128) {
        int rr = tid >> 5, hh = tid & 31;
        float o = 0.f;
        #pragma unroll
        for (int g = 0; g < 32; ++g) o = fmaf(ybuf[rr * 32 + g] * gbuf[g], W2[g * 32 + hh], o);
        o = (fabsf(o) < 1e30f) ? o : 0.f;
        size_t idx = (size_t)t * 128 + tid;
        if (obf) ((u16*)outv)[idx] = f2bf(o);
        else     ((float*)outv)[idx] = o;
    }
}

extern "C" void kernel_launch(void* const* d_in, const int* in_sizes, int n_in,
                              void* d_out, int out_size, void* d_ws, size_t ws_size,
                              hipStream_t stream)
{
    const void* rots         = d_in[0];
    const void* trans        = d_in[1];
    const void* node_emb     = d_in[2];
    /* d_in[3] = batch (unused; chains contiguous) */
    const void* x_mask       = d_in[4];
    const void* noising_mask = d_in[5];
    const void* Wa           = d_in[6];
    const void* avec         = d_in[7];
    const void* Wv           = d_in[8];
    const void* Wo           = d_in[9];
    const void* Wg           = d_in[10];
    const void* W2           = d_in[11];

    char* ws = (char*)d_ws;
    int*   flag    = (int*)  (ws + 0);            // 64
    float* c_trans = (float*)(ws + 64);           //    98,304
    float* c_rots  = (float*)(ws + 98368);        //   294,912
    float* c_node  = (float*)(ws + 393280);       // 4,194,304
    float* c_Wa    = (float*)(ws + 4587584);      //    52,224
    float* c_av    = (float*)(ws + 4639808);      //       512
    float* c_Wv    = (float*)(ws + 4640320);      //     8,960
    float* c_Wo    = (float*)(ws + 4649280);      //     8,192
    float* c_Wg    = (float*)(ws + 4657472);      //     4,096
    float* c_W2    = (float*)(ws + 4661568);      //     4,096
    float* c_edit  = (float*)(ws + 4665664);      //    32,768
    int*   srcArr  = (int*)  (ws + 4698432);      //   983,040
    float* emb     = (float*)(ws + 5681472);      // 4,587,520
    float* hsrc    = (float*)(ws + 10268992);     // 4,194,304
    float* htgt    = (float*)(ws + 14463296);     // 4,194,304
    float* ptab    = (float*)(ws + 18657600);     //   524,288
    float* logitsw = (float*)(ws + 19181888);     // 7,864,320  (end ~27.0 MB)

    hipLaunchKernelGGL(detect_kernel, dim3(1), dim3(64), 0, stream,
                       (const u16*)trans, (const u32*)x_mask, flag);
    hipLaunchKernelGGL(conv_kernel, dim3((T_EDIT + 255) / 256), dim3(256), 0, stream,
                       rots, trans, node_emb, x_mask, noising_mask,
                       Wa, avec, Wv, Wo, Wg, W2, flag,
                       c_node, c_trans, c_rots, c_Wa, c_av, c_Wv, c_Wo, c_Wg, c_W2, c_edit);
    hipLaunchKernelGGL(knn_kernel,   dim3(N_/4),             dim3(256), 0, stream, c_trans, srcArr);
    hipLaunchKernelGGL(emb_kernel,   dim3((N_*140+255)/256), dim3(256), 0, stream, c_rots, c_node, c_edit, emb);
    hipLaunchKernelGGL(prep_kernel,  dim3(N_ + 1024),        dim3(128), 0, stream, emb, c_Wa, hsrc, htgt, ptab);
    hipLaunchKernelGGL(logits_kernel,dim3(E_/256),           dim3(256), 0, stream,
                       c_trans, srcArr, hsrc, htgt, ptab, c_Wa, c_av, logitsw);
    hipLaunchKernelGGL(agg_out_kernel, dim3(N_),             dim3(256), 0, stream,
                       emb, srcArr, logitsw, c_Wv, c_Wo, c_Wg, c_W2, flag, d_out);
}

// Round 7
// 268.321 us; speedup vs baseline: 5.6247x; 1.0178x over previous
//
#include <hip/hip_runtime.h>
#include <cstdint>

#define B_ 16
#define L_ 512
#define N_ 8192
#define K_ 30
#define E_ (N_*K_)
#define H_ 32
#define C_ 35

typedef uint16_t u16;
typedef uint32_t u32;

// adaptive float load: bf16 (u16<<16) or fp32
static __device__ __forceinline__ float ldf(const void* p, int i, int bf) {
    return bf ? __uint_as_float(((u32)((const u16*)p)[i]) << 16)
              : ((const float*)p)[i];
}
// mask load: mode 0 = u8 bool, 1 = int32, 2 = int64 (little-endian low word)
static __device__ __forceinline__ int ldmask(const void* p, int i, int mode) {
    if (mode == 0) return ((const unsigned char*)p)[i] != 0;
    if (mode == 2) return ((const u32*)p)[2*i] != 0;
    return ((const u32*)p)[i] != 0;
}
// f32 -> bf16 RNE
static __device__ __forceinline__ u16 f2bf(float f) {
    u32 x = __float_as_uint(f);
    u32 r = x + 0x7FFFu + ((x >> 16) & 1u);
    return (u16)(r >> 16);
}

// ---------------- kernel 0: dtype detection ----------------
__global__ void detect_kernel(const u16* __restrict__ tr, const u32* __restrict__ xm,
                              int* __restrict__ flag)
{
    int lane = threadIdx.x;
    int cnt = 0;
    for (int i = lane; i < 256; i += 64) {
        u16 v = tr[2 * i];
        int e = (v >> 7) & 0xFF;
        if ((e >= 100 && e <= 141) || (v & 0x7FFFu) == 0) cnt++;
    }
    int anyBig = 0, oddNZ = 0;
    for (int i = lane; i < 1024; i += 64) {
        u32 w = xm[i];
        if (w & ~1u) anyBig = 1;
        if ((i & 1) && w) oddNZ = 1;
    }
    #pragma unroll
    for (int d = 1; d < 64; d <<= 1) {
        cnt    += __shfl_xor(cnt, d, 64);
        anyBig |= __shfl_xor(anyBig, d, 64);
        oddNZ  |= __shfl_xor(oddNZ, d, 64);
    }
    if (lane == 0) {
        flag[0] = (cnt >= 192) ? 1 : 0;
        flag[1] = anyBig ? 0 : (oddNZ ? 1 : 2);
    }
}

// ---------------- kernel 0.5: canonicalize all inputs to f32 ----------------
#define T_NODE  1048576
#define T_TRANS 1073152
#define T_ROTS  1146880
#define T_WA    1159936
#define T_AV    1160064
#define T_WV    1162304
#define T_WO    1164352
#define T_WG    1165376
#define T_W2    1166400
#define T_EDIT  1174592

__global__ void conv_kernel(const void* rots, const void* trans, const void* node,
                            const void* xm, const void* nm,
                            const void* Wa, const void* av, const void* Wv,
                            const void* Wo, const void* Wg, const void* W2,
                            const int* __restrict__ flag,
                            float* c_node, float* c_trans, float* c_rots,
                            float* c_Wa, float* c_av, float* c_Wv,
                            float* c_Wo, float* c_Wg, float* c_W2, float* c_edit)
{
    int gid = blockIdx.x * 256 + threadIdx.x;
    if (gid >= T_EDIT) return;
    int bf = flag[0], mm = flag[1];
    if      (gid < T_NODE)  c_node [gid]           = ldf(node,  gid,            bf);
    else if (gid < T_TRANS) c_trans[gid - T_NODE]  = ldf(trans, gid - T_NODE,   bf);
    else if (gid < T_ROTS)  c_rots [gid - T_TRANS] = ldf(rots,  gid - T_TRANS,  bf);
    else if (gid < T_WA)    c_Wa   [gid - T_ROTS]  = ldf(Wa,    gid - T_ROTS,   bf);
    else if (gid < T_AV)    c_av   [gid - T_WA]    = ldf(av,    gid - T_WA,     bf);
    else if (gid < T_WV)    c_Wv   [gid - T_AV]    = ldf(Wv,    gid - T_AV,     bf);
    else if (gid < T_WO)    c_Wo   [gid - T_WV]    = ldf(Wo,    gid - T_WV,     bf);
    else if (gid < T_WG)    c_Wg   [gid - T_WO]    = ldf(Wg,    gid - T_WO,     bf);
    else if (gid < T_W2)    c_W2   [gid - T_WG]    = ldf(W2,    gid - T_WG,     bf);
    else {
        int n = gid - T_W2;
        c_edit[n] = (ldmask(nm, n, mm) && !ldmask(xm, n, mm)) ? 1.f : 0.f;
    }
}

// ---------------- kernel 1: per-chain kNN — one wave per target, barrier-free selection ----------
__global__ __launch_bounds__(256) void knn_kernel(const float* __restrict__ trans,
                                                  int* __restrict__ srcArr)
{
    __shared__ float xs[L_], ys[L_], zs[L_];
    const int tid  = threadIdx.x;
    const int t0   = blockIdx.x * 4;        // 4 targets per block, same chain (512 % 4 == 0)
    const int base = (t0 >> 9) << 9;        // chain base node

    for (int i = tid; i < L_; i += 256) {
        xs[i] = trans[(base + i) * 3 + 0];
        ys[i] = trans[(base + i) * 3 + 1];
        zs[i] = trans[(base + i) * 3 + 2];
    }
    __syncthreads();

    const int wid = tid >> 6, lane = tid & 63;
    const int t = t0 + wid;
    const int l = t & 511;
    const float tx = xs[l], ty = ys[l], tz = zs[l];

    float cd[8];
    #pragma unroll
    for (int i = 0; i < 8; ++i) {
        int j = lane + (i << 6);
        // match numpy: ((dx*dx + dy*dy) + dz*dz), no FMA contraction
        float dx = __fsub_rn(tx, xs[j]);
        float dy = __fsub_rn(ty, ys[j]);
        float dz = __fsub_rn(tz, zs[j]);
        float d2 = __fadd_rn(__fadd_rn(__fmul_rn(dx, dx), __fmul_rn(dy, dy)), __fmul_rn(dz, dz));
        if (j == l) d2 = __fadd_rn(d2, 1e9f);   // exclude self
        cd[i] = d2;
    }

    int myres = 0;
    for (int k = 0; k < K_; ++k) {
        float lm = cd[0]; int ls = 0;
        #pragma unroll
        for (int i = 1; i < 8; ++i)
            if (cd[i] < lm) { lm = cd[i]; ls = i; }
        float md = lm;
        int   mi = lane + (ls << 6);
        #pragma unroll
        for (int d = 1; d < 64; d <<= 1) {
            float od = __shfl_xor(md, d, 64);
            int   oi = __shfl_xor(mi, d, 64);
            if (od < md || (od == md && oi < mi)) { md = od; mi = oi; }
        }
        if (k == lane) myres = mi;
        if ((mi & 63) == lane) {
            int ws = mi >> 6;
            #pragma unroll
            for (int i = 0; i < 8; ++i)
                if (ws == i) cd[i] = 3.0e38f;
        }
    }
    if (lane < K_) srcArr[t * K_ + lane] = base + myres;
}

// ---------------- kernel 2: fused node embedding [N,4,35] f32 ----------------
__constant__ float cBB[9] = {-0.525f, 1.363f, 0.f,  0.f, 0.f, 0.f,  1.526f, 0.f, 0.f};

__global__ void emb_kernel(const float* __restrict__ rots,
                           const float* __restrict__ node_emb,
                           const float* __restrict__ edit,
                           float* __restrict__ emb)
{
    int gid = blockIdx.x * blockDim.x + threadIdx.x;
    if (gid >= N_ * 140) return;
    int n = gid / 140, s = gid - n * 140;
    int r = s / 35,   c = s - r * 35;
    float v;
    if (c < H_) {
        v = node_emb[n * 128 + r * 32 + c];
    } else if (r == 0) {
        v = (c == 34) ? edit[n] : 0.f;
    } else {
        int i = r - 1, a = c - 32;
        v = rots[n*9 + i*3 + 0] * cBB[a*3 + 0]
          + rots[n*9 + i*3 + 1] * cBB[a*3 + 1]
          + rots[n*9 + i*3 + 2] * cBB[a*3 + 2];
    }
    emb[gid] = v;
}

// ---------------- kernel 3: per-node hidden contributions + pos-emb table ----------------
__global__ __launch_bounds__(128) void prep_kernel(const float* __restrict__ emb,
                                                   const float* __restrict__ Wa,
                                                   float* __restrict__ hsrc,
                                                   float* __restrict__ htgt,
                                                   float* __restrict__ ptab)
{
    const int bid = blockIdx.x, c = threadIdx.x;
    if (bid < N_) {
        __shared__ float e0[35];
        if (c < 35) e0[c] = emb[(size_t)bid * 140 + c];
        __syncthreads();
        float a = 0.f, bacc = 0.f;
        #pragma unroll 5
        for (int i = 0; i < 35; ++i) {
            float v = e0[i];
            a    = fmaf(v, Wa[i * 128 + c],        a);
            bacc = fmaf(v, Wa[(35 + i) * 128 + c], bacc);
        }
        hsrc[(size_t)bid * 128 + c] = a;
        htgt[(size_t)bid * 128 + c] = bacc;
    } else {
        int d = bid - N_;                   // 0..1023
        float dd = (float)(d - 512);
        float acc = 0.f;
        #pragma unroll
        for (int q = 0; q < 8; ++q) {
            float fr = expf((float)(2 * q) * (-0.5756462732485115f)); // -ln(1e4)/16
            float ang = dd * fr;
            acc = fmaf(cosf(ang), Wa[(86 + q) * 128 + c], acc);
            acc = fmaf(sinf(ang), Wa[(94 + q) * 128 + c], acc);
        }
        ptab[(size_t)d * 128 + c] = acc;
    }
}

// ---------------- kernel 4: per-edge logits, two-phase (dedup scalar work per edge) ------------
__global__ __launch_bounds__(256) void logits_kernel(
    const float* __restrict__ trans, const int* __restrict__ srcArr,
    const float* __restrict__ hsrc, const float* __restrict__ htgt,
    const float* __restrict__ ptab, const float* __restrict__ Wa,
    const float* __restrict__ avec, float* __restrict__ logitsw)
{
    __shared__ float rbfS[4][64][20];   // pad 20 -> 16B-aligned rows, broadcast reads
    __shared__ int   srcS[4][64];
    __shared__ int   dS[4][64];         // d | (invalid << 16)
    __shared__ float lgS[4][512];       // staged logits for coalesced flush
    const int tid = threadIdx.x, wid = tid >> 6, lane = tid & 63;

    float2 wrb[16];
    #pragma unroll
    for (int j = 0; j < 16; ++j)
        wrb[j] = ((const float2*)(Wa + (70 + j) * 128))[lane];
    const float2 av = ((const float2*)avec)[lane];

    const int e0 = (blockIdx.x * 4 + wid) * 64;

    // ---- phase A ----
    {
        const int e   = e0 + lane;
        const int tgt = e / K_;
        int src = srcArr[e];
        src = (src < 0) ? 0 : ((src >= N_) ? (N_ - 1) : src);
        float vx = trans[src*3+0] - trans[tgt*3+0];
        float vy = trans[src*3+1] - trans[tgt*3+1];
        float vz = trans[src*3+2] - trans[tgt*3+2];
        float dist = sqrtf(vx*vx + vy*vy + vz*vz);
        bool valid = isfinite(dist) && (dist > 1e-3f);
        int d = src - tgt + 512;
        d = (d < 0) ? 0 : ((d > 1023) ? 1023 : d);
        srcS[wid][lane] = src;
        dS[wid][lane]   = d | (valid ? 0 : (1 << 16));
        #pragma unroll
        for (int j = 0; j < 16; ++j) {
            float tt = (dist - (float)j * (20.f/15.f)) * 0.8f;
            rbfS[wid][lane][j] = expf(-tt * tt);
        }
    }
    __syncthreads();

    // ---- phase B ----
    #pragma unroll 2
    for (int q = 0; q < 64; ++q) {
        const int e   = e0 + q;             // wave-uniform
        const int tgt = e / K_;
        const int src = srcS[wid][q];
        const int dm  = dS[wid][q];
        const int d   = dm & 0xFFFF;
        const bool valid = (dm >> 16) == 0;

        float2 hs = ((const float2*)(hsrc + (size_t)src * 128))[lane];
        float2 ht = ((const float2*)(htgt + (size_t)tgt * 128))[lane];
        float2 pt = ((const float2*)(ptab + (size_t)d   * 128))[lane];
        float acc0 = hs.x + ht.x + pt.x;
        float acc1 = hs.y + ht.y + pt.y;
        const float4* rp = (const float4*)(&rbfS[wid][q][0]);
        #pragma unroll
        for (int jj = 0; jj < 4; ++jj) {
            float4 rb = rp[jj];             // broadcast read (all lanes same addr)
            acc0 = fmaf(rb.x, wrb[4*jj+0].x, acc0); acc1 = fmaf(rb.x, wrb[4*jj+0].y, acc1);
            acc0 = fmaf(rb.y, wrb[4*jj+1].x, acc0); acc1 = fmaf(rb.y, wrb[4*jj+1].y, acc1);
            acc0 = fmaf(rb.z, wrb[4*jj+2].x, acc0); acc1 = fmaf(rb.z, wrb[4*jj+2].y, acc1);
            acc0 = fmaf(rb.w, wrb[4*jj+3].x, acc0); acc1 = fmaf(rb.w, wrb[4*jj+3].y, acc1);
        }
        float h0 = acc0 / (1.f + expf(-acc0));      // silu
        float h1 = acc1 / (1.f + expf(-acc1));
        float part = h0 * av.x + h1 * av.y;
        #pragma unroll
        for (int s = 1; s < 8; s <<= 1) part += __shfl_xor(part, s, 64);
        float lg = (part >= 0.f) ? part : 0.2f * part;
        if (!valid) lg = -1e9f;
        lg = (fabsf(lg) < 1e30f) ? lg : -1e9f;
        if ((lane & 7) == 0) lgS[wid][q * 8 + (lane >> 3)] = lg;
    }
    __syncthreads();
    {
        float4* dst = (float4*)(logitsw + (size_t)e0 * 8);
        const float4* srcp = (const float4*)lgS[wid];
        dst[lane]      = srcp[lane];
        dst[lane + 64] = srcp[lane + 64];
    }
}

// ---------------- kernel 4.5: per-node value matrix V[n] = emb[n] (4x35) @ Wv (35x64) ----------
__global__ __launch_bounds__(256) void vcompute_kernel(const float* __restrict__ emb,
                                                       const float* __restrict__ Wv,
                                                       float* __restrict__ V)
{
    __shared__ float e[140];
    const int n = blockIdx.x, tid = threadIdx.x;
    if (tid < 140) e[tid] = emb[(size_t)n * 140 + tid];
    __syncthreads();
    const int r = tid >> 6, cc = tid & 63;
    const float* er = e + r * 35;           // wave-uniform base -> broadcast reads
    float acc = 0.f;
    #pragma unroll 5
    for (int cp = 0; cp < 35; ++cp) acc = fmaf(er[cp], Wv[cp * 64 + cc], acc);
    V[(size_t)n * 256 + tid] = acc;
}

// ---------------- kernel 5: softmax (in-reg) + alpha-weighted V sum + epilogue -----------------
// agg[t][r][cc] = sum_k alpha[k][cc>>3] * V[src_k][r][cc]   (rotation cancels, Wv per node)
__global__ __launch_bounds__(256) void agg_out_kernel(
    const float* __restrict__ V, const int* __restrict__ srcArr,
    const float* __restrict__ logitsw,
    const float* __restrict__ Wo, const float* __restrict__ Wg,
    const float* __restrict__ W2,
    const int* __restrict__ flag, void* __restrict__ outv)
{
    __shared__ int   srcs[K_];
    __shared__ float aggS[256];
    __shared__ float ybuf[128];
    __shared__ float gbuf[32];
    const int bid = blockIdx.x;
    const int t   = ((bid & 7) << 10) | (bid >> 3);   // XCD-locality swizzle (2 chains per XCD)
    const int tid = threadIdx.x;
    const int obf = flag[0];
    const int cc = tid & 63, r = tid >> 6, h = cc >> 3;

    if (tid < K_) {
        int s = srcArr[t * K_ + tid];
        srcs[tid] = (s < 0) ? 0 : ((s >= N_) ? (N_ - 1) : s);
    }

    // per-thread softmax weights for head h (dup x32/head; VALU-cheap, no barrier needed)
    const float* lp = logitsw + (size_t)t * 240 + h;
    float lg[K_];
    float mx = -1e30f;
    #pragma unroll
    for (int k = 0; k < K_; ++k) { lg[k] = lp[k * 8]; mx = fmaxf(mx, lg[k]); }
    float den = 0.f;
    #pragma unroll
    for (int k = 0; k < K_; ++k) {
        float e = (lg[k] > -1e8f) ? expf(lg[k] - mx) : 0.f;
        lg[k] = e; den += e;
    }
    const float inv = 1.f / (den + 1e-9f);
    __syncthreads();

    const int off = (r << 6) | cc;
    float acc = 0.f;
    #pragma unroll 6
    for (int k = 0; k < K_; ++k)
        acc = fmaf(lg[k], V[(size_t)srcs[k] * 256 + off], acc);
    aggS[tid] = acc * inv;
    __syncthreads();

    // epilogue: y = agg @ W_o ; gate = silu(y0 @ W_g) ; out = (y*gate) @ W_2
    if (tid < 128) {
        int rr = tid >> 5, o = tid & 31;
        float y = 0.f;
        #pragma unroll
        for (int c = 0; c < 64; ++c) y = fmaf(aggS[rr * 64 + c], Wo[c * 32 + o], y);
        ybuf[tid] = y;
    }
    __syncthreads();
    if (tid < 32) {
        float g = 0.f;
        #pragma unroll
        for (int o = 0; o < 32; ++o) g = fmaf(ybuf[o], Wg[o * 32 + tid], g);
        gbuf[tid] = g / (1.f + expf(-g));
    }
    __syncthreads();
    if (tid < 128) {
        int rr = tid >> 5, hh = tid & 31;
        float o = 0.f;
        #pragma unroll
        for (int g = 0; g < 32; ++g) o = fmaf(ybuf[rr * 32 + g] * gbuf[g], W2[g * 32 + hh], o);
        o = (fabsf(o) < 1e30f) ? o : 0.f;
        size_t idx = (size_t)t * 128 + tid;
        if (obf) ((u16*)outv)[idx] = f2bf(o);
        else     ((float*)outv)[idx] = o;
    }
}

extern "C" void kernel_launch(void* const* d_in, const int* in_sizes, int n_in,
                              void* d_out, int out_size, void* d_ws, size_t ws_size,
                              hipStream_t stream)
{
    const void* rots         = d_in[0];
    const void* trans        = d_in[1];
    const void* node_emb     = d_in[2];
    /* d_in[3] = batch (unused; chains contiguous) */
    const void* x_mask       = d_in[4];
    const void* noising_mask = d_in[5];
    const void* Wa           = d_in[6];
    const void* avec         = d_in[7];
    const void* Wv           = d_in[8];
    const void* Wo           = d_in[9];
    const void* Wg           = d_in[10];
    const void* W2           = d_in[11];

    char* ws = (char*)d_ws;
    int*   flag    = (int*)  (ws + 0);            // 64
    float* c_trans = (float*)(ws + 64);           //    98,304
    float* c_rots  = (float*)(ws + 98368);        //   294,912
    float* c_node  = (float*)(ws + 393280);       // 4,194,304
    float* c_Wa    = (float*)(ws + 4587584);      //    52,224
    float* c_av    = (float*)(ws + 4639808);      //       512
    float* c_Wv    = (float*)(ws + 4640320);      //     8,960
    float* c_Wo    = (float*)(ws + 4649280);      //     8,192
    float* c_Wg    = (float*)(ws + 4657472);      //     4,096
    float* c_W2    = (float*)(ws + 4661568);      //     4,096
    float* c_edit  = (float*)(ws + 4665664);      //    32,768
    int*   srcArr  = (int*)  (ws + 4698432);      //   983,040
    float* emb     = (float*)(ws + 5681472);      // 4,587,520
    float* hsrc    = (float*)(ws + 10268992);     // 4,194,304  } V (8,388,608) overlays hsrc+htgt
    float* htgt    = (float*)(ws + 14463296);     // 4,194,304  } after logits_kernel is done
    float* ptab    = (float*)(ws + 18657600);     //   524,288
    float* logitsw = (float*)(ws + 19181888);     // 7,864,320  (end ~27.0 MB)
    float* V       = (float*)(ws + 10268992);

    hipLaunchKernelGGL(detect_kernel, dim3(1), dim3(64), 0, stream,
                       (const u16*)trans, (const u32*)x_mask, flag);
    hipLaunchKernelGGL(conv_kernel, dim3((T_EDIT + 255) / 256), dim3(256), 0, stream,
                       rots, trans, node_emb, x_mask, noising_mask,
                       Wa, avec, Wv, Wo, Wg, W2, flag,
                       c_node, c_trans, c_rots, c_Wa, c_av, c_Wv, c_Wo, c_Wg, c_W2, c_edit);
    hipLaunchKernelGGL(knn_kernel,   dim3(N_/4),             dim3(256), 0, stream, c_trans, srcArr);
    hipLaunchKernelGGL(emb_kernel,   dim3((N_*140+255)/256), dim3(256), 0, stream, c_rots, c_node, c_edit, emb);
    hipLaunchKernelGGL(prep_kernel,  dim3(N_ + 1024),        dim3(128), 0, stream, emb, c_Wa, hsrc, htgt, ptab);
    hipLaunchKernelGGL(logits_kernel,dim3(E_/256),           dim3(256), 0, stream,
                       c_trans, srcArr, hsrc, htgt, ptab, c_Wa, c_av, logitsw);
    hipLaunchKernelGGL(vcompute_kernel, dim3(N_),            dim3(256), 0, stream, emb, c_Wv, V);
    hipLaunchKernelGGL(agg_out_kernel,  dim3(N_),            dim3(256), 0, stream,
                       V, srcArr, logitsw, c_Wo, c_Wg, c_W2, flag, d_out);
}

// Round 8
// 231.758 us; speedup vs baseline: 6.5120x; 1.1578x over previous
//
#include <hip/hip_runtime.h>
#include <cstdint>

#define B_ 16
#define L_ 512
#define N_ 8192
#define K_ 30
#define E_ (N_*K_)
#define H_ 32
#define C_ 35

typedef uint16_t u16;
typedef uint32_t u32;

// adaptive float load: bf16 (u16<<16) or fp32
static __device__ __forceinline__ float ldf(const void* p, int i, int bf) {
    return bf ? __uint_as_float(((u32)((const u16*)p)[i]) << 16)
              : ((const float*)p)[i];
}
// mask load: mode 0 = u8 bool, 1 = int32, 2 = int64 (little-endian low word)
static __device__ __forceinline__ int ldmask(const void* p, int i, int mode) {
    if (mode == 0) return ((const unsigned char*)p)[i] != 0;
    if (mode == 2) return ((const u32*)p)[2*i] != 0;
    return ((const u32*)p)[i] != 0;
}
// f32 -> bf16 RNE
static __device__ __forceinline__ u16 f2bf(float f) {
    u32 x = __float_as_uint(f);
    u32 r = x + 0x7FFFu + ((x >> 16) & 1u);
    return (u16)(r >> 16);
}
// fast silu: x * rcp(1 + exp(-x))  (~1e-7 rel err, threshold is 4.3e-3)
static __device__ __forceinline__ float fsilu(float x) {
    return x * __builtin_amdgcn_rcpf(1.f + __expf(-x));
}

// ---------------- kernel 0: dtype detection ----------------
__global__ void detect_kernel(const u16* __restrict__ tr, const u32* __restrict__ xm,
                              int* __restrict__ flag)
{
    int lane = threadIdx.x;
    int cnt = 0;
    for (int i = lane; i < 256; i += 64) {
        u16 v = tr[2 * i];
        int e = (v >> 7) & 0xFF;
        if ((e >= 100 && e <= 141) || (v & 0x7FFFu) == 0) cnt++;
    }
    int anyBig = 0, oddNZ = 0;
    for (int i = lane; i < 1024; i += 64) {
        u32 w = xm[i];
        if (w & ~1u) anyBig = 1;
        if ((i & 1) && w) oddNZ = 1;
    }
    #pragma unroll
    for (int d = 1; d < 64; d <<= 1) {
        cnt    += __shfl_xor(cnt, d, 64);
        anyBig |= __shfl_xor(anyBig, d, 64);
        oddNZ  |= __shfl_xor(oddNZ, d, 64);
    }
    if (lane == 0) {
        flag[0] = (cnt >= 192) ? 1 : 0;
        flag[1] = anyBig ? 0 : (oddNZ ? 1 : 2);
    }
}

// ---------------- kernel 0.5: canonicalize trans + weights to f32 (small now) ----------------
#define U_TRANS 24576
#define U_WA    37632
#define U_AV    37760
#define U_WV    40000
#define U_WO    42048
#define U_WG    43072
#define U_W2    44096

__global__ void conv_kernel(const void* trans,
                            const void* Wa, const void* av, const void* Wv,
                            const void* Wo, const void* Wg, const void* W2,
                            const int* __restrict__ flag,
                            float* c_trans, float* c_Wa, float* c_av, float* c_Wv,
                            float* c_Wo, float* c_Wg, float* c_W2)
{
    int gid = blockIdx.x * 256 + threadIdx.x;
    if (gid >= U_W2) return;
    int bf = flag[0];
    if      (gid < U_TRANS) c_trans[gid]           = ldf(trans, gid,           bf);
    else if (gid < U_WA)    c_Wa   [gid - U_TRANS] = ldf(Wa,    gid - U_TRANS, bf);
    else if (gid < U_AV)    c_av   [gid - U_WA]    = ldf(av,    gid - U_WA,    bf);
    else if (gid < U_WV)    c_Wv   [gid - U_AV]    = ldf(Wv,    gid - U_AV,    bf);
    else if (gid < U_WO)    c_Wo   [gid - U_WV]    = ldf(Wo,    gid - U_WV,    bf);
    else if (gid < U_WG)    c_Wg   [gid - U_WO]    = ldf(Wg,    gid - U_WO,    bf);
    else                    c_W2   [gid - U_WG]    = ldf(W2,    gid - U_WG,    bf);
}

// ---------------- kernel 1: per-chain kNN — one wave per target, barrier-free selection ----------
__global__ __launch_bounds__(256) void knn_kernel(const float* __restrict__ trans,
                                                  int* __restrict__ srcArr)
{
    __shared__ float xs[L_], ys[L_], zs[L_];
    const int tid  = threadIdx.x;
    const int t0   = blockIdx.x * 4;        // 4 targets per block, same chain (512 % 4 == 0)
    const int base = (t0 >> 9) << 9;        // chain base node

    for (int i = tid; i < L_; i += 256) {
        xs[i] = trans[(base + i) * 3 + 0];
        ys[i] = trans[(base + i) * 3 + 1];
        zs[i] = trans[(base + i) * 3 + 2];
    }
    __syncthreads();

    const int wid = tid >> 6, lane = tid & 63;
    const int t = t0 + wid;
    const int l = t & 511;
    const float tx = xs[l], ty = ys[l], tz = zs[l];

    float cd[8];
    #pragma unroll
    for (int i = 0; i < 8; ++i) {
        int j = lane + (i << 6);
        // match numpy: ((dx*dx + dy*dy) + dz*dz), no FMA contraction
        float dx = __fsub_rn(tx, xs[j]);
        float dy = __fsub_rn(ty, ys[j]);
        float dz = __fsub_rn(tz, zs[j]);
        float d2 = __fadd_rn(__fadd_rn(__fmul_rn(dx, dx), __fmul_rn(dy, dy)), __fmul_rn(dz, dz));
        if (j == l) d2 = __fadd_rn(d2, 1e9f);   // exclude self
        cd[i] = d2;
    }

    int myres = 0;
    for (int k = 0; k < K_; ++k) {
        float lm = cd[0]; int ls = 0;
        #pragma unroll
        for (int i = 1; i < 8; ++i)
            if (cd[i] < lm) { lm = cd[i]; ls = i; }
        float md = lm;
        int   mi = lane + (ls << 6);
        #pragma unroll
        for (int d = 1; d < 64; d <<= 1) {
            float od = __shfl_xor(md, d, 64);
            int   oi = __shfl_xor(mi, d, 64);
            if (od < md || (od == md && oi < mi)) { md = od; mi = oi; }
        }
        if (k == lane) myres = mi;
        if ((mi & 63) == lane) {
            int ws = mi >> 6;
            #pragma unroll
            for (int i = 0; i < 8; ++i)
                if (ws == i) cd[i] = 3.0e38f;
        }
    }
    if (lane < K_) srcArr[t * K_ + lane] = base + myres;
}

// ---------------- kernel 2: fused node pipeline: emb(LDS) -> hsrc/htgt, V ; ptab tail -----------
__constant__ float cBB[9] = {-0.525f, 1.363f, 0.f,  0.f, 0.f, 0.f,  1.526f, 0.f, 0.f};

__global__ __launch_bounds__(256) void node_kernel(
    const void* __restrict__ rots, const void* __restrict__ node,
    const void* __restrict__ xm, const void* __restrict__ nm,
    const int* __restrict__ flag,
    const float* __restrict__ Wa, const float* __restrict__ Wv,
    float* __restrict__ hsrc, float* __restrict__ htgt,
    float* __restrict__ ptab, float* __restrict__ V)
{
    const int bid = blockIdx.x, tid = threadIdx.x;
    if (bid >= N_) {                        // pos-emb table rows
        int d = bid - N_;
        if (tid < 128) {
            float dd = (float)(d - 512);
            float acc = 0.f;
            #pragma unroll
            for (int q = 0; q < 8; ++q) {
                float fr = expf((float)(2 * q) * (-0.5756462732485115f)); // -ln(1e4)/16
                float ang = dd * fr;
                acc = fmaf(cosf(ang), Wa[(86 + q) * 128 + tid], acc);
                acc = fmaf(sinf(ang), Wa[(94 + q) * 128 + tid], acc);
            }
            ptab[(size_t)d * 128 + tid] = acc;
        }
        return;
    }
    __shared__ float e[140];
    const int bf = flag[0], mm = flag[1];
    if (tid < 140) {
        int r = tid / 35, c = tid - r * 35;
        float v;
        if (c < H_) {
            v = ldf(node, bid * 128 + r * 32 + c, bf);
        } else if (r == 0) {
            v = (c == 34) ? ((ldmask(nm, bid, mm) && !ldmask(xm, bid, mm)) ? 1.f : 0.f) : 0.f;
        } else {
            int i = r - 1, a = c - 32;
            v = ldf(rots, bid*9 + i*3 + 0, bf) * cBB[a*3 + 0]
              + ldf(rots, bid*9 + i*3 + 1, bf) * cBB[a*3 + 1]
              + ldf(rots, bid*9 + i*3 + 2, bf) * cBB[a*3 + 2];
        }
        e[tid] = v;
    }
    __syncthreads();
    if (tid < 128) {                        // hsrc/htgt GEMVs over l=0 row
        float a = 0.f, b = 0.f;
        #pragma unroll 5
        for (int i = 0; i < 35; ++i) {
            float v = e[i];
            a = fmaf(v, Wa[i * 128 + tid],        a);
            b = fmaf(v, Wa[(35 + i) * 128 + tid], b);
        }
        hsrc[(size_t)bid * 128 + tid] = a;
        htgt[(size_t)bid * 128 + tid] = b;
    }
    {                                       // V[n] = emb[n] (4x35) @ Wv (35x64)
        int r = tid >> 6, cc = tid & 63;
        const float* er = e + r * 35;       // wave-uniform base -> LDS broadcast
        float acc = 0.f;
        #pragma unroll 5
        for (int cp = 0; cp < 35; ++cp) acc = fmaf(er[cp], Wv[cp * 64 + cc], acc);
        V[(size_t)bid * 256 + tid] = acc;
    }
}

// ---------------- kernel 3: per-edge logits, two-phase, 32 edges/wave (occupancy) ---------------
__global__ __launch_bounds__(128) void logits_kernel(
    const float* __restrict__ trans, const int* __restrict__ srcArr,
    const float* __restrict__ hsrc, const float* __restrict__ htgt,
    const float* __restrict__ ptab, const float* __restrict__ Wa,
    const float* __restrict__ avec, float* __restrict__ logitsw)
{
    __shared__ float rbfS[2][32][20];   // pad 20 -> float4 rows
    __shared__ int   srcS[2][32];
    __shared__ int   tgtS[2][32];
    __shared__ int   dS[2][32];         // d | (invalid << 16)
    __shared__ float lgS[2][256];       // staged logits for coalesced flush
    const int tid = threadIdx.x, wid = tid >> 6, lane = tid & 63;

    float2 wrb[16];                     // W_alpha rbf-block cols (2/lane) in 32 VGPRs
    #pragma unroll
    for (int j = 0; j < 16; ++j)
        wrb[j] = ((const float2*)(Wa + (70 + j) * 128))[lane];
    const float2 av = ((const float2*)avec)[lane];

    const int e0 = (blockIdx.x * 2 + wid) * 32;

    // ---- phase A: lane pairs share an edge; each computes 8 of 16 rbf exps ----
    {
        const int el  = lane & 31;
        const int e   = e0 + el;
        const int tgt = e / K_;
        int src = srcArr[e];
        src = (src < 0) ? 0 : ((src >= N_) ? (N_ - 1) : src);
        float vx = trans[src*3+0] - trans[tgt*3+0];
        float vy = trans[src*3+1] - trans[tgt*3+1];
        float vz = trans[src*3+2] - trans[tgt*3+2];
        float dist = sqrtf(vx*vx + vy*vy + vz*vz);
        bool valid = isfinite(dist) && (dist > 1e-3f);
        int d = src - tgt + 512;
        d = (d < 0) ? 0 : ((d > 1023) ? 1023 : d);
        if (lane < 32) {
            srcS[wid][el] = src;
            tgtS[wid][el] = tgt;
            dS[wid][el]   = d | (valid ? 0 : (1 << 16));
        }
        const int jb = (lane >> 5) * 8;
        #pragma unroll
        for (int j = 0; j < 8; ++j) {
            float tt = (dist - (float)(jb + j) * (20.f/15.f)) * 0.8f;
            rbfS[wid][el][jb + j] = __expf(-tt * tt);
        }
    }
    __syncthreads();

    // ---- phase B: wave sweeps its 32 edges ----
    #pragma unroll 2
    for (int q = 0; q < 32; ++q) {
        const int src = srcS[wid][q];
        const int tgt = tgtS[wid][q];
        const int dm  = dS[wid][q];
        const int d   = dm & 0xFFFF;
        const bool valid = (dm >> 16) == 0;

        float2 hs = ((const float2*)(hsrc + (size_t)src * 128))[lane];
        float2 ht = ((const float2*)(htgt + (size_t)tgt * 128))[lane];
        float2 pt = ((const float2*)(ptab + (size_t)d   * 128))[lane];
        float acc0 = hs.x + ht.x + pt.x;
        float acc1 = hs.y + ht.y + pt.y;
        const float4* rp = (const float4*)(&rbfS[wid][q][0]);
        #pragma unroll
        for (int jj = 0; jj < 4; ++jj) {
            float4 rb = rp[jj];             // broadcast read (all lanes same addr)
            acc0 = fmaf(rb.x, wrb[4*jj+0].x, acc0); acc1 = fmaf(rb.x, wrb[4*jj+0].y, acc1);
            acc0 = fmaf(rb.y, wrb[4*jj+1].x, acc0); acc1 = fmaf(rb.y, wrb[4*jj+1].y, acc1);
            acc0 = fmaf(rb.z, wrb[4*jj+2].x, acc0); acc1 = fmaf(rb.z, wrb[4*jj+2].y, acc1);
            acc0 = fmaf(rb.w, wrb[4*jj+3].x, acc0); acc1 = fmaf(rb.w, wrb[4*jj+3].y, acc1);
        }
        float part = fsilu(acc0) * av.x + fsilu(acc1) * av.y;
        #pragma unroll
        for (int s = 1; s < 8; s <<= 1) part += __shfl_xor(part, s, 64);
        float lg = (part >= 0.f) ? part : 0.2f * part;
        if (!valid) lg = -1e9f;
        lg = (fabsf(lg) < 1e30f) ? lg : -1e9f;
        if ((lane & 7) == 0) lgS[wid][q * 8 + (lane >> 3)] = lg;
    }
    __syncthreads();
    {   // coalesced flush: 256 floats per wave = 1 float4 per lane
        float4* dst = (float4*)(logitsw + (size_t)e0 * 8);
        dst[lane] = ((const float4*)lgS[wid])[lane];
    }
}

// ---------------- kernel 4: softmax (in-reg, fast exp) + alpha-weighted V sum + epilogue --------
__global__ __launch_bounds__(256) void agg_out_kernel(
    const float* __restrict__ V, const int* __restrict__ srcArr,
    const float* __restrict__ logitsw,
    const float* __restrict__ Wo, const float* __restrict__ Wg,
    const float* __restrict__ W2,
    const int* __restrict__ flag, void* __restrict__ outv)
{
    __shared__ int   srcs[K_];
    __shared__ float aggS[256];
    __shared__ float ybuf[128];
    __shared__ float gbuf[32];
    const int bid = blockIdx.x;
    const int t   = ((bid & 7) << 10) | (bid >> 3);   // XCD-locality swizzle
    const int tid = threadIdx.x;
    const int obf = flag[0];
    const int cc = tid & 63, r = tid >> 6, h = cc >> 3;

    if (tid < K_) {
        int s = srcArr[t * K_ + tid];
        srcs[tid] = (s < 0) ? 0 : ((s >= N_) ? (N_ - 1) : s);
    }

    const float* lp = logitsw + (size_t)t * 240 + h;
    float lg[K_];
    float mx = -1e30f;
    #pragma unroll
    for (int k = 0; k < K_; ++k) { lg[k] = lp[k * 8]; mx = fmaxf(mx, lg[k]); }
    float den = 0.f;
    #pragma unroll
    for (int k = 0; k < K_; ++k) {
        float e = (lg[k] > -1e8f) ? __expf(lg[k] - mx) : 0.f;
        lg[k] = e; den += e;
    }
    const float inv = 1.f / (den + 1e-9f);
    __syncthreads();

    const int off = (r << 6) | cc;
    float acc = 0.f;
    #pragma unroll 6
    for (int k = 0; k < K_; ++k)
        acc = fmaf(lg[k], V[(size_t)srcs[k] * 256 + off], acc);
    aggS[tid] = acc * inv;
    __syncthreads();

    // epilogue: y = agg @ W_o ; gate = silu(y0 @ W_g) ; out = (y*gate) @ W_2
    if (tid < 128) {
        int rr = tid >> 5, o = tid & 31;
        float y = 0.f;
        #pragma unroll
        for (int c = 0; c < 64; ++c) y = fmaf(aggS[rr * 64 + c], Wo[c * 32 + o], y);
        ybuf[tid] = y;
    }
    __syncthreads();
    if (tid < 32) {
        float g = 0.f;
        #pragma unroll
        for (int o = 0; o < 32; ++o) g = fmaf(ybuf[o], Wg[o * 32 + tid], g);
        gbuf[tid] = g / (1.f + expf(-g));
    }
    __syncthreads();
    if (tid < 128) {
        int rr = tid >> 5, hh = tid & 31;
        float o = 0.f;
        #pragma unroll
        for (int g = 0; g < 32; ++g) o = fmaf(ybuf[rr * 32 + g] * gbuf[g], W2[g * 32 + hh], o);
        o = (fabsf(o) < 1e30f) ? o : 0.f;
        size_t idx = (size_t)t * 128 + tid;
        if (obf) ((u16*)outv)[idx] = f2bf(o);
        else     ((float*)outv)[idx] = o;
    }
}

extern "C" void kernel_launch(void* const* d_in, const int* in_sizes, int n_in,
                              void* d_out, int out_size, void* d_ws, size_t ws_size,
                              hipStream_t stream)
{
    const void* rots         = d_in[0];
    const void* trans        = d_in[1];
    const void* node_emb     = d_in[2];
    /* d_in[3] = batch (unused; chains contiguous) */
    const void* x_mask       = d_in[4];
    const void* noising_mask = d_in[5];
    const void* Wa           = d_in[6];
    const void* avec         = d_in[7];
    const void* Wv           = d_in[8];
    const void* Wo           = d_in[9];
    const void* Wg           = d_in[10];
    const void* W2           = d_in[11];

    char* ws = (char*)d_ws;
    int*   flag    = (int*)  (ws + 0);            //        64
    float* c_trans = (float*)(ws + 64);           //    98,304
    float* c_Wa    = (float*)(ws + 98368);        //    52,224
    float* c_av    = (float*)(ws + 150592);       //       512
    float* c_Wv    = (float*)(ws + 151104);       //     8,960
    float* c_Wo    = (float*)(ws + 160064);       //     8,192
    float* c_Wg    = (float*)(ws + 168256);       //     4,096
    float* c_W2    = (float*)(ws + 172352);       //     4,096
    int*   srcArr  = (int*)  (ws + 176448);       //   983,040
    float* hsrc    = (float*)(ws + 1159488);      // 4,194,304
    float* htgt    = (float*)(ws + 5353792);      // 4,194,304
    float* ptab    = (float*)(ws + 9548096);      //   524,288
    float* logitsw = (float*)(ws + 10072384);     // 7,864,320
    float* V       = (float*)(ws + 17936704);     // 8,388,608  (end ~26.3 MB)

    hipLaunchKernelGGL(detect_kernel, dim3(1), dim3(64), 0, stream,
                       (const u16*)trans, (const u32*)x_mask, flag);
    hipLaunchKernelGGL(conv_kernel, dim3((U_W2 + 255) / 256), dim3(256), 0, stream,
                       trans, Wa, avec, Wv, Wo, Wg, W2, flag,
                       c_trans, c_Wa, c_av, c_Wv, c_Wo, c_Wg, c_W2);
    hipLaunchKernelGGL(knn_kernel,  dim3(N_/4),     dim3(256), 0, stream, c_trans, srcArr);
    hipLaunchKernelGGL(node_kernel, dim3(N_+1024),  dim3(256), 0, stream,
                       rots, node_emb, x_mask, noising_mask, flag, c_Wa, c_Wv,
                       hsrc, htgt, ptab, V);
    hipLaunchKernelGGL(logits_kernel, dim3(E_/64),  dim3(128), 0, stream,
                       c_trans, srcArr, hsrc, htgt, ptab, c_Wa, c_av, logitsw);
    hipLaunchKernelGGL(agg_out_kernel, dim3(N_),    dim3(256), 0, stream,
                       V, srcArr, logitsw, c_Wo, c_Wg, c_W2, flag, d_out);
}

// Round 9
// 227.117 us; speedup vs baseline: 6.6451x; 1.0204x over previous
//
#include <hip/hip_runtime.h>
#include <cstdint>

#define B_ 16
#define L_ 512
#define N_ 8192
#define K_ 30
#define E_ (N_*K_)
#define H_ 32
#define C_ 35

typedef uint16_t u16;
typedef uint32_t u32;
typedef unsigned long long u64;

// adaptive float load: bf16 (u16<<16) or fp32
static __device__ __forceinline__ float ldf(const void* p, int i, int bf) {
    return bf ? __uint_as_float(((u32)((const u16*)p)[i]) << 16)
              : ((const float*)p)[i];
}
// mask load: mode 0 = u8 bool, 1 = int32, 2 = int64 (little-endian low word)
static __device__ __forceinline__ int ldmask(const void* p, int i, int mode) {
    if (mode == 0) return ((const unsigned char*)p)[i] != 0;
    if (mode == 2) return ((const u32*)p)[2*i] != 0;
    return ((const u32*)p)[i] != 0;
}
// f32 -> bf16 RNE
static __device__ __forceinline__ u16 f2bf(float f) {
    u32 x = __float_as_uint(f);
    u32 r = x + 0x7FFFu + ((x >> 16) & 1u);
    return (u16)(r >> 16);
}
// fast silu: x * rcp(1 + exp(-x))  (~1e-7 rel err, threshold is 4.3e-3)
static __device__ __forceinline__ float fsilu(float x) {
    return x * __builtin_amdgcn_rcpf(1.f + __expf(-x));
}

// ---------------- kernel 0: dtype detection ----------------
__global__ void detect_kernel(const u16* __restrict__ tr, const u32* __restrict__ xm,
                              int* __restrict__ flag)
{
    int lane = threadIdx.x;
    int cnt = 0;
    for (int i = lane; i < 256; i += 64) {
        u16 v = tr[2 * i];
        int e = (v >> 7) & 0xFF;
        if ((e >= 100 && e <= 141) || (v & 0x7FFFu) == 0) cnt++;
    }
    int anyBig = 0, oddNZ = 0;
    for (int i = lane; i < 1024; i += 64) {
        u32 w = xm[i];
        if (w & ~1u) anyBig = 1;
        if ((i & 1) && w) oddNZ = 1;
    }
    #pragma unroll
    for (int d = 1; d < 64; d <<= 1) {
        cnt    += __shfl_xor(cnt, d, 64);
        anyBig |= __shfl_xor(anyBig, d, 64);
        oddNZ  |= __shfl_xor(oddNZ, d, 64);
    }
    if (lane == 0) {
        flag[0] = (cnt >= 192) ? 1 : 0;
        flag[1] = anyBig ? 0 : (oddNZ ? 1 : 2);
    }
}

// ---------------- kernel 0.5: canonicalize trans + weights to f32 ----------------
#define U_TRANS 24576
#define U_WA    37632
#define U_AV    37760
#define U_WV    40000
#define U_WO    42048
#define U_WG    43072
#define U_W2    44096

__global__ void conv_kernel(const void* trans,
                            const void* Wa, const void* av, const void* Wv,
                            const void* Wo, const void* Wg, const void* W2,
                            const int* __restrict__ flag,
                            float* c_trans, float* c_Wa, float* c_av, float* c_Wv,
                            float* c_Wo, float* c_Wg, float* c_W2)
{
    int gid = blockIdx.x * 256 + threadIdx.x;
    if (gid >= U_W2) return;
    int bf = flag[0];
    if      (gid < U_TRANS) c_trans[gid]           = ldf(trans, gid,           bf);
    else if (gid < U_WA)    c_Wa   [gid - U_TRANS] = ldf(Wa,    gid - U_TRANS, bf);
    else if (gid < U_AV)    c_av   [gid - U_WA]    = ldf(av,    gid - U_WA,    bf);
    else if (gid < U_WV)    c_Wv   [gid - U_AV]    = ldf(Wv,    gid - U_AV,    bf);
    else if (gid < U_WO)    c_Wo   [gid - U_WV]    = ldf(Wo,    gid - U_WV,    bf);
    else if (gid < U_WG)    c_Wg   [gid - U_WO]    = ldf(Wg,    gid - U_WO,    bf);
    else                    c_W2   [gid - U_WG]    = ldf(W2,    gid - U_WG,    bf);
}

// ---------------- kernel 1: per-chain kNN — DPP (VALU-pipe) argmin, zero DS in loop ------------
// (d2,idx) packed into u64 key: d2>=0 -> float bits order-preserving; low word = idx
// -> lexicographic u64 min == lax.top_k tie-breaking. Reduction via row_shr/row_bcast DPP
// (runs on VALU, not the CU-shared LDS pipe that made the shuffle version DS-bound).
#define DPP_MIN_STEP(CTRL) \
    { u32 olo = (u32)__builtin_amdgcn_update_dpp((int)lo, (int)lo, CTRL, 0xF, 0xF, false); \
      u32 ohi = (u32)__builtin_amdgcn_update_dpp((int)hi, (int)hi, CTRL, 0xF, 0xF, false); \
      u64 o = (((u64)ohi) << 32) | olo; \
      if (o < m) m = o; \
      lo = (u32)m; hi = (u32)(m >> 32); }

__global__ __launch_bounds__(256) void knn_kernel(const float* __restrict__ trans,
                                                  int* __restrict__ srcArr)
{
    __shared__ float xs[L_], ys[L_], zs[L_];
    const int tid  = threadIdx.x;
    const int t0   = blockIdx.x * 4;        // 4 targets per block, same chain (512 % 4 == 0)
    const int base = (t0 >> 9) << 9;        // chain base node

    for (int i = tid; i < L_; i += 256) {
        xs[i] = trans[(base + i) * 3 + 0];
        ys[i] = trans[(base + i) * 3 + 1];
        zs[i] = trans[(base + i) * 3 + 2];
    }
    __syncthreads();

    const int wid = tid >> 6, lane = tid & 63;
    const int t = t0 + wid;
    const int l = t & 511;
    const float tx = xs[l], ty = ys[l], tz = zs[l];

    // lane owns candidates idx = lane + 64*slot (registers only)
    u64 key[8];
    #pragma unroll
    for (int i = 0; i < 8; ++i) {
        int j = lane + (i << 6);
        // match numpy: ((dx*dx + dy*dy) + dz*dz), no FMA contraction
        float dx = __fsub_rn(tx, xs[j]);
        float dy = __fsub_rn(ty, ys[j]);
        float dz = __fsub_rn(tz, zs[j]);
        float d2 = __fadd_rn(__fadd_rn(__fmul_rn(dx, dx), __fmul_rn(dy, dy)), __fmul_rn(dz, dz));
        if (j == l) d2 = __fadd_rn(d2, 1e9f);   // exclude self
        key[i] = (((u64)__float_as_uint(d2)) << 32) | (u32)j;
    }

    int myres = 0;
    for (int k = 0; k < K_; ++k) {
        // local lexicographic min over 8 slots
        u64 m = key[0];
        #pragma unroll
        for (int i = 1; i < 8; ++i)
            if (key[i] < m) m = key[i];
        // wave-64 min reduce on VALU via DPP; result lands in lane 63
        u32 lo = (u32)m, hi = (u32)(m >> 32);
        DPP_MIN_STEP(0x111)   // row_shr:1
        DPP_MIN_STEP(0x112)   // row_shr:2
        DPP_MIN_STEP(0x114)   // row_shr:4
        DPP_MIN_STEP(0x118)   // row_shr:8
        DPP_MIN_STEP(0x142)   // row_bcast:15
        DPP_MIN_STEP(0x143)   // row_bcast:31
        u32 glo = (u32)__builtin_amdgcn_readlane((int)lo, 63);
        u32 ghi = (u32)__builtin_amdgcn_readlane((int)hi, 63);
        u64 gm = (((u64)ghi) << 32) | glo;
        if (lane == k) myres = (int)(glo & 511u);  // lane k records k-th neighbor
        #pragma unroll
        for (int i = 0; i < 8; ++i)                 // invalidate winner (keys unique)
            if (key[i] == gm) key[i] = ~0ULL;
    }
    if (lane < K_) srcArr[t * K_ + lane] = base + myres;
}

// ---------------- kernel 2: fused node pipeline: emb(LDS) -> hsrc/htgt, V ; ptab tail -----------
__constant__ float cBB[9] = {-0.525f, 1.363f, 0.f,  0.f, 0.f, 0.f,  1.526f, 0.f, 0.f};

__global__ __launch_bounds__(256) void node_kernel(
    const void* __restrict__ rots, const void* __restrict__ node,
    const void* __restrict__ xm, const void* __restrict__ nm,
    const int* __restrict__ flag,
    const float* __restrict__ Wa, const float* __restrict__ Wv,
    float* __restrict__ hsrc, float* __restrict__ htgt,
    float* __restrict__ ptab, float* __restrict__ V)
{
    const int bid = blockIdx.x, tid = threadIdx.x;
    if (bid >= N_) {                        // pos-emb table rows
        int d = bid - N_;
        if (tid < 128) {
            float dd = (float)(d - 512);
            float acc = 0.f;
            #pragma unroll
            for (int q = 0; q < 8; ++q) {
                float fr = expf((float)(2 * q) * (-0.5756462732485115f)); // -ln(1e4)/16
                float ang = dd * fr;
                acc = fmaf(cosf(ang), Wa[(86 + q) * 128 + tid], acc);
                acc = fmaf(sinf(ang), Wa[(94 + q) * 128 + tid], acc);
            }
            ptab[(size_t)d * 128 + tid] = acc;
        }
        return;
    }
    __shared__ float e[140];
    const int bf = flag[0], mm = flag[1];
    if (tid < 140) {
        int r = tid / 35, c = tid - r * 35;
        float v;
        if (c < H_) {
            v = ldf(node, bid * 128 + r * 32 + c, bf);
        } else if (r == 0) {
            v = (c == 34) ? ((ldmask(nm, bid, mm) && !ldmask(xm, bid, mm)) ? 1.f : 0.f) : 0.f;
        } else {
            int i = r - 1, a = c - 32;
            v = ldf(rots, bid*9 + i*3 + 0, bf) * cBB[a*3 + 0]
              + ldf(rots, bid*9 + i*3 + 1, bf) * cBB[a*3 + 1]
              + ldf(rots, bid*9 + i*3 + 2, bf) * cBB[a*3 + 2];
        }
        e[tid] = v;
    }
    __syncthreads();
    if (tid < 128) {                        // hsrc/htgt GEMVs over l=0 row
        float a = 0.f, b = 0.f;
        #pragma unroll 5
        for (int i = 0; i < 35; ++i) {
            float v = e[i];
            a = fmaf(v, Wa[i * 128 + tid],        a);
            b = fmaf(v, Wa[(35 + i) * 128 + tid], b);
        }
        hsrc[(size_t)bid * 128 + tid] = a;
        htgt[(size_t)bid * 128 + tid] = b;
    }
    {                                       // V[n] = emb[n] (4x35) @ Wv (35x64)
        int r = tid >> 6, cc = tid & 63;
        const float* er = e + r * 35;       // wave-uniform base -> LDS broadcast
        float acc = 0.f;
        #pragma unroll 5
        for (int cp = 0; cp < 35; ++cp) acc = fmaf(er[cp], Wv[cp * 64 + cc], acc);
        V[(size_t)bid * 256 + tid] = acc;
    }
}

// ---------------- kernel 3: per-edge logits, two-phase, 32 edges/wave ---------------
__global__ __launch_bounds__(128) void logits_kernel(
    const float* __restrict__ trans, const int* __restrict__ srcArr,
    const float* __restrict__ hsrc, const float* __restrict__ htgt,
    const float* __restrict__ ptab, const float* __restrict__ Wa,
    const float* __restrict__ avec, float* __restrict__ logitsw)
{
    __shared__ float rbfS[2][32][20];   // pad 20 -> float4 rows
    __shared__ int   srcS[2][32];
    __shared__ int   tgtS[2][32];
    __shared__ int   dS[2][32];         // d | (invalid << 16)
    __shared__ float lgS[2][256];       // staged logits for coalesced flush
    const int tid = threadIdx.x, wid = tid >> 6, lane = tid & 63;

    float2 wrb[16];                     // W_alpha rbf-block cols (2/lane) in 32 VGPRs
    #pragma unroll
    for (int j = 0; j < 16; ++j)
        wrb[j] = ((const float2*)(Wa + (70 + j) * 128))[lane];
    const float2 av = ((const float2*)avec)[lane];

    const int e0 = (blockIdx.x * 2 + wid) * 32;

    // ---- phase A: lane pairs share an edge; each computes 8 of 16 rbf exps ----
    {
        const int el  = lane & 31;
        const int e   = e0 + el;
        const int tgt = e / K_;
        int src = srcArr[e];
        src = (src < 0) ? 0 : ((src >= N_) ? (N_ - 1) : src);
        float vx = trans[src*3+0] - trans[tgt*3+0];
        float vy = trans[src*3+1] - trans[tgt*3+1];
        float vz = trans[src*3+2] - trans[tgt*3+2];
        float dist = sqrtf(vx*vx + vy*vy + vz*vz);
        bool valid = isfinite(dist) && (dist > 1e-3f);
        int d = src - tgt + 512;
        d = (d < 0) ? 0 : ((d > 1023) ? 1023 : d);
        if (lane < 32) {
            srcS[wid][el] = src;
            tgtS[wid][el] = tgt;
            dS[wid][el]   = d | (valid ? 0 : (1 << 16));
        }
        const int jb = (lane >> 5) * 8;
        #pragma unroll
        for (int j = 0; j < 8; ++j) {
            float tt = (dist - (float)(jb + j) * (20.f/15.f)) * 0.8f;
            rbfS[wid][el][jb + j] = __expf(-tt * tt);
        }
    }
    __syncthreads();

    // ---- phase B: wave sweeps its 32 edges ----
    #pragma unroll 2
    for (int q = 0; q < 32; ++q) {
        const int src = srcS[wid][q];
        const int tgt = tgtS[wid][q];
        const int dm  = dS[wid][q];
        const int d   = dm & 0xFFFF;
        const bool valid = (dm >> 16) == 0;

        float2 hs = ((const float2*)(hsrc + (size_t)src * 128))[lane];
        float2 ht = ((const float2*)(htgt + (size_t)tgt * 128))[lane];
        float2 pt = ((const float2*)(ptab + (size_t)d   * 128))[lane];
        float acc0 = hs.x + ht.x + pt.x;
        float acc1 = hs.y + ht.y + pt.y;
        const float4* rp = (const float4*)(&rbfS[wid][q][0]);
        #pragma unroll
        for (int jj = 0; jj < 4; ++jj) {
            float4 rb = rp[jj];             // broadcast read (all lanes same addr)
            acc0 = fmaf(rb.x, wrb[4*jj+0].x, acc0); acc1 = fmaf(rb.x, wrb[4*jj+0].y, acc1);
            acc0 = fmaf(rb.y, wrb[4*jj+1].x, acc0); acc1 = fmaf(rb.y, wrb[4*jj+1].y, acc1);
            acc0 = fmaf(rb.z, wrb[4*jj+2].x, acc0); acc1 = fmaf(rb.z, wrb[4*jj+2].y, acc1);
            acc0 = fmaf(rb.w, wrb[4*jj+3].x, acc0); acc1 = fmaf(rb.w, wrb[4*jj+3].y, acc1);
        }
        float part = fsilu(acc0) * av.x + fsilu(acc1) * av.y;
        #pragma unroll
        for (int s = 1; s < 8; s <<= 1) part += __shfl_xor(part, s, 64);
        float lg = (part >= 0.f) ? part : 0.2f * part;
        if (!valid) lg = -1e9f;
        lg = (fabsf(lg) < 1e30f) ? lg : -1e9f;
        if ((lane & 7) == 0) lgS[wid][q * 8 + (lane >> 3)] = lg;
    }
    __syncthreads();
    {   // coalesced flush: 256 floats per wave = 1 float4 per lane
        float4* dst = (float4*)(logitsw + (size_t)e0 * 8);
        dst[lane] = ((const float4*)lgS[wid])[lane];
    }
}

// ---------------- kernel 4: softmax (in-reg, fast exp) + alpha-weighted V sum + epilogue --------
__global__ __launch_bounds__(256) void agg_out_kernel(
    const float* __restrict__ V, const int* __restrict__ srcArr,
    const float* __restrict__ logitsw,
    const float* __restrict__ Wo, const float* __restrict__ Wg,
    const float* __restrict__ W2,
    const int* __restrict__ flag, void* __restrict__ outv)
{
    __shared__ int   srcs[K_];
    __shared__ float aggS[256];
    __shared__ float ybuf[128];
    __shared__ float gbuf[32];
    const int bid = blockIdx.x;
    const int t   = ((bid & 7) << 10) | (bid >> 3);   // XCD-locality swizzle
    const int tid = threadIdx.x;
    const int obf = flag[0];
    const int cc = tid & 63, r = tid >> 6, h = cc >> 3;

    if (tid < K_) {
        int s = srcArr[t * K_ + tid];
        srcs[tid] = (s < 0) ? 0 : ((s >= N_) ? (N_ - 1) : s);
    }

    const float* lp = logitsw + (size_t)t * 240 + h;
    float lg[K_];
    float mx = -1e30f;
    #pragma unroll
    for (int k = 0; k < K_; ++k) { lg[k] = lp[k * 8]; mx = fmaxf(mx, lg[k]); }
    float den = 0.f;
    #pragma unroll
    for (int k = 0; k < K_; ++k) {
        float e = (lg[k] > -1e8f) ? __expf(lg[k] - mx) : 0.f;
        lg[k] = e; den += e;
    }
    const float inv = 1.f / (den + 1e-9f);
    __syncthreads();

    const int off = (r << 6) | cc;
    float acc = 0.f;
    #pragma unroll 6
    for (int k = 0; k < K_; ++k)
        acc = fmaf(lg[k], V[(size_t)srcs[k] * 256 + off], acc);
    aggS[tid] = acc * inv;
    __syncthreads();

    // epilogue: y = agg @ W_o ; gate = silu(y0 @ W_g) ; out = (y*gate) @ W_2
    if (tid < 128) {
        int rr = tid >> 5, o = tid & 31;
        float y = 0.f;
        #pragma unroll
        for (int c = 0; c < 64; ++c) y = fmaf(aggS[rr * 64 + c], Wo[c * 32 + o], y);
        ybuf[tid] = y;
    }
    __syncthreads();
    if (tid < 32) {
        float g = 0.f;
        #pragma unroll
        for (int o = 0; o < 32; ++o) g = fmaf(ybuf[o], Wg[o * 32 + tid], g);
        gbuf[tid] = g / (1.f + expf(-g));
    }
    __syncthreads();
    if (tid < 128) {
        int rr = tid >> 5, hh = tid & 31;
        float o = 0.f;
        #pragma unroll
        for (int g = 0; g < 32; ++g) o = fmaf(ybuf[rr * 32 + g] * gbuf[g], W2[g * 32 + hh], o);
        o = (fabsf(o) < 1e30f) ? o : 0.f;
        size_t idx = (size_t)t * 128 + tid;
        if (obf) ((u16*)outv)[idx] = f2bf(o);
        else     ((float*)outv)[idx] = o;
    }
}

extern "C" void kernel_launch(void* const* d_in, const int* in_sizes, int n_in,
                              void* d_out, int out_size, void* d_ws, size_t ws_size,
                              hipStream_t stream)
{
    const void* rots         = d_in[0];
    const void* trans        = d_in[1];
    const void* node_emb     = d_in[2];
    /* d_in[3] = batch (unused; chains contiguous) */
    const void* x_mask       = d_in[4];
    const void* noising_mask = d_in[5];
    const void* Wa           = d_in[6];
    const void* avec         = d_in[7];
    const void* Wv           = d_in[8];
    const void* Wo           = d_in[9];
    const void* Wg           = d_in[10];
    const void* W2           = d_in[11];

    char* ws = (char*)d_ws;
    int*   flag    = (int*)  (ws + 0);            //        64
    float* c_trans = (float*)(ws + 64);           //    98,304
    float* c_Wa    = (float*)(ws + 98368);        //    52,224
    float* c_av    = (float*)(ws + 150592);       //       512
    float* c_Wv    = (float*)(ws + 151104);       //     8,960
    float* c_Wo    = (float*)(ws + 160064);       //     8,192
    float* c_Wg    = (float*)(ws + 168256);       //     4,096
    float* c_W2    = (float*)(ws + 172352);       //     4,096
    int*   srcArr  = (int*)  (ws + 176448);       //   983,040
    float* hsrc    = (float*)(ws + 1159488);      // 4,194,304
    float* htgt    = (float*)(ws + 5353792);      // 4,194,304
    float* ptab    = (float*)(ws + 9548096);      //   524,288
    float* logitsw = (float*)(ws + 10072384);     // 7,864,320
    float* V       = (float*)(ws + 17936704);     // 8,388,608  (end ~26.3 MB)

    hipLaunchKernelGGL(detect_kernel, dim3(1), dim3(64), 0, stream,
                       (const u16*)trans, (const u32*)x_mask, flag);
    hipLaunchKernelGGL(conv_kernel, dim3((U_W2 + 255) / 256), dim3(256), 0, stream,
                       trans, Wa, avec, Wv, Wo, Wg, W2, flag,
                       c_trans, c_Wa, c_av, c_Wv, c_Wo, c_Wg, c_W2);
    hipLaunchKernelGGL(knn_kernel,  dim3(N_/4),     dim3(256), 0, stream, c_trans, srcArr);
    hipLaunchKernelGGL(node_kernel, dim3(N_+1024),  dim3(256), 0, stream,
                       rots, node_emb, x_mask, noising_mask, flag, c_Wa, c_Wv,
                       hsrc, htgt, ptab, V);
    hipLaunchKernelGGL(logits_kernel, dim3(E_/64),  dim3(128), 0, stream,
                       c_trans, srcArr, hsrc, htgt, ptab, c_Wa, c_av, logitsw);
    hipLaunchKernelGGL(agg_out_kernel, dim3(N_),    dim3(256), 0, stream,
                       V, srcArr, logitsw, c_Wo, c_Wg, c_W2, flag, d_out);
}

// Round 10
// 224.310 us; speedup vs baseline: 6.7283x; 1.0125x over previous
//
#include <hip/hip_runtime.h>
#include <cstdint>

#define B_ 16
#define L_ 512
#define N_ 8192
#define K_ 30
#define E_ (N_*K_)
#define H_ 32
#define C_ 35

typedef uint16_t u16;
typedef uint32_t u32;
typedef unsigned long long u64;

// adaptive float load: bf16 (u16<<16) or fp32
static __device__ __forceinline__ float ldf(const void* p, int i, int bf) {
    return bf ? __uint_as_float(((u32)((const u16*)p)[i]) << 16)
              : ((const float*)p)[i];
}
static __device__ __forceinline__ float bfu16(u16 x) {
    return __uint_as_float(((u32)x) << 16);
}
// mask load: mode 0 = u8 bool, 1 = int32, 2 = int64 (little-endian low word)
static __device__ __forceinline__ int ldmask(const void* p, int i, int mode) {
    if (mode == 0) return ((const unsigned char*)p)[i] != 0;
    if (mode == 2) return ((const u32*)p)[2*i] != 0;
    return ((const u32*)p)[i] != 0;
}
// f32 -> bf16 RNE
static __device__ __forceinline__ u16 f2bf(float f) {
    u32 x = __float_as_uint(f);
    u32 r = x + 0x7FFFu + ((x >> 16) & 1u);
    return (u16)(r >> 16);
}
// fast silu (~1e-7 rel err; threshold 4.3e-3)
static __device__ __forceinline__ float fsilu(float x) {
    return x * __builtin_amdgcn_rcpf(1.f + __expf(-x));
}

// per-block inline dtype detection (wave 0 only; deterministic)
static __device__ __forceinline__ int detect_bf(const void* tr, int lane) {
    const u16* p = (const u16*)tr;
    int cnt = 0;
    for (int i = lane; i < 256; i += 64) {
        u16 v = p[2 * i];
        int e = (v >> 7) & 0xFF;
        if ((e >= 100 && e <= 141) || (v & 0x7FFFu) == 0) cnt++;
    }
    #pragma unroll
    for (int d = 1; d < 64; d <<= 1) cnt += __shfl_xor(cnt, d, 64);
    return cnt >= 192;
}
static __device__ __forceinline__ int detect_mm(const void* xmv, int lane) {
    const u32* xm = (const u32*)xmv;
    int anyBig = 0, oddNZ = 0;
    for (int i = lane; i < 1024; i += 64) {
        u32 w = xm[i];
        if (w & ~1u) anyBig = 1;
        if ((i & 1) && w) oddNZ = 1;
    }
    #pragma unroll
    for (int d = 1; d < 64; d <<= 1) {
        anyBig |= __shfl_xor(anyBig, d, 64);
        oddNZ  |= __shfl_xor(oddNZ, d, 64);
    }
    return anyBig ? 0 : (oddNZ ? 1 : 2);
}

__constant__ float cBB[9] = {-0.525f, 1.363f, 0.f,  0.f, 0.f, 0.f,  1.526f, 0.f, 0.f};

// DPP u64-key min step (runs on VALU pipe, not the CU-shared LDS pipe)
#define DPP_MIN_STEP(CTRL) \
    { u32 olo = (u32)__builtin_amdgcn_update_dpp((int)lo, (int)lo, CTRL, 0xF, 0xF, false); \
      u32 ohi = (u32)__builtin_amdgcn_update_dpp((int)hi, (int)hi, CTRL, 0xF, 0xF, false); \
      u64 o = (((u64)ohi) << 32) | olo; \
      if (o < m) m = o; \
      lo = (u32)m; hi = (u32)(m >> 32); }

// =============== kernel 1: mega prep (knn | node | ptab | weight-convert) =================
// blocks [0,2048): kNN (4 targets/block)   [2048,10240): node n=bid-2048
// [10240,11264): ptab d=bid-10240          [11264,11272): convert K2 weights (+flag)
__global__ __launch_bounds__(256) void mega_kernel(
    const void* __restrict__ rots, const void* __restrict__ trans,
    const void* __restrict__ node, const void* __restrict__ xm,
    const void* __restrict__ nm,
    const void* __restrict__ Wa, const void* __restrict__ av,
    const void* __restrict__ Wv, const void* __restrict__ Wo,
    const void* __restrict__ Wg, const void* __restrict__ W2,
    int* __restrict__ flag, int* __restrict__ srcArr,
    float* __restrict__ hsrc, float* __restrict__ htgt,
    float* __restrict__ ptab, float* __restrict__ V,
    float* __restrict__ c_wrb, float* __restrict__ c_av,
    float* __restrict__ c_Wo, float* __restrict__ c_Wg, float* __restrict__ c_W2)
{
    __shared__ float sX[L_], sY[L_], sZ[L_];
    __shared__ float eS[140];
    __shared__ int flagS[2];
    const int bid = blockIdx.x, tid = threadIdx.x;
    const int lane = tid & 63, wid = tid >> 6;

    if (bid < 2048) {
        // ---------------- kNN ----------------
        if (wid == 0) {
            int bf = detect_bf(trans, lane);
            if (lane == 0) flagS[0] = bf;
        }
        __syncthreads();
        const int bf = flagS[0];
        const int t0 = bid * 4;
        const int base = (t0 >> 9) << 9;
        if (bf) {
            const u16* tp = (const u16*)trans;
            for (int i = tid; i < L_; i += 256) {
                sX[i] = bfu16(tp[(base + i) * 3 + 0]);
                sY[i] = bfu16(tp[(base + i) * 3 + 1]);
                sZ[i] = bfu16(tp[(base + i) * 3 + 2]);
            }
        } else {
            const float* tp = (const float*)trans;
            for (int i = tid; i < L_; i += 256) {
                sX[i] = tp[(base + i) * 3 + 0];
                sY[i] = tp[(base + i) * 3 + 1];
                sZ[i] = tp[(base + i) * 3 + 2];
            }
        }
        __syncthreads();

        const int t = t0 + wid;
        const int l = t & 511;
        const float tx = sX[l], ty = sY[l], tz = sZ[l];

        u64 key[8];
        #pragma unroll
        for (int i = 0; i < 8; ++i) {
            int j = lane + (i << 6);
            // match numpy: ((dx*dx + dy*dy) + dz*dz), no FMA contraction
            float dx = __fsub_rn(tx, sX[j]);
            float dy = __fsub_rn(ty, sY[j]);
            float dz = __fsub_rn(tz, sZ[j]);
            float d2 = __fadd_rn(__fadd_rn(__fmul_rn(dx, dx), __fmul_rn(dy, dy)), __fmul_rn(dz, dz));
            if (j == l) d2 = __fadd_rn(d2, 1e9f);
            key[i] = (((u64)__float_as_uint(d2)) << 32) | (u32)j;
        }
        int myres = 0;
        for (int k = 0; k < K_; ++k) {
            u64 m = key[0];
            #pragma unroll
            for (int i = 1; i < 8; ++i)
                if (key[i] < m) m = key[i];
            u32 lo = (u32)m, hi = (u32)(m >> 32);
            DPP_MIN_STEP(0x111)   // row_shr:1
            DPP_MIN_STEP(0x112)   // row_shr:2
            DPP_MIN_STEP(0x114)   // row_shr:4
            DPP_MIN_STEP(0x118)   // row_shr:8
            DPP_MIN_STEP(0x142)   // row_bcast:15
            DPP_MIN_STEP(0x143)   // row_bcast:31
            u32 glo = (u32)__builtin_amdgcn_readlane((int)lo, 63);
            u32 ghi = (u32)__builtin_amdgcn_readlane((int)hi, 63);
            u64 gm = (((u64)ghi) << 32) | glo;
            if (lane == k) myres = (int)(glo & 511u);
            #pragma unroll
            for (int i = 0; i < 8; ++i)
                if (key[i] == gm) key[i] = ~0ULL;
        }
        if (lane < K_) srcArr[t * K_ + lane] = base + myres;

    } else if (bid < 10240) {
        // ---------------- node: emb -> hsrc/htgt, V ----------------
        const int n = bid - 2048;
        if (wid == 0) {
            int bf = detect_bf(trans, lane);
            int mm = detect_mm(xm, lane);
            if (lane == 0) { flagS[0] = bf; flagS[1] = mm; }
        }
        __syncthreads();
        const int bf = flagS[0], mm = flagS[1];
        if (tid < 140) {
            int r = tid / 35, c = tid - r * 35;
            float v;
            if (c < H_) {
                v = ldf(node, n * 128 + r * 32 + c, bf);
            } else if (r == 0) {
                v = (c == 34) ? ((ldmask(nm, n, mm) && !ldmask(xm, n, mm)) ? 1.f : 0.f) : 0.f;
            } else {
                int i = r - 1, a = c - 32;
                v = ldf(rots, n*9 + i*3 + 0, bf) * cBB[a*3 + 0]
                  + ldf(rots, n*9 + i*3 + 1, bf) * cBB[a*3 + 1]
                  + ldf(rots, n*9 + i*3 + 2, bf) * cBB[a*3 + 2];
            }
            eS[tid] = v;
        }
        __syncthreads();
        const int r = tid >> 6, cc = tid & 63;
        if (bf) {
            const u16* wa = (const u16*)Wa;
            const u16* wv = (const u16*)Wv;
            if (tid < 128) {
                float a = 0.f, b = 0.f;
                #pragma unroll 5
                for (int i = 0; i < 35; ++i) {
                    float v = eS[i];
                    a = fmaf(v, bfu16(wa[i * 128 + tid]),        a);
                    b = fmaf(v, bfu16(wa[(35 + i) * 128 + tid]), b);
                }
                hsrc[(size_t)n * 128 + tid] = a;
                htgt[(size_t)n * 128 + tid] = b;
            }
            const float* er = eS + r * 35;
            float acc = 0.f;
            #pragma unroll 5
            for (int cp = 0; cp < 35; ++cp) acc = fmaf(er[cp], bfu16(wv[cp * 64 + cc]), acc);
            V[(size_t)n * 256 + tid] = acc;
        } else {
            const float* wa = (const float*)Wa;
            const float* wv = (const float*)Wv;
            if (tid < 128) {
                float a = 0.f, b = 0.f;
                #pragma unroll 5
                for (int i = 0; i < 35; ++i) {
                    float v = eS[i];
                    a = fmaf(v, wa[i * 128 + tid],        a);
                    b = fmaf(v, wa[(35 + i) * 128 + tid], b);
                }
                hsrc[(size_t)n * 128 + tid] = a;
                htgt[(size_t)n * 128 + tid] = b;
            }
            const float* er = eS + r * 35;
            float acc = 0.f;
            #pragma unroll 5
            for (int cp = 0; cp < 35; ++cp) acc = fmaf(er[cp], wv[cp * 64 + cc], acc);
            V[(size_t)n * 256 + tid] = acc;
        }

    } else if (bid < 11264) {
        // ---------------- ptab row ----------------
        const int d = bid - 10240;
        if (wid == 0) {
            int bf = detect_bf(trans, lane);
            if (lane == 0) flagS[0] = bf;
        }
        __syncthreads();
        const int bf = flagS[0];
        if (tid < 128) {
            float dd = (float)(d - 512);
            float acc = 0.f;
            if (bf) {
                const u16* wa = (const u16*)Wa;
                #pragma unroll
                for (int q = 0; q < 8; ++q) {
                    float fr = expf((float)(2 * q) * (-0.5756462732485115f)); // -ln(1e4)/16
                    float ang = dd * fr;
                    acc = fmaf(cosf(ang), bfu16(wa[(86 + q) * 128 + tid]), acc);
                    acc = fmaf(sinf(ang), bfu16(wa[(94 + q) * 128 + tid]), acc);
                }
            } else {
                const float* wa = (const float*)Wa;
                #pragma unroll
                for (int q = 0; q < 8; ++q) {
                    float fr = expf((float)(2 * q) * (-0.5756462732485115f));
                    float ang = dd * fr;
                    acc = fmaf(cosf(ang), wa[(86 + q) * 128 + tid], acc);
                    acc = fmaf(sinf(ang), wa[(94 + q) * 128 + tid], acc);
                }
            }
            ptab[(size_t)d * 128 + tid] = acc;
        }

    } else {
        // ---------------- convert K2 weights + flag ----------------
        if (wid == 0) {
            int bf = detect_bf(trans, lane);
            if (lane == 0) flagS[0] = bf;
        }
        __syncthreads();
        const int bf = flagS[0];
        if (bid == 11264 && tid == 0) flag[0] = bf;
        int g0 = (bid - 11264) * 256 + tid;
        for (int i = g0; i < 6272; i += 2048) {
            if      (i < 2048) c_wrb[i]        = ldf(Wa, 70 * 128 + i, bf);
            else if (i < 2176) c_av[i - 2048]  = ldf(av, i - 2048, bf);
            else if (i < 4224) c_Wo[i - 2176]  = ldf(Wo, i - 2176, bf);
            else if (i < 5248) c_Wg[i - 4224]  = ldf(Wg, i - 4224, bf);
            else               c_W2[i - 5248]  = ldf(W2, i - 5248, bf);
        }
    }
}

// =============== kernel 2: fused logits + softmax + V-aggregation + epilogue ==============
__global__ __launch_bounds__(256) void edge_agg_kernel(
    const void* __restrict__ trans, const int* __restrict__ srcArr,
    const float* __restrict__ hsrc, const float* __restrict__ htgt,
    const float* __restrict__ ptab, const float* __restrict__ V,
    const float* __restrict__ c_wrb, const float* __restrict__ c_av,
    const float* __restrict__ Wo, const float* __restrict__ Wg,
    const float* __restrict__ W2,
    const int* __restrict__ flag, void* __restrict__ outv)
{
    __shared__ float rbfS[K_][20];      // pad 20 -> 16B-aligned rows
    __shared__ int   srcS[K_];
    __shared__ int   dS[K_];            // d | (invalid << 16)
    __shared__ float lgS[240];
    __shared__ float aggS[256];
    __shared__ float ybuf[128];
    __shared__ float gbuf[32];
    const int bid = blockIdx.x, tid = threadIdx.x;
    const int t   = ((bid & 7) << 10) | (bid >> 3);   // XCD-locality swizzle
    const int lane = tid & 63, wid = tid >> 6;
    const int bf = flag[0];

    // W_alpha rbf-block cols (2/lane) in 32 VGPRs
    float2 wrb[16];
    #pragma unroll
    for (int j = 0; j < 16; ++j) wrb[j] = ((const float2*)c_wrb)[j * 64 + lane];
    const float2 avv = ((const float2*)c_av)[lane];

    // ---- phase A: thread pairs own edges; each computes 8 of 16 rbf exps ----
    if (tid < 2 * K_) {
        const int k = tid >> 1, half = tid & 1;
        const int e = t * K_ + k;
        int src = srcArr[e];
        src = (src < 0) ? 0 : ((src >= N_) ? (N_ - 1) : src);
        float vx = ldf(trans, src*3+0, bf) - ldf(trans, t*3+0, bf);
        float vy = ldf(trans, src*3+1, bf) - ldf(trans, t*3+1, bf);
        float vz = ldf(trans, src*3+2, bf) - ldf(trans, t*3+2, bf);
        float dist = sqrtf(vx*vx + vy*vy + vz*vz);
        bool valid = isfinite(dist) && (dist > 1e-3f);
        int d = src - t + 512;
        d = (d < 0) ? 0 : ((d > 1023) ? 1023 : d);
        if (half == 0) {
            srcS[k] = src;
            dS[k]   = d | (valid ? 0 : (1 << 16));
        }
        const int jb = half * 8;
        #pragma unroll
        for (int j = 0; j < 8; ++j) {
            float tt = (dist - (float)(jb + j) * (20.f/15.f)) * 0.8f;
            rbfS[k][jb + j] = __expf(-tt * tt);
        }
    }
    __syncthreads();

    // ---- phase B: wave wid handles edges wid*8 .. wid*8+7 (<30) ----
    const float2 htv = ((const float2*)(htgt + (size_t)t * 128))[lane];  // block-constant
    #pragma unroll
    for (int j = 0; j < 8; ++j) {
        const int k = wid * 8 + j;
        if (k < K_) {
            const int src = srcS[k];
            const int dm  = dS[k];
            const int d   = dm & 0xFFFF;
            const bool valid = (dm >> 16) == 0;
            float2 hs = ((const float2*)(hsrc + (size_t)src * 128))[lane];
            float2 pt = ((const float2*)(ptab + (size_t)d   * 128))[lane];
            float acc0 = hs.x + htv.x + pt.x;
            float acc1 = hs.y + htv.y + pt.y;
            const float4* rp = (const float4*)(&rbfS[k][0]);
            #pragma unroll
            for (int jj = 0; jj < 4; ++jj) {
                float4 rb = rp[jj];         // broadcast read
                acc0 = fmaf(rb.x, wrb[4*jj+0].x, acc0); acc1 = fmaf(rb.x, wrb[4*jj+0].y, acc1);
                acc0 = fmaf(rb.y, wrb[4*jj+1].x, acc0); acc1 = fmaf(rb.y, wrb[4*jj+1].y, acc1);
                acc0 = fmaf(rb.z, wrb[4*jj+2].x, acc0); acc1 = fmaf(rb.z, wrb[4*jj+2].y, acc1);
                acc0 = fmaf(rb.w, wrb[4*jj+3].x, acc0); acc1 = fmaf(rb.w, wrb[4*jj+3].y, acc1);
            }
            float part = fsilu(acc0) * avv.x + fsilu(acc1) * avv.y;
            #pragma unroll
            for (int s = 1; s < 8; s <<= 1) part += __shfl_xor(part, s, 64);
            float lg = (part >= 0.f) ? part : 0.2f * part;
            if (!valid) lg = -1e9f;
            lg = (fabsf(lg) < 1e30f) ? lg : -1e9f;
            if ((lane & 7) == 0) lgS[k * 8 + (lane >> 3)] = lg;
        }
    }
    __syncthreads();

    // ---- phase C: per-thread softmax (head h) + alpha-weighted V sum ----
    {
        const int h = (tid & 63) >> 3;
        float lg[K_];
        float mx = -1e30f;
        #pragma unroll
        for (int k = 0; k < K_; ++k) { lg[k] = lgS[k * 8 + h]; mx = fmaxf(mx, lg[k]); }
        float den = 0.f;
        #pragma unroll
        for (int k = 0; k < K_; ++k) {
            float e = (lg[k] > -1e8f) ? __expf(lg[k] - mx) : 0.f;
            lg[k] = e; den += e;
        }
        const float inv = 1.f / (den + 1e-9f);
        float acc = 0.f;
        #pragma unroll 6
        for (int k = 0; k < K_; ++k)
            acc = fmaf(lg[k], V[(size_t)srcS[k] * 256 + tid], acc);
        aggS[tid] = acc * inv;
    }
    __syncthreads();

    // ---- epilogue: y = agg @ W_o ; gate = silu(y0 @ W_g) ; out = (y*gate) @ W_2 ----
    if (tid < 128) {
        int rr = tid >> 5, o = tid & 31;
        float y = 0.f;
        #pragma unroll
        for (int c = 0; c < 64; ++c) y = fmaf(aggS[rr * 64 + c], Wo[c * 32 + o], y);
        ybuf[tid] = y;
    }
    __syncthreads();
    if (tid < 32) {
        float g = 0.f;
        #pragma unroll
        for (int o = 0; o < 32; ++o) g = fmaf(ybuf[o], Wg[o * 32 + tid], g);
        gbuf[tid] = fsilu(g);
    }
    __syncthreads();
    if (tid < 128) {
        int rr = tid >> 5, hh = tid & 31;
        float o = 0.f;
        #pragma unroll
        for (int g = 0; g < 32; ++g) o = fmaf(ybuf[rr * 32 + g] * gbuf[g], W2[g * 32 + hh], o);
        o = (fabsf(o) < 1e30f) ? o : 0.f;
        size_t idx = (size_t)t * 128 + tid;
        if (bf) ((u16*)outv)[idx] = f2bf(o);
        else    ((float*)outv)[idx] = o;
    }
}

extern "C" void kernel_launch(void* const* d_in, const int* in_sizes, int n_in,
                              void* d_out, int out_size, void* d_ws, size_t ws_size,
                              hipStream_t stream)
{
    const void* rots         = d_in[0];
    const void* trans        = d_in[1];
    const void* node_emb     = d_in[2];
    /* d_in[3] = batch (unused; chains contiguous) */
    const void* x_mask       = d_in[4];
    const void* noising_mask = d_in[5];
    const void* Wa           = d_in[6];
    const void* avec         = d_in[7];
    const void* Wv           = d_in[8];
    const void* Wo           = d_in[9];
    const void* Wg           = d_in[10];
    const void* W2           = d_in[11];

    char* ws = (char*)d_ws;
    int*   flag    = (int*)  (ws + 0);            //        64
    int*   srcArr  = (int*)  (ws + 64);           //   983,040
    float* hsrc    = (float*)(ws + 983104);       // 4,194,304
    float* htgt    = (float*)(ws + 5177408);      // 4,194,304
    float* ptab    = (float*)(ws + 9371712);      //   524,288
    float* V       = (float*)(ws + 9896000);      // 8,388,608
    float* c_wrb   = (float*)(ws + 18284608);     //     8,192
    float* c_av    = (float*)(ws + 18292800);     //       512
    float* c_Wo    = (float*)(ws + 18293312);     //     8,192
    float* c_Wg    = (float*)(ws + 18301504);     //     4,096
    float* c_W2    = (float*)(ws + 18305600);     //     4,096  (end ~18.3 MB)

    hipLaunchKernelGGL(mega_kernel, dim3(11272), dim3(256), 0, stream,
                       rots, trans, node_emb, x_mask, noising_mask,
                       Wa, avec, Wv, Wo, Wg, W2,
                       flag, srcArr, hsrc, htgt, ptab, V,
                       c_wrb, c_av, c_Wo, c_Wg, c_W2);
    hipLaunchKernelGGL(edge_agg_kernel, dim3(N_), dim3(256), 0, stream,
                       trans, srcArr, hsrc, htgt, ptab, V,
                       c_wrb, c_av, c_Wo, c_Wg, c_W2, flag, d_out);
}

// Round 11
// 222.750 us; speedup vs baseline: 6.7754x; 1.0070x over previous
//
#include <hip/hip_runtime.h>
#include <cstdint>

#define B_ 16
#define L_ 512
#define N_ 8192
#define K_ 30
#define E_ (N_*K_)
#define H_ 32
#define C_ 35

typedef uint16_t u16;
typedef uint32_t u32;
typedef unsigned long long u64;

// adaptive float load: bf16 (u16<<16) or fp32
static __device__ __forceinline__ float ldf(const void* p, int i, int bf) {
    return bf ? __uint_as_float(((u32)((const u16*)p)[i]) << 16)
              : ((const float*)p)[i];
}
static __device__ __forceinline__ float bfu16(u16 x) {
    return __uint_as_float(((u32)x) << 16);
}
// mask load: mode 0 = u8 bool, 1 = int32, 2 = int64 (little-endian low word)
static __device__ __forceinline__ int ldmask(const void* p, int i, int mode) {
    if (mode == 0) return ((const unsigned char*)p)[i] != 0;
    if (mode == 2) return ((const u32*)p)[2*i] != 0;
    return ((const u32*)p)[i] != 0;
}
// f32 -> bf16 RNE
static __device__ __forceinline__ u16 f2bf(float f) {
    u32 x = __float_as_uint(f);
    u32 r = x + 0x7FFFu + ((x >> 16) & 1u);
    return (u16)(r >> 16);
}
// fast silu (~1e-7 rel err; threshold 4.3e-3)
static __device__ __forceinline__ float fsilu(float x) {
    return x * __builtin_amdgcn_rcpf(1.f + __expf(-x));
}

// per-block inline dtype detection (wave 0 only; deterministic)
static __device__ __forceinline__ int detect_bf(const void* tr, int lane) {
    const u16* p = (const u16*)tr;
    int cnt = 0;
    for (int i = lane; i < 256; i += 64) {
        u16 v = p[2 * i];
        int e = (v >> 7) & 0xFF;
        if ((e >= 100 && e <= 141) || (v & 0x7FFFu) == 0) cnt++;
    }
    #pragma unroll
    for (int d = 1; d < 64; d <<= 1) cnt += __shfl_xor(cnt, d, 64);
    return cnt >= 192;
}
static __device__ __forceinline__ int detect_mm(const void* xmv, int lane) {
    const u32* xm = (const u32*)xmv;
    int anyBig = 0, oddNZ = 0;
    for (int i = lane; i < 1024; i += 64) {
        u32 w = xm[i];
        if (w & ~1u) anyBig = 1;
        if ((i & 1) && w) oddNZ = 1;
    }
    #pragma unroll
    for (int d = 1; d < 64; d <<= 1) {
        anyBig |= __shfl_xor(anyBig, d, 64);
        oddNZ  |= __shfl_xor(oddNZ, d, 64);
    }
    return anyBig ? 0 : (oddNZ ? 1 : 2);
}

__constant__ float cBB[9] = {-0.525f, 1.363f, 0.f,  0.f, 0.f, 0.f,  1.526f, 0.f, 0.f};

// DPP u64-key min step (VALU pipe, not the CU-shared LDS pipe)
#define DPP_MIN_STEP(CTRL) \
    { u32 olo = (u32)__builtin_amdgcn_update_dpp((int)lo, (int)lo, CTRL, 0xF, 0xF, false); \
      u32 ohi = (u32)__builtin_amdgcn_update_dpp((int)hi, (int)hi, CTRL, 0xF, 0xF, false); \
      u64 o = (((u64)ohi) << 32) | olo; \
      if (o < m) m = o; \
      lo = (u32)m; hi = (u32)(m >> 32); }

// =============== kernel 1: mega prep (knn | node | ptab | weight-convert) =================
__global__ __launch_bounds__(256) void mega_kernel(
    const void* __restrict__ rots, const void* __restrict__ trans,
    const void* __restrict__ node, const void* __restrict__ xm,
    const void* __restrict__ nm,
    const void* __restrict__ Wa, const void* __restrict__ av,
    const void* __restrict__ Wv, const void* __restrict__ Wo,
    const void* __restrict__ Wg, const void* __restrict__ W2,
    int* __restrict__ flag, int* __restrict__ srcArr,
    float* __restrict__ hsrc, float* __restrict__ htgt,
    float* __restrict__ ptab, float* __restrict__ V,
    float* __restrict__ c_wrb, float* __restrict__ c_av,
    float* __restrict__ c_Wo, float* __restrict__ c_Wg, float* __restrict__ c_W2)
{
    __shared__ float sX[L_], sY[L_], sZ[L_];
    __shared__ float eS[140];
    __shared__ int flagS[2];
    const int bid = blockIdx.x, tid = threadIdx.x;
    const int lane = tid & 63, wid = tid >> 6;

    if (bid < 2048) {
        // ---------------- kNN ----------------
        if (wid == 0) {
            int bf = detect_bf(trans, lane);
            if (lane == 0) flagS[0] = bf;
        }
        __syncthreads();
        const int bf = flagS[0];
        const int t0 = bid * 4;
        const int base = (t0 >> 9) << 9;
        if (bf) {
            const u16* tp = (const u16*)trans;
            for (int i = tid; i < L_; i += 256) {
                sX[i] = bfu16(tp[(base + i) * 3 + 0]);
                sY[i] = bfu16(tp[(base + i) * 3 + 1]);
                sZ[i] = bfu16(tp[(base + i) * 3 + 2]);
            }
        } else {
            const float* tp = (const float*)trans;
            for (int i = tid; i < L_; i += 256) {
                sX[i] = tp[(base + i) * 3 + 0];
                sY[i] = tp[(base + i) * 3 + 1];
                sZ[i] = tp[(base + i) * 3 + 2];
            }
        }
        __syncthreads();

        const int t = t0 + wid;
        const int l = t & 511;
        const float tx = sX[l], ty = sY[l], tz = sZ[l];

        u64 key[8];
        #pragma unroll
        for (int i = 0; i < 8; ++i) {
            int j = lane + (i << 6);
            // match numpy: ((dx*dx + dy*dy) + dz*dz), no FMA contraction
            float dx = __fsub_rn(tx, sX[j]);
            float dy = __fsub_rn(ty, sY[j]);
            float dz = __fsub_rn(tz, sZ[j]);
            float d2 = __fadd_rn(__fadd_rn(__fmul_rn(dx, dx), __fmul_rn(dy, dy)), __fmul_rn(dz, dz));
            if (j == l) d2 = __fadd_rn(d2, 1e9f);
            key[i] = (((u64)__float_as_uint(d2)) << 32) | (u32)j;
        }
        int myres = 0;
        for (int k = 0; k < K_; ++k) {
            u64 m = key[0];
            #pragma unroll
            for (int i = 1; i < 8; ++i)
                if (key[i] < m) m = key[i];
            u32 lo = (u32)m, hi = (u32)(m >> 32);
            DPP_MIN_STEP(0x111)   // row_shr:1
            DPP_MIN_STEP(0x112)   // row_shr:2
            DPP_MIN_STEP(0x114)   // row_shr:4
            DPP_MIN_STEP(0x118)   // row_shr:8
            DPP_MIN_STEP(0x142)   // row_bcast:15
            DPP_MIN_STEP(0x143)   // row_bcast:31
            u32 glo = (u32)__builtin_amdgcn_readlane((int)lo, 63);
            u32 ghi = (u32)__builtin_amdgcn_readlane((int)hi, 63);
            u64 gm = (((u64)ghi) << 32) | glo;
            if (lane == k) myres = (int)(glo & 511u);
            #pragma unroll
            for (int i = 0; i < 8; ++i)
                if (key[i] == gm) key[i] = ~0ULL;
        }
        if (lane < K_) srcArr[t * K_ + lane] = base + myres;

    } else if (bid < 10240) {
        // ---------------- node: emb -> hsrc/htgt, V ----------------
        const int n = bid - 2048;
        if (wid == 0) {
            int bf = detect_bf(trans, lane);
            int mm = detect_mm(xm, lane);
            if (lane == 0) { flagS[0] = bf; flagS[1] = mm; }
        }
        __syncthreads();
        const int bf = flagS[0], mm = flagS[1];
        if (tid < 140) {
            int r = tid / 35, c = tid - r * 35;
            float v;
            if (c < H_) {
                v = ldf(node, n * 128 + r * 32 + c, bf);
            } else if (r == 0) {
                v = (c == 34) ? ((ldmask(nm, n, mm) && !ldmask(xm, n, mm)) ? 1.f : 0.f) : 0.f;
            } else {
                int i = r - 1, a = c - 32;
                v = ldf(rots, n*9 + i*3 + 0, bf) * cBB[a*3 + 0]
                  + ldf(rots, n*9 + i*3 + 1, bf) * cBB[a*3 + 1]
                  + ldf(rots, n*9 + i*3 + 2, bf) * cBB[a*3 + 2];
            }
            eS[tid] = v;
        }
        __syncthreads();
        const int r = tid >> 6, cc = tid & 63;
        if (bf) {
            const u16* wa = (const u16*)Wa;
            const u16* wv = (const u16*)Wv;
            if (tid < 128) {
                float a = 0.f, b = 0.f;
                #pragma unroll 5
                for (int i = 0; i < 35; ++i) {
                    float v = eS[i];
                    a = fmaf(v, bfu16(wa[i * 128 + tid]),        a);
                    b = fmaf(v, bfu16(wa[(35 + i) * 128 + tid]), b);
                }
                hsrc[(size_t)n * 128 + tid] = a;
                htgt[(size_t)n * 128 + tid] = b;
            }
            const float* er = eS + r * 35;
            float acc = 0.f;
            #pragma unroll 5
            for (int cp = 0; cp < 35; ++cp) acc = fmaf(er[cp], bfu16(wv[cp * 64 + cc]), acc);
            V[(size_t)n * 256 + tid] = acc;
        } else {
            const float* wa = (const float*)Wa;
            const float* wv = (const float*)Wv;
            if (tid < 128) {
                float a = 0.f, b = 0.f;
                #pragma unroll 5
                for (int i = 0; i < 35; ++i) {
                    float v = eS[i];
                    a = fmaf(v, wa[i * 128 + tid],        a);
                    b = fmaf(v, wa[(35 + i) * 128 + tid], b);
                }
                hsrc[(size_t)n * 128 + tid] = a;
                htgt[(size_t)n * 128 + tid] = b;
            }
            const float* er = eS + r * 35;
            float acc = 0.f;
            #pragma unroll 5
            for (int cp = 0; cp < 35; ++cp) acc = fmaf(er[cp], wv[cp * 64 + cc], acc);
            V[(size_t)n * 256 + tid] = acc;
        }

    } else if (bid < 11264) {
        // ---------------- ptab row ----------------
        const int d = bid - 10240;
        if (wid == 0) {
            int bf = detect_bf(trans, lane);
            if (lane == 0) flagS[0] = bf;
        }
        __syncthreads();
        const int bf = flagS[0];
        if (tid < 128) {
            float dd = (float)(d - 512);
            float acc = 0.f;
            if (bf) {
                const u16* wa = (const u16*)Wa;
                #pragma unroll
                for (int q = 0; q < 8; ++q) {
                    float fr = expf((float)(2 * q) * (-0.5756462732485115f)); // -ln(1e4)/16
                    float ang = dd * fr;
                    acc = fmaf(cosf(ang), bfu16(wa[(86 + q) * 128 + tid]), acc);
                    acc = fmaf(sinf(ang), bfu16(wa[(94 + q) * 128 + tid]), acc);
                }
            } else {
                const float* wa = (const float*)Wa;
                #pragma unroll
                for (int q = 0; q < 8; ++q) {
                    float fr = expf((float)(2 * q) * (-0.5756462732485115f));
                    float ang = dd * fr;
                    acc = fmaf(cosf(ang), wa[(86 + q) * 128 + tid], acc);
                    acc = fmaf(sinf(ang), wa[(94 + q) * 128 + tid], acc);
                }
            }
            ptab[(size_t)d * 128 + tid] = acc;
        }

    } else {
        // ---------------- convert K2 weights + flag ----------------
        if (wid == 0) {
            int bf = detect_bf(trans, lane);
            if (lane == 0) flagS[0] = bf;
        }
        __syncthreads();
        const int bf = flagS[0];
        if (bid == 11264 && tid == 0) flag[0] = bf;
        int g0 = (bid - 11264) * 256 + tid;
        for (int i = g0; i < 6272; i += 2048) {
            if      (i < 2048) c_wrb[i]        = ldf(Wa, 70 * 128 + i, bf);
            else if (i < 2176) c_av[i - 2048]  = ldf(av, i - 2048, bf);
            else if (i < 4224) c_Wo[i - 2176]  = ldf(Wo, i - 2176, bf);
            else if (i < 5248) c_Wg[i - 4224]  = ldf(Wg, i - 4224, bf);
            else               c_W2[i - 5248]  = ldf(W2, i - 5248, bf);
        }
    }
}

// =============== kernel 2: fused logits + softmax + V-aggregation + epilogue ==============
// launch_bounds(256,4): 128-VGPR budget so wrb[16] (32 VGPRs) stays register-resident
// (r10 compiled to 36 VGPRs -> compiler rematerialized the weight loads per edge).
__global__ __launch_bounds__(256, 4) void edge_agg_kernel(
    const void* __restrict__ trans, const int* __restrict__ srcArr,
    const float* __restrict__ hsrc, const float* __restrict__ htgt,
    const float* __restrict__ ptab, const float* __restrict__ V,
    const float* __restrict__ c_wrb, const float* __restrict__ c_av,
    const float* __restrict__ Wo, const float* __restrict__ Wg,
    const float* __restrict__ W2,
    const int* __restrict__ flag, void* __restrict__ outv)
{
    __shared__ float rbfS[K_][20];      // pad 20 -> 16B-aligned rows
    __shared__ int   srcS[K_];
    __shared__ int   voffS[K_];         // src*256 (V row offset, precomputed)
    __shared__ int   dS[K_];            // d | (invalid << 16)
    __shared__ float lgS[240];          // logits, then unnormalized exp weights
    __shared__ float invS[8];
    __shared__ float aggS[256];
    __shared__ float ybuf[128];
    __shared__ float gbuf[32];
    const int bid = blockIdx.x, tid = threadIdx.x;
    const int t   = ((bid & 7) << 10) | (bid >> 3);   // XCD-locality swizzle
    const int lane = tid & 63, wid = tid >> 6;
    const int bf = flag[0];

    // W_alpha rbf-block cols (2/lane) in 32 VGPRs (register-resident under (256,4))
    float2 wrb[16];
    #pragma unroll
    for (int j = 0; j < 16; ++j) wrb[j] = ((const float2*)c_wrb)[j * 64 + lane];
    const float2 avv = ((const float2*)c_av)[lane];

    // ---- phase A: 8 threads per edge (redundant scalar, 2 exps each) — all 4 waves busy ----
    if (tid < 8 * K_) {
        const int k = tid >> 3, sub = tid & 7;
        const int e = t * K_ + k;
        int src = srcArr[e];
        src = (src < 0) ? 0 : ((src >= N_) ? (N_ - 1) : src);
        float vx = ldf(trans, src*3+0, bf) - ldf(trans, t*3+0, bf);
        float vy = ldf(trans, src*3+1, bf) - ldf(trans, t*3+1, bf);
        float vz = ldf(trans, src*3+2, bf) - ldf(trans, t*3+2, bf);
        float dist = sqrtf(vx*vx + vy*vy + vz*vz);
        bool valid = isfinite(dist) && (dist > 1e-3f);
        int d = src - t + 512;
        d = (d < 0) ? 0 : ((d > 1023) ? 1023 : d);
        if (sub == 0) {
            srcS[k]  = src;
            voffS[k] = src << 8;
            dS[k]    = d | (valid ? 0 : (1 << 16));
        }
        const int j0 = sub * 2;
        float t0 = (dist - (float)j0       * (20.f/15.f)) * 0.8f;
        float t1 = (dist - (float)(j0 + 1) * (20.f/15.f)) * 0.8f;
        rbfS[k][j0]     = __expf(-t0 * t0);
        rbfS[k][j0 + 1] = __expf(-t1 * t1);
    }
    __syncthreads();

    // ---- phase B: wave wid handles edges wid*8 .. wid*8+7 (<30) ----
    const float2 htv = ((const float2*)(htgt + (size_t)t * 128))[lane];  // block-constant
    #pragma unroll
    for (int j = 0; j < 8; ++j) {
        const int k = wid * 8 + j;
        if (k < K_) {
            const int src = srcS[k];
            const int dm  = dS[k];
            const int d   = dm & 0xFFFF;
            const bool valid = (dm >> 16) == 0;
            float2 hs = ((const float2*)(hsrc + (size_t)src * 128))[lane];
            float2 pt = ((const float2*)(ptab + (size_t)d   * 128))[lane];
            float acc0 = hs.x + htv.x + pt.x;
            float acc1 = hs.y + htv.y + pt.y;
            const float4* rp = (const float4*)(&rbfS[k][0]);
            #pragma unroll
            for (int jj = 0; jj < 4; ++jj) {
                float4 rb = rp[jj];         // broadcast read
                acc0 = fmaf(rb.x, wrb[4*jj+0].x, acc0); acc1 = fmaf(rb.x, wrb[4*jj+0].y, acc1);
                acc0 = fmaf(rb.y, wrb[4*jj+1].x, acc0); acc1 = fmaf(rb.y, wrb[4*jj+1].y, acc1);
                acc0 = fmaf(rb.z, wrb[4*jj+2].x, acc0); acc1 = fmaf(rb.z, wrb[4*jj+2].y, acc1);
                acc0 = fmaf(rb.w, wrb[4*jj+3].x, acc0); acc1 = fmaf(rb.w, wrb[4*jj+3].y, acc1);
            }
            float part = fsilu(acc0) * avv.x + fsilu(acc1) * avv.y;
            #pragma unroll
            for (int s = 1; s < 8; s <<= 1) part += __shfl_xor(part, s, 64);
            float lg = (part >= 0.f) ? part : 0.2f * part;
            if (!valid) lg = -1e9f;
            lg = (fabsf(lg) < 1e30f) ? lg : -1e9f;
            if ((lane & 7) == 0) lgS[k * 8 + (lane >> 3)] = lg;
        }
    }
    __syncthreads();

    // ---- softmax numerators once per (k,h): thread h handles head h ----
    if (tid < 8) {
        float mx = -1e30f;
        #pragma unroll
        for (int k = 0; k < K_; ++k) mx = fmaxf(mx, lgS[k * 8 + tid]);
        float den = 0.f;
        #pragma unroll
        for (int k = 0; k < K_; ++k) {
            float l = lgS[k * 8 + tid];
            float e = (l > -1e8f) ? __expf(l - mx) : 0.f;
            lgS[k * 8 + tid] = e; den += e;
        }
        invS[tid] = 1.f / (den + 1e-9f);
    }
    __syncthreads();

    // ---- phase C: weighted V sum (pure FMA; same accumulation order as r10) ----
    {
        const int h = (tid & 63) >> 3;
        float acc = 0.f;
        #pragma unroll 6
        for (int k = 0; k < K_; ++k)
            acc = fmaf(lgS[k * 8 + h], V[voffS[k] + tid], acc);
        aggS[tid] = acc * invS[h];
    }
    __syncthreads();

    // ---- epilogue: y = agg @ W_o ; gate = silu(y0 @ W_g) ; out = (y*gate) @ W_2 ----
    if (tid < 128) {
        int rr = tid >> 5, o = tid & 31;
        float y = 0.f;
        #pragma unroll
        for (int c = 0; c < 64; ++c) y = fmaf(aggS[rr * 64 + c], Wo[c * 32 + o], y);
        ybuf[tid] = y;
    }
    __syncthreads();
    if (tid < 32) {
        float g = 0.f;
        #pragma unroll
        for (int o = 0; o < 32; ++o) g = fmaf(ybuf[o], Wg[o * 32 + tid], g);
        gbuf[tid] = fsilu(g);
    }
    __syncthreads();
    if (tid < 128) {
        int rr = tid >> 5, hh = tid & 31;
        float o = 0.f;
        #pragma unroll
        for (int g = 0; g < 32; ++g) o = fmaf(ybuf[rr * 32 + g] * gbuf[g], W2[g * 32 + hh], o);
        o = (fabsf(o) < 1e30f) ? o : 0.f;
        size_t idx = (size_t)t * 128 + tid;
        if (bf) ((u16*)outv)[idx] = f2bf(o);
        else    ((float*)outv)[idx] = o;
    }
}

extern "C" void kernel_launch(void* const* d_in, const int* in_sizes, int n_in,
                              void* d_out, int out_size, void* d_ws, size_t ws_size,
                              hipStream_t stream)
{
    const void* rots         = d_in[0];
    const void* trans        = d_in[1];
    const void* node_emb     = d_in[2];
    /* d_in[3] = batch (unused; chains contiguous) */
    const void* x_mask       = d_in[4];
    const void* noising_mask = d_in[5];
    const void* Wa           = d_in[6];
    const void* avec         = d_in[7];
    const void* Wv           = d_in[8];
    const void* Wo           = d_in[9];
    const void* Wg           = d_in[10];
    const void* W2           = d_in[11];

    char* ws = (char*)d_ws;
    int*   flag    = (int*)  (ws + 0);            //        64
    int*   srcArr  = (int*)  (ws + 64);           //   983,040
    float* hsrc    = (float*)(ws + 983104);       // 4,194,304
    float* htgt    = (float*)(ws + 5177408);      // 4,194,304
    float* ptab    = (float*)(ws + 9371712);      //   524,288
    float* V       = (float*)(ws + 9896000);      // 8,388,608
    float* c_wrb   = (float*)(ws + 18284608);     //     8,192
    float* c_av    = (float*)(ws + 18292800);     //       512
    float* c_Wo    = (float*)(ws + 18293312);     //     8,192
    float* c_Wg    = (float*)(ws + 18301504);     //     4,096
    float* c_W2    = (float*)(ws + 18305600);     //     4,096  (end ~18.3 MB)

    hipLaunchKernelGGL(mega_kernel, dim3(11272), dim3(256), 0, stream,
                       rots, trans, node_emb, x_mask, noising_mask,
                       Wa, avec, Wv, Wo, Wg, W2,
                       flag, srcArr, hsrc, htgt, ptab, V,
                       c_wrb, c_av, c_Wo, c_Wg, c_W2);
    hipLaunchKernelGGL(edge_agg_kernel, dim3(N_), dim3(256), 0, stream,
                       trans, srcArr, hsrc, htgt, ptab, V,
                       c_wrb, c_av, c_Wo, c_Wg, c_W2, flag, d_out);
}

// Round 12
// 213.032 us; speedup vs baseline: 7.0844x; 1.0456x over previous
//
#include <hip/hip_runtime.h>
#include <cstdint>

#define B_ 16
#define L_ 512
#define N_ 8192
#define K_ 30
#define E_ (N_*K_)
#define H_ 32
#define C_ 35

typedef uint16_t u16;
typedef uint32_t u32;
typedef unsigned long long u64;

// adaptive float load: bf16 (u16<<16) or fp32
static __device__ __forceinline__ float ldf(const void* p, int i, int bf) {
    return bf ? __uint_as_float(((u32)((const u16*)p)[i]) << 16)
              : ((const float*)p)[i];
}
static __device__ __forceinline__ float bfu16(u16 x) {
    return __uint_as_float(((u32)x) << 16);
}
// mask load: mode 0 = u8 bool, 1 = int32, 2 = int64 (little-endian low word)
static __device__ __forceinline__ int ldmask(const void* p, int i, int mode) {
    if (mode == 0) return ((const unsigned char*)p)[i] != 0;
    if (mode == 2) return ((const u32*)p)[2*i] != 0;
    return ((const u32*)p)[i] != 0;
}
// f32 -> bf16 RNE
static __device__ __forceinline__ u16 f2bf(float f) {
    u32 x = __float_as_uint(f);
    u32 r = x + 0x7FFFu + ((x >> 16) & 1u);
    return (u16)(r >> 16);
}
// fast silu (~1e-7 rel err; threshold 4.3e-3)
static __device__ __forceinline__ float fsilu(float x) {
    return x * __builtin_amdgcn_rcpf(1.f + __expf(-x));
}

// per-block inline dtype detection (wave 0 only; deterministic)
static __device__ __forceinline__ int detect_bf(const void* tr, int lane) {
    const u16* p = (const u16*)tr;
    int cnt = 0;
    for (int i = lane; i < 256; i += 64) {
        u16 v = p[2 * i];
        int e = (v >> 7) & 0xFF;
        if ((e >= 100 && e <= 141) || (v & 0x7FFFu) == 0) cnt++;
    }
    #pragma unroll
    for (int d = 1; d < 64; d <<= 1) cnt += __shfl_xor(cnt, d, 64);
    return cnt >= 192;
}
static __device__ __forceinline__ int detect_mm(const void* xmv, int lane) {
    const u32* xm = (const u32*)xmv;
    int anyBig = 0, oddNZ = 0;
    for (int i = lane; i < 1024; i += 64) {
        u32 w = xm[i];
        if (w & ~1u) anyBig = 1;
        if ((i & 1) && w) oddNZ = 1;
    }
    #pragma unroll
    for (int d = 1; d < 64; d <<= 1) {
        anyBig |= __shfl_xor(anyBig, d, 64);
        oddNZ  |= __shfl_xor(oddNZ, d, 64);
    }
    return anyBig ? 0 : (oddNZ ? 1 : 2);
}

__constant__ float cBB[9] = {-0.525f, 1.363f, 0.f,  0.f, 0.f, 0.f,  1.526f, 0.f, 0.f};

// u32 DPP min step (VALU pipe; d2>=0 -> f32 bit order == u32 order)
#define DPP_UMIN(var, CTRL) \
    { u32 o_ = (u32)__builtin_amdgcn_update_dpp((int)(var), (int)(var), CTRL, 0xF, 0xF, false); \
      (var) = (o_ < (var)) ? o_ : (var); }
#define DPP_UMIN_ALL(var) \
    DPP_UMIN(var, 0x111) DPP_UMIN(var, 0x112) DPP_UMIN(var, 0x114) \
    DPP_UMIN(var, 0x118) DPP_UMIN(var, 0x142) DPP_UMIN(var, 0x143)

// =============== kernel 1: mega prep (knn | node | ptab | weight-convert) =================
__global__ __launch_bounds__(256) void mega_kernel(
    const void* __restrict__ rots, const void* __restrict__ trans,
    const void* __restrict__ node, const void* __restrict__ xm,
    const void* __restrict__ nm,
    const void* __restrict__ Wa, const void* __restrict__ av,
    const void* __restrict__ Wv, const void* __restrict__ Wo,
    const void* __restrict__ Wg, const void* __restrict__ W2,
    int* __restrict__ flag, int* __restrict__ srcArr,
    float* __restrict__ hsrc, float* __restrict__ htgt,
    float* __restrict__ ptab, float* __restrict__ V,
    float* __restrict__ c_wrb, float* __restrict__ c_av,
    float* __restrict__ c_Wo, float* __restrict__ c_Wg, float* __restrict__ c_W2)
{
    __shared__ float sX[L_], sY[L_], sZ[L_];
    __shared__ float eS[140];
    __shared__ int flagS[2];
    const int bid = blockIdx.x, tid = threadIdx.x;
    const int lane = tid & 63, wid = tid >> 6;

    if (bid < 2048) {
        // ---------------- kNN: u32-bit d2 keys, two-phase DPP argmin ----------------
        if (wid == 0) {
            int bf = detect_bf(trans, lane);
            if (lane == 0) flagS[0] = bf;
        }
        __syncthreads();
        const int bf = flagS[0];
        const int t0 = bid * 4;
        const int base = (t0 >> 9) << 9;
        if (bf) {
            const u16* tp = (const u16*)trans;
            for (int i = tid; i < L_; i += 256) {
                sX[i] = bfu16(tp[(base + i) * 3 + 0]);
                sY[i] = bfu16(tp[(base + i) * 3 + 1]);
                sZ[i] = bfu16(tp[(base + i) * 3 + 2]);
            }
        } else {
            const float* tp = (const float*)trans;
            for (int i = tid; i < L_; i += 256) {
                sX[i] = tp[(base + i) * 3 + 0];
                sY[i] = tp[(base + i) * 3 + 1];
                sZ[i] = tp[(base + i) * 3 + 2];
            }
        }
        __syncthreads();

        const int t = t0 + wid;
        const int l = t & 511;
        const float tx = sX[l], ty = sY[l], tz = sZ[l];

        u32 d2b[8];              // f32 bits of d2 (non-negative -> u32-order preserving)
        #pragma unroll
        for (int i = 0; i < 8; ++i) {
            int j = lane + (i << 6);
            // match numpy: ((dx*dx + dy*dy) + dz*dz), no FMA contraction
            float dx = __fsub_rn(tx, sX[j]);
            float dy = __fsub_rn(ty, sY[j]);
            float dz = __fsub_rn(tz, sZ[j]);
            float d2 = __fadd_rn(__fadd_rn(__fmul_rn(dx, dx), __fmul_rn(dy, dy)), __fmul_rn(dz, dz));
            if (j == l) d2 = __fadd_rn(d2, 1e9f);
            d2b[i] = __float_as_uint(d2);
        }

        int myres = 0;
        for (int k = 0; k < K_; ++k) {
            // local min over 8 slots; strict < keeps lowest slot (= lowest idx) on bit-ties
            u32 bb = d2b[0]; int bs = 0;
            #pragma unroll
            for (int i = 1; i < 8; ++i)
                if (d2b[i] < bb) { bb = d2b[i]; bs = i; }
            // phase 1: wave min of d2 bits
            u32 m = bb;
            DPP_UMIN_ALL(m)
            u32 gbits = (u32)__builtin_amdgcn_readlane((int)m, 63);
            // phase 2: min idx among exact-bit ties (lax.top_k tiebreak)
            u32 cand = (bb == gbits) ? (u32)(lane | (bs << 6)) : 0xFFFFFFFFu;
            DPP_UMIN_ALL(cand)
            u32 gidx = (u32)__builtin_amdgcn_readlane((int)cand, 63);
            if (lane == (u32)k) myres = (int)(gidx & 511u);
            if ((gidx & 63u) == (u32)lane) {        // winner lane invalidates its slot
                int ws = (int)(gidx >> 6);
                #pragma unroll
                for (int i = 0; i < 8; ++i)
                    if (ws == i) d2b[i] = 0xFFFFFFFFu;
            }
        }
        if (lane < K_) srcArr[t * K_ + lane] = base + myres;

    } else if (bid < 10240) {
        // ---------------- node: emb -> hsrc/htgt, V ----------------
        const int n = bid - 2048;
        if (wid == 0) {
            int bf = detect_bf(trans, lane);
            int mm = detect_mm(xm, lane);
            if (lane == 0) { flagS[0] = bf; flagS[1] = mm; }
        }
        __syncthreads();
        const int bf = flagS[0], mm = flagS[1];
        if (tid < 140) {
            int r = tid / 35, c = tid - r * 35;
            float v;
            if (c < H_) {
                v = ldf(node, n * 128 + r * 32 + c, bf);
            } else if (r == 0) {
                v = (c == 34) ? ((ldmask(nm, n, mm) && !ldmask(xm, n, mm)) ? 1.f : 0.f) : 0.f;
            } else {
                int i = r - 1, a = c - 32;
                v = ldf(rots, n*9 + i*3 + 0, bf) * cBB[a*3 + 0]
                  + ldf(rots, n*9 + i*3 + 1, bf) * cBB[a*3 + 1]
                  + ldf(rots, n*9 + i*3 + 2, bf) * cBB[a*3 + 2];
            }
            eS[tid] = v;
        }
        __syncthreads();
        const int r = tid >> 6, cc = tid & 63;
        if (bf) {
            const u16* wa = (const u16*)Wa;
            const u16* wv = (const u16*)Wv;
            if (tid < 128) {
                float a = 0.f, b = 0.f;
                #pragma unroll 5
                for (int i = 0; i < 35; ++i) {
                    float v = eS[i];
                    a = fmaf(v, bfu16(wa[i * 128 + tid]),        a);
                    b = fmaf(v, bfu16(wa[(35 + i) * 128 + tid]), b);
                }
                hsrc[(size_t)n * 128 + tid] = a;
                htgt[(size_t)n * 128 + tid] = b;
            }
            const float* er = eS + r * 35;
            float acc = 0.f;
            #pragma unroll 5
            for (int cp = 0; cp < 35; ++cp) acc = fmaf(er[cp], bfu16(wv[cp * 64 + cc]), acc);
            V[(size_t)n * 256 + tid] = acc;
        } else {
            const float* wa = (const float*)Wa;
            const float* wv = (const float*)Wv;
            if (tid < 128) {
                float a = 0.f, b = 0.f;
                #pragma unroll 5
                for (int i = 0; i < 35; ++i) {
                    float v = eS[i];
                    a = fmaf(v, wa[i * 128 + tid],        a);
                    b = fmaf(v, wa[(35 + i) * 128 + tid], b);
                }
                hsrc[(size_t)n * 128 + tid] = a;
                htgt[(size_t)n * 128 + tid] = b;
            }
            const float* er = eS + r * 35;
            float acc = 0.f;
            #pragma unroll 5
            for (int cp = 0; cp < 35; ++cp) acc = fmaf(er[cp], wv[cp * 64 + cc], acc);
            V[(size_t)n * 256 + tid] = acc;
        }

    } else if (bid < 11264) {
        // ---------------- ptab row ----------------
        const int d = bid - 10240;
        if (wid == 0) {
            int bf = detect_bf(trans, lane);
            if (lane == 0) flagS[0] = bf;
        }
        __syncthreads();
        const int bf = flagS[0];
        if (tid < 128) {
            float dd = (float)(d - 512);
            float acc = 0.f;
            if (bf) {
                const u16* wa = (const u16*)Wa;
                #pragma unroll
                for (int q = 0; q < 8; ++q) {
                    float fr = expf((float)(2 * q) * (-0.5756462732485115f)); // -ln(1e4)/16
                    float ang = dd * fr;
                    acc = fmaf(cosf(ang), bfu16(wa[(86 + q) * 128 + tid]), acc);
                    acc = fmaf(sinf(ang), bfu16(wa[(94 + q) * 128 + tid]), acc);
                }
            } else {
                const float* wa = (const float*)Wa;
                #pragma unroll
                for (int q = 0; q < 8; ++q) {
                    float fr = expf((float)(2 * q) * (-0.5756462732485115f));
                    float ang = dd * fr;
                    acc = fmaf(cosf(ang), wa[(86 + q) * 128 + tid], acc);
                    acc = fmaf(sinf(ang), wa[(94 + q) * 128 + tid], acc);
                }
            }
            ptab[(size_t)d * 128 + tid] = acc;
        }

    } else {
        // ---------------- convert K2 weights + flag ----------------
        if (wid == 0) {
            int bf = detect_bf(trans, lane);
            if (lane == 0) flagS[0] = bf;
        }
        __syncthreads();
        const int bf = flagS[0];
        if (bid == 11264 && tid == 0) flag[0] = bf;
        int g0 = (bid - 11264) * 256 + tid;
        for (int i = g0; i < 6272; i += 2048) {
            if      (i < 2048) c_wrb[i]        = ldf(Wa, 70 * 128 + i, bf);
            else if (i < 2176) c_av[i - 2048]  = ldf(av, i - 2048, bf);
            else if (i < 4224) c_Wo[i - 2176]  = ldf(Wo, i - 2176, bf);
            else if (i < 5248) c_Wg[i - 4224]  = ldf(Wg, i - 4224, bf);
            else               c_W2[i - 5248]  = ldf(W2, i - 5248, bf);
        }
    }
}

// =============== kernel 2: fused logits + softmax + V-aggregation + epilogue ==============
// wrb as 16 NAMED float2 scalars + branch-free padded 32-edge loop: both register-demotion
// triggers removed (r11 compiled to 36 VGPR -> weights reloaded per edge).
__global__ __launch_bounds__(256, 4) void edge_agg_kernel(
    const void* __restrict__ trans, const int* __restrict__ srcArr,
    const float* __restrict__ hsrc, const float* __restrict__ htgt,
    const float* __restrict__ ptab, const float* __restrict__ V,
    const float* __restrict__ c_wrb, const float* __restrict__ c_av,
    const float* __restrict__ Wo, const float* __restrict__ Wg,
    const float* __restrict__ W2,
    const int* __restrict__ flag, void* __restrict__ outv)
{
    __shared__ float rbfS[32][20];      // padded to 32 edges; 20 -> 16B-aligned rows
    __shared__ int   srcS[32];
    __shared__ int   voffS[32];         // src*256 (V row offset)
    __shared__ int   dS[32];            // d | (invalid << 16)
    __shared__ float lgS[256];          // logits (k<32), then unnormalized exp weights
    __shared__ float invS[8];
    __shared__ float aggS[256];
    __shared__ float ybuf[128];
    __shared__ float gbuf[32];
    const int bid = blockIdx.x, tid = threadIdx.x;
    const int t   = ((bid & 7) << 10) | (bid >> 3);   // XCD-locality swizzle
    const int lane = tid & 63, wid = tid >> 6;
    const int bf = flag[0];

    // W_alpha rbf-block cols (2/lane) as named scalars -> 32 VGPRs register-resident
    const float2* cw = (const float2*)c_wrb;
    const float2 w0 = cw[0*64+lane],  w1 = cw[1*64+lane],  w2 = cw[2*64+lane],  w3 = cw[3*64+lane];
    const float2 w4 = cw[4*64+lane],  w5 = cw[5*64+lane],  w6 = cw[6*64+lane],  w7 = cw[7*64+lane];
    const float2 w8 = cw[8*64+lane],  w9 = cw[9*64+lane],  wA = cw[10*64+lane], wB = cw[11*64+lane];
    const float2 wC = cw[12*64+lane], wD = cw[13*64+lane], wE = cw[14*64+lane], wF = cw[15*64+lane];
    const float2 avv = ((const float2*)c_av)[lane];

    // ---- phase A: 8 threads per edge (2 exps each); pad edges 30,31 as invalid ----
    if (tid < 8 * K_) {
        const int k = tid >> 3, sub = tid & 7;
        const int e = t * K_ + k;
        int src = srcArr[e];
        src = (src < 0) ? 0 : ((src >= N_) ? (N_ - 1) : src);
        float vx = ldf(trans, src*3+0, bf) - ldf(trans, t*3+0, bf);
        float vy = ldf(trans, src*3+1, bf) - ldf(trans, t*3+1, bf);
        float vz = ldf(trans, src*3+2, bf) - ldf(trans, t*3+2, bf);
        float dist = sqrtf(vx*vx + vy*vy + vz*vz);
        bool valid = isfinite(dist) && (dist > 1e-3f);
        int d = src - t + 512;
        d = (d < 0) ? 0 : ((d > 1023) ? 1023 : d);
        if (sub == 0) {
            srcS[k]  = src;
            voffS[k] = src << 8;
            dS[k]    = d | (valid ? 0 : (1 << 16));
        }
        const int j0 = sub * 2;
        float t0 = (dist - (float)j0       * (20.f/15.f)) * 0.8f;
        float t1 = (dist - (float)(j0 + 1) * (20.f/15.f)) * 0.8f;
        rbfS[k][j0]     = __expf(-t0 * t0);
        rbfS[k][j0 + 1] = __expf(-t1 * t1);
    } else {
        const int k = 30 + ((tid - 240) >> 3), sub = (tid - 240) & 7;
        if (sub == 0) { srcS[k] = 0; voffS[k] = 0; dS[k] = 1 << 16; }
        rbfS[k][sub * 2] = 0.f;
        rbfS[k][sub * 2 + 1] = 0.f;
    }
    __syncthreads();

    // ---- phase B: wave wid handles edges wid*8..wid*8+7 (branch-free, k<32 always valid) ----
    const float2 htv = ((const float2*)(htgt + (size_t)t * 128))[lane];  // block-constant
    #pragma unroll
    for (int j = 0; j < 8; ++j) {
        const int k = wid * 8 + j;
        const int src = srcS[k];
        const int dm  = dS[k];
        const int d   = dm & 0xFFFF;
        const bool valid = (dm >> 16) == 0;
        float2 hs = ((const float2*)(hsrc + (size_t)src * 128))[lane];
        float2 pt = ((const float2*)(ptab + (size_t)d   * 128))[lane];
        float acc0 = hs.x + htv.x + pt.x;
        float acc1 = hs.y + htv.y + pt.y;
        const float4* rp = (const float4*)(&rbfS[k][0]);
        float4 ra = rp[0], rb = rp[1], rc = rp[2], rd = rp[3];   // broadcast reads
        acc0 = fmaf(ra.x, w0.x, acc0); acc1 = fmaf(ra.x, w0.y, acc1);
        acc0 = fmaf(ra.y, w1.x, acc0); acc1 = fmaf(ra.y, w1.y, acc1);
        acc0 = fmaf(ra.z, w2.x, acc0); acc1 = fmaf(ra.z, w2.y, acc1);
        acc0 = fmaf(ra.w, w3.x, acc0); acc1 = fmaf(ra.w, w3.y, acc1);
        acc0 = fmaf(rb.x, w4.x, acc0); acc1 = fmaf(rb.x, w4.y, acc1);
        acc0 = fmaf(rb.y, w5.x, acc0); acc1 = fmaf(rb.y, w5.y, acc1);
        acc0 = fmaf(rb.z, w6.x, acc0); acc1 = fmaf(rb.z, w6.y, acc1);
        acc0 = fmaf(rb.w, w7.x, acc0); acc1 = fmaf(rb.w, w7.y, acc1);
        acc0 = fmaf(rc.x, w8.x, acc0); acc1 = fmaf(rc.x, w8.y, acc1);
        acc0 = fmaf(rc.y, w9.x, acc0); acc1 = fmaf(rc.y, w9.y, acc1);
        acc0 = fmaf(rc.z, wA.x, acc0); acc1 = fmaf(rc.z, wA.y, acc1);
        acc0 = fmaf(rc.w, wB.x, acc0); acc1 = fmaf(rc.w, wB.y, acc1);
        acc0 = fmaf(rd.x, wC.x, acc0); acc1 = fmaf(rd.x, wC.y, acc1);
        acc0 = fmaf(rd.y, wD.x, acc0); acc1 = fmaf(rd.y, wD.y, acc1);
        acc0 = fmaf(rd.z, wE.x, acc0); acc1 = fmaf(rd.z, wE.y, acc1);
        acc0 = fmaf(rd.w, wF.x, acc0); acc1 = fmaf(rd.w, wF.y, acc1);
        float part = fsilu(acc0) * avv.x + fsilu(acc1) * avv.y;
        // 8-lane reduce on VALU via DPP (bit-identical tree to shfl_xor 1/2/4)
        part += __uint_as_float((u32)__builtin_amdgcn_update_dpp(
                    (int)__float_as_uint(part), (int)__float_as_uint(part), 0xB1, 0xF, 0xF, false)); // quad_perm xor1
        part += __uint_as_float((u32)__builtin_amdgcn_update_dpp(
                    (int)__float_as_uint(part), (int)__float_as_uint(part), 0x4E, 0xF, 0xF, false)); // quad_perm xor2
        part += __uint_as_float((u32)__builtin_amdgcn_update_dpp(
                    (int)__float_as_uint(part), (int)__float_as_uint(part), 0x141, 0xF, 0xF, false)); // row_half_mirror
        float lg = (part >= 0.f) ? part : 0.2f * part;
        if (!valid) lg = -1e9f;
        lg = (fabsf(lg) < 1e30f) ? lg : -1e9f;
        if ((lane & 7) == 0) lgS[k * 8 + (lane >> 3)] = lg;
    }
    __syncthreads();

    // ---- softmax numerators once per (k,h): thread h handles head h (k<30 only) ----
    if (tid < 8) {
        float mx = -1e30f;
        #pragma unroll
        for (int k = 0; k < K_; ++k) mx = fmaxf(mx, lgS[k * 8 + tid]);
        float den = 0.f;
        #pragma unroll
        for (int k = 0; k < K_; ++k) {
            float l = lgS[k * 8 + tid];
            float e = (l > -1e8f) ? __expf(l - mx) : 0.f;
            lgS[k * 8 + tid] = e; den += e;
        }
        invS[tid] = 1.f / (den + 1e-9f);
    }
    __syncthreads();

    // ---- phase C: weighted V sum (pure FMA; same accumulation order) ----
    {
        const int h = (tid & 63) >> 3;
        float acc = 0.f;
        #pragma unroll 6
        for (int k = 0; k < K_; ++k)
            acc = fmaf(lgS[k * 8 + h], V[voffS[k] + tid], acc);
        aggS[tid] = acc * invS[h];
    }
    __syncthreads();

    // ---- epilogue: y = agg @ W_o ; gate = silu(y0 @ W_g) ; out = (y*gate) @ W_2 ----
    if (tid < 128) {
        int rr = tid >> 5, o = tid & 31;
        float y = 0.f;
        #pragma unroll
        for (int c = 0; c < 64; ++c) y = fmaf(aggS[rr * 64 + c], Wo[c * 32 + o], y);
        ybuf[tid] = y;
    }
    __syncthreads();
    if (tid < 32) {
        float g = 0.f;
        #pragma unroll
        for (int o = 0; o < 32; ++o) g = fmaf(ybuf[o], Wg[o * 32 + tid], g);
        gbuf[tid] = fsilu(g);
    }
    __syncthreads();
    if (tid < 128) {
        int rr = tid >> 5, hh = tid & 31;
        float o = 0.f;
        #pragma unroll
        for (int g = 0; g < 32; ++g) o = fmaf(ybuf[rr * 32 + g] * gbuf[g], W2[g * 32 + hh], o);
        o = (fabsf(o) < 1e30f) ? o : 0.f;
        size_t idx = (size_t)t * 128 + tid;
        if (bf) ((u16*)outv)[idx] = f2bf(o);
        else    ((float*)outv)[idx] = o;
    }
}

extern "C" void kernel_launch(void* const* d_in, const int* in_sizes, int n_in,
                              void* d_out, int out_size, void* d_ws, size_t ws_size,
                              hipStream_t stream)
{
    const void* rots         = d_in[0];
    const void* trans        = d_in[1];
    const void* node_emb     = d_in[2];
    /* d_in[3] = batch (unused; chains contiguous) */
    const void* x_mask       = d_in[4];
    const void* noising_mask = d_in[5];
    const void* Wa           = d_in[6];
    const void* avec         = d_in[7];
    const void* Wv           = d_in[8];
    const void* Wo           = d_in[9];
    const void* Wg           = d_in[10];
    const void* W2           = d_in[11];

    char* ws = (char*)d_ws;
    int*   flag    = (int*)  (ws + 0);            //        64
    int*   srcArr  = (int*)  (ws + 64);           //   983,040
    float* hsrc    = (float*)(ws + 983104);       // 4,194,304
    float* htgt    = (float*)(ws + 5177408);      // 4,194,304
    float* ptab    = (float*)(ws + 9371712);      //   524,288
    float* V       = (float*)(ws + 9896000);      // 8,388,608
    float* c_wrb   = (float*)(ws + 18284608);     //     8,192
    float* c_av    = (float*)(ws + 18292800);     //       512
    float* c_Wo    = (float*)(ws + 18293312);     //     8,192
    float* c_Wg    = (float*)(ws + 18301504);     //     4,096
    float* c_W2    = (float*)(ws + 18305600);     //     4,096  (end ~18.3 MB)

    hipLaunchKernelGGL(mega_kernel, dim3(11272), dim3(256), 0, stream,
                       rots, trans, node_emb, x_mask, noising_mask,
                       Wa, avec, Wv, Wo, Wg, W2,
                       flag, srcArr, hsrc, htgt, ptab, V,
                       c_wrb, c_av, c_Wo, c_Wg, c_W2);
    hipLaunchKernelGGL(edge_agg_kernel, dim3(N_), dim3(256), 0, stream,
                       trans, srcArr, hsrc, htgt, ptab, V,
                       c_wrb, c_av, c_Wo, c_Wg, c_W2, flag, d_out);
}